// Round 1
// baseline (534.764 us; speedup 1.0000x reference)
//
#include <hip/hip_runtime.h>

#define DEV __device__ __forceinline__

typedef __attribute__((ext_vector_type(4))) float f32x4;
typedef __attribute__((ext_vector_type(2))) float f32x2;
typedef __attribute__((ext_vector_type(8))) short bf16x8;

// Shapes: E=16, D=1024, ED=512, NB=8, DB=64, R=2, F=256, N=32768, C=2048

// ---------- helpers ----------
DEV unsigned short f2bf(float f) {
  union { float f; unsigned u; } v; v.f = f;
  unsigned r = v.u + 0x7fffu + ((v.u >> 16) & 1u);
  return (unsigned short)(r >> 16);
}

DEV unsigned pk2bf(float lo, float hi) {  // v_cvt_pk_bf16_f32 (RNE)
  unsigned r;
  asm("v_cvt_pk_bf16_f32 %0, %1, %2" : "=v"(r) : "v"(lo), "v"(hi));
  return r;
}
DEV unsigned short f2bf1(float v) { return (unsigned short)pk2bf(v, v); }

DEV float bf2f(unsigned short b) {
  union { unsigned u; float f; } v; v.u = ((unsigned)b) << 16; return v.f;
}

DEV float frcp(float x) { return __builtin_amdgcn_rcpf(x); }

// raw barrier: NO implicit vmcnt drain. "memory" clobber = compiler fence.
DEV void sbar() { asm volatile("s_barrier" ::: "memory"); }
DEV void wait_lgkm0() { asm volatile("s_waitcnt lgkmcnt(0)" ::: "memory"); }
DEV void wait_vm0() { asm volatile("s_waitcnt vmcnt(0)" ::: "memory"); }

DEV void async16(const unsigned short* g, unsigned short* l) {
  __builtin_amdgcn_global_load_lds(
      (__attribute__((address_space(1))) const unsigned int*)g,
      (__attribute__((address_space(3))) unsigned int*)l, 16, 0, 0);
}

// Tiled global layout for GEMM operands: element (n,k) of an [N][K] panel at
//   (n>>3)*8K + (k>>3)*64 + (n&7)*8 + (k&7)
DEV long tiled_off(long n, int k, int K) {
  return (n >> 3) * (8L * K) + (long)(((k >> 3) * 64) + ((int)(n & 7)) * 8 + (k & 7));
}

// frag read from a tiled 32-k LDS subtile (bf16)
DEV bf16x8 ld_frag(const char* s, int row, int hi) {
  return *(const bf16x8*)(s + ((row >> 3) * 512 + hi * 128 + (row & 7) * 16));
}

// ---------- Cayley table at compile time ----------
__host__ __device__ constexpr int km_(int i) { return i==0?0:i==1?1:i==2?2:i==3?4:i==4?3:i==5?5:i==6?6:7; }
__host__ __device__ constexpr int pc_(int x) { int c = 0; while (x) { c += x & 1; x >>= 1; } return c; }
__host__ __device__ constexpr int KIDX(int i, int j) { return km_(km_(i) ^ km_(j)); }
__host__ __device__ constexpr int CSGN(int i, int j) {
  int a = km_(i), b = km_(j), aa = a >> 1, s = 0;
  while (aa) { s += pc_(aa & b); aa >>= 1; }
  return (s & 1) ? -1 : 1;
}
__host__ __device__ constexpr int PIDX(int i, int j) {  // i<=j
  return 8 * i - (i * (i - 1)) / 2 + (j - i);
}

// ---------- small kernels ----------
__global__ __launch_bounds__(64) void geoprep_k(const float* __restrict__ iw,
                                                const float* __restrict__ gg,
                                                float* __restrict__ wcomb) {
  int er = threadIdx.x;
  if (er >= 32) return;
  const float* w = iw + er * 64;
  float gate = frcp(1.f + __expf(-gg[er]));
  float* c = wcomb + er * 40;
  int p = 0;
  for (int i = 0; i < 8; ++i)
    for (int j = i; j < 8; ++j) {
      float v = (float)CSGN(i, j) * frcp(1.f + __expf(-w[i * 8 + j]));
      if (j > i) v += (float)CSGN(j, i) * frcp(1.f + __expf(-w[j * 8 + i]));
      c[p++] = gate * v;
    }
  c[36] = 1.f - gate;
}

// x fp32 [32768][1024] -> xb bf16 in tiled layout (K=1024).
__global__ __launch_bounds__(256) void convert_k(const float* __restrict__ in,
                                                 unsigned short* __restrict__ out,
                                                 long nchunks) {
  long q = (long)blockIdx.x * 256 + threadIdx.x;
  long stride = (long)gridDim.x * 256;
  for (; q < nchunks; q += stride) {
    long n = q >> 7;
    int k8 = (int)(q & 127);
    const float4* p = (const float4*)(in + n * 1024 + k8 * 8);
    float4 v0 = p[0], v1 = p[1];
    uint4 o;
    o.x = pk2bf(v0.x, v0.y);
    o.y = pk2bf(v0.z, v0.w);
    o.z = pk2bf(v1.x, v1.y);
    o.w = pk2bf(v1.z, v1.w);
    *(uint4*)(out + (n >> 3) * 8192 + k8 * 64 + (n & 7) * 8) = o;
  }
}

// small transposes (wg/wu/wd): in (Rr,Cc) fp32 (batch z) -> (Cc,Rr) bf16.
// TI=0 linear; TI=1: k ^= (row&7)<<3 (needs Rr==64).
template<int TI>
__global__ __launch_bounds__(256) void transpose_k(const float* __restrict__ in,
                                                   unsigned short* __restrict__ out,
                                                   int Rr, int Cc) {
  __shared__ unsigned short tile[32][33];
  const float* ib = in + (long)blockIdx.z * Rr * Cc;
  unsigned short* ob = out + (long)blockIdx.z * Rr * Cc;
  int r0 = blockIdx.y * 32, c0 = blockIdx.x * 32;
  int tr = threadIdx.x >> 5, tc = threadIdx.x & 31;
#pragma unroll
  for (int i = 0; i < 4; ++i) {
    int r = tr + i * 8;
    tile[r][tc] = f2bf(ib[(long)(r0 + r) * Cc + c0 + tc]);
  }
  __syncthreads();
#pragma unroll
  for (int i = 0; i < 4; ++i) {
    int c = tr + i * 8;
    int row = c0 + c;
    int k = r0 + tc;
    if (TI == 0) ob[(long)row * Rr + k] = tile[tc][c];
    else ob[(long)row * Rr + (k ^ ((row & 7) << 3))] = tile[tc][c];
  }
}

// big convert+transpose for pin/pout: in [Rr k][Cc n] fp32 -> out tiled bf16 [n][k].
__global__ __launch_bounds__(256) void trans_big_k(const float* __restrict__ in,
                                                   unsigned short* __restrict__ out,
                                                   int Rr, int Cc) {
  __shared__ float t[64][64];
  const float* ib = in + (long)blockIdx.z * Rr * Cc;
  unsigned short* ob = out + (long)blockIdx.z * (long)Rr * Cc;
  int k0 = blockIdx.y * 64, n0 = blockIdx.x * 64;
  int tid = threadIdx.x;
#pragma unroll
  for (int p = 0; p < 4; ++p) {
    int idx = p * 256 + tid;
    int kr = idx >> 4, nc = (idx & 15) * 4;
    *(float4*)&t[kr][nc] = *(const float4*)(ib + (long)(k0 + kr) * Cc + n0 + nc);
  }
  __syncthreads();
#pragma unroll
  for (int p = 0; p < 2; ++p) {
    int idx = p * 256 + tid;
    int n = idx & 63, kc = idx >> 6;       // kc 0..7
    float v[8];
#pragma unroll
    for (int u = 0; u < 8; ++u) v[u] = t[kc * 8 + u][n];
    uint4 o;
    o.x = pk2bf(v[0], v[1]); o.y = pk2bf(v[2], v[3]);
    o.z = pk2bf(v[4], v[5]); o.w = pk2bf(v[6], v[7]);
    *(uint4*)(ob + tiled_off(n0 + n, k0 + kc * 8, Rr)) = o;
  }
}

// GEMM1: mvB(bf16, linear [token][512]) = x @ Pin^T per expert. 256x256 tile, BK=64,
// quantum-pipelined (r10 structure).
__global__ __launch_bounds__(512, 1) void gemm_in_k(const unsigned short* __restrict__ Xb,
                                                    const unsigned short* __restrict__ Bw,
                                                    unsigned short* __restrict__ MvB,
                                                    const int* __restrict__ offs) {
  extern __shared__ char smem[];    // [2 buf][ A 32K | B 32K ], each op as 2 x 16K ksub
  int bid = blockIdx.x;             // 256 blocks
  int wg = (bid & 7) * 32 + (bid >> 3);      // XCD swizzle (256 % 8 == 0)
  int e = wg >> 4, rem = wg & 15, bm = rem >> 1, bn = rem & 1;
  int tid = threadIdx.x, wid = tid >> 6, lane = tid & 63;
  int wm = (wid >> 2) * 128, wn = (wid & 3) * 64;
  int ri = lane & 15, hi = lane >> 4;
  long aw = ((long)offs[e] >> 3) + bm * 32;  // A window base (xb tiled, K=1024)
  long bw = (long)e * 64 + bn * 32;          // B window base (pinT tiled, K=1024)

  auto STG = [&](int b, int kt, int s, int op) {
    const unsigned short* src = op ? Bw : Xb;
    long wbase = op ? bw : aw;
    char* dst = smem + b * 65536 + op * 32768 + s * 16384;
#pragma unroll
    for (int i = 0; i < 2; ++i) {
      int d = i * 512 + tid;
      async16(src + (wbase + (d >> 5)) * 8192 +
                  (long)((kt * 8 + s * 4 + ((d >> 3) & 3)) * 64 + (d & 7) * 8),
              (unsigned short*)(dst + d * 16));
    }
  };

  f32x4 acc[8][4];
#pragma unroll
  for (int i = 0; i < 8; ++i)
#pragma unroll
    for (int j = 0; j < 4; ++j) acc[i][j] = (f32x4){0.f, 0.f, 0.f, 0.f};

  STG(0, 0, 0, 0); STG(0, 0, 0, 1); STG(0, 0, 1, 0); STG(0, 0, 1, 1);

  for (int t = 0; t < 16; ++t) {
    int c = t & 1;
    const char* cA = smem + c * 65536;
    const char* cB = smem + c * 65536 + 32768;
#pragma unroll
    for (int s = 0; s < 2; ++s) {
      if (t < 15) {
        STG(c ^ 1, t + 1, s, 0);
        STG(c ^ 1, t + 1, s, 1);
        asm volatile("s_waitcnt vmcnt(8)" ::: "memory");
      } else if (s == 0) {
        asm volatile("s_waitcnt vmcnt(4)" ::: "memory");
      } else {
        asm volatile("s_waitcnt vmcnt(0)" ::: "memory");
      }
      sbar();
      bf16x8 a[8], b[4];
#pragma unroll
      for (int i = 0; i < 8; ++i) a[i] = ld_frag(cA + s * 16384, wm + i * 16 + ri, hi);
#pragma unroll
      for (int j = 0; j < 4; ++j) b[j] = ld_frag(cB + s * 16384, wn + j * 16 + ri, hi);
      __builtin_amdgcn_s_setprio(1);
#pragma unroll
      for (int i = 0; i < 8; ++i)
#pragma unroll
        for (int j = 0; j < 4; ++j)
          acc[i][j] = __builtin_amdgcn_mfma_f32_16x16x32_bf16(a[i], b[j], acc[i][j], 0, 0, 0);
      __builtin_amdgcn_s_setprio(0);
    }
  }

  unsigned short* Cb = MvB + ((long)e * 2048 + (long)bm * 256) * 512 + bn * 256;
#pragma unroll
  for (int i = 0; i < 8; ++i)
#pragma unroll
    for (int j = 0; j < 4; ++j)
#pragma unroll
      for (int rr = 0; rr < 4; ++rr)
        Cb[(long)(wm + i * 16 + hi * 4 + rr) * 512 + wn + j * 16 + ri] =
            f2bf1(acc[i][j][rr]);
}

// ---------- merged 2-round fused kernel ----------
// 16 tokens/block, 512 threads, BOTH rounds. F in FOUR QUARTERS per round.
// Wg/Wu/Wd ALL read directly from global per-wave (L1/L2-resident; no LDS
// staging, no W double-buffer) -> LDS shrinks 80K -> 48K -> 3 blocks/CU:
//   sFlat @0      16K: [128 row][128B], xor (4q ^ (row&7)<<4)
//   sH @16K       16K: h-qtr [128 trow][128B], xor (trow&7)<<4
//   sMvh @32K     16K: bf16 [16 tok][512] residual state (across rounds)
// Flat B-frags hoisted to regs once/round (sFlat immutable within round).
// P1 math packed as f32x2 -> v_pk_fma_f32/v_pk_mul_f32 on gfx950.
__global__ __launch_bounds__(512, 6) void rounds_k(
    const unsigned short* __restrict__ MvB, const unsigned short* __restrict__ WgT,
    const unsigned short* __restrict__ WuT, const unsigned short* __restrict__ WdT,
    const float* __restrict__ wcomb, const float* __restrict__ lnw,
    const float* __restrict__ lnb, unsigned short* __restrict__ Mvb) {
  extern __shared__ char smem[];
  char* sH = smem + 16384;
  unsigned short* sMvh = (unsigned short*)(smem + 32768);  // [16][512] bf16
  int tid = threadIdx.x, wid = tid >> 6, lane = tid & 63;
  int bid = blockIdx.x;
  int wg = (bid & 7) * 256 + (bid >> 3);          // XCD swizzle (2048 % 8 == 0)
  int e = wg >> 7, bx = wg & 127;

  int tok = tid >> 5, q = tid & 31;
  int wmf = (wid & 1) * 32, wnr = (wid >> 1) * 32;   // P2: F-half 2x32, trow 4x32
  int wm2 = wid * 16;                                 // P4: trow 8x16
  int ri = lane & 15, hi = lane >> 4, kb16 = hi * 16;

#pragma unroll 1
  for (int r = 0; r < 2; ++r) {
    int er = e * 2 + r;
    const unsigned short* wgp = WgT + (long)er * 16384;  // [256 F][64 DB] linear
    const unsigned short* wup = WuT + (long)er * 16384;  // [256 F][64 DB] linear
    const unsigned short* wd  = WdT + (long)er * 16384;  // [64 dout][256 F]

    // ---- P1a: get mv (global bf16 on r0 -> stash; sMvh on r1) ----
    f32x2 mv[8];
    if (r == 0) {
      long base = ((long)e * 2048 + bx * 16 + tok) * 512 + 2 * q;
      unsigned uv[8];
#pragma unroll
      for (int i = 0; i < 8; ++i)
        uv[i] = *(const unsigned*)(MvB + base + i * 64);
#pragma unroll
      for (int i = 0; i < 8; ++i) {
        *(unsigned*)(sMvh + tok * 512 + i * 64 + 2 * q) = uv[i];
        mv[i] = (f32x2){bf2f((unsigned short)(uv[i] & 0xffff)),
                        bf2f((unsigned short)(uv[i] >> 16))};
      }
    } else {
#pragma unroll
      for (int i = 0; i < 8; ++i) {
        unsigned uv = *(const unsigned*)(sMvh + tok * 512 + i * 64 + 2 * q);
        mv[i] = (f32x2){bf2f((unsigned short)(uv & 0xffff)),
                        bf2f((unsigned short)(uv >> 16))};
      }
    }

    // ---- P1b: geo + mix + LN(64) -> sFlat (packed f32x2 math) ----
    {
      const float* C = wcomb + er * 40;
      f32x2 g[8];
#pragma unroll
      for (int k = 0; k < 8; ++k) g[k] = (f32x2){0.f, 0.f};
#pragma unroll
      for (int i = 0; i < 8; ++i)
#pragma unroll
        for (int j = i; j < 8; ++j) {
          float cc = C[PIDX(i, j)];
          const int k = KIDX(i, j);
          g[k] += cc * (mv[i] * mv[j]);
        }
      float omg = C[36];
#pragma unroll
      for (int k = 0; k < 8; ++k) g[k] = omg * mv[k] + g[k];   // mixed, in place
      float2 lw = *(const float2*)(lnw + (long)er * 64 + 2 * q);
      float2 lb = *(const float2*)(lnb + (long)er * 64 + 2 * q);
      f32x2 lwv = (f32x2){lw.x, lw.y}, lbv = (f32x2){lb.x, lb.y};
#pragma unroll
      for (int half = 0; half < 2; ++half) {
        f32x2 red[4];
#pragma unroll
        for (int k = 0; k < 4; ++k) {
          f32x2 mx = g[half * 4 + k];
          red[k].x = mx.x + mx.y;
          red[k].y = fmaf(mx.x, mx.x, mx.y * mx.y);
        }
#pragma unroll
        for (int off = 16; off >= 1; off >>= 1)
#pragma unroll
          for (int t = 0; t < 4; ++t) {
            f32x2 o;
            o.x = __shfl_xor(red[t].x, off);
            o.y = __shfl_xor(red[t].y, off);
            red[t] += o;
          }
#pragma unroll
        for (int k = 0; k < 4; ++k) {
          int kk = half * 4 + k;
          float mean = red[k].x * (1.f / 64.f);
          float var = red[k].y * (1.f / 64.f) - mean * mean;
          float rs = rsqrtf(var + 1e-5f);
          f32x2 nv = (g[kk] - mean) * rs;
          f32x2 ov = nv * lwv + lbv;
          unsigned pv = pk2bf(ov.x, ov.y);
          int row = tok * 8 + kk;                   // row&7 == kk
          *(unsigned*)(smem + row * 128 + ((4 * q) ^ (kk << 4))) = pv;
        }
      }
    }
    __syncthreads();   // sFlat + sMvh visible

    // ---- hoist flat B-frags (sFlat immutable for the rest of the round) ----
    bf16x8 bf[2][2];
#pragma unroll
    for (int j = 0; j < 2; ++j) {
      int row = wnr + j * 16 + ri;
      int sw = (row & 7) << 4;
#pragma unroll
      for (int kt = 0; kt < 2; ++kt)
        bf[j][kt] = *(const bf16x8*)(smem + row * 128 + ((kt * 64 + kb16) ^ sw));
    }

    f32x4 acc2[4];
#pragma unroll
    for (int j = 0; j < 4; ++j) acc2[j] = (f32x4){0.f, 0.f, 0.f, 0.f};

#pragma unroll 1
    for (int qq = 0; qq < 4; ++qq) {
      // ---- P2: W-qtr(global) x flat(regs), swapped -> D[F][trow]; silu -> hpk ----
      uint2 hpk[2][2];
#pragma unroll
      for (int i = 0; i < 2; ++i) {
        int frow = qq * 64 + wmf + i * 16 + ri;
        const unsigned short* gp = wgp + frow * 64 + hi * 8;
        const unsigned short* up = wup + frow * 64 + hi * 8;
        bf16x8 wg0 = *(const bf16x8*)gp;
        bf16x8 wg1 = *(const bf16x8*)(gp + 32);
        bf16x8 wu0 = *(const bf16x8*)up;
        bf16x8 wu1 = *(const bf16x8*)(up + 32);
        f32x4 ag[2], au[2];
#pragma unroll
        for (int j = 0; j < 2; ++j) {
          ag[j] = (f32x4){0.f, 0.f, 0.f, 0.f};
          au[j] = (f32x4){0.f, 0.f, 0.f, 0.f};
        }
        __builtin_amdgcn_s_setprio(1);
#pragma unroll
        for (int j = 0; j < 2; ++j) {
          ag[j] = __builtin_amdgcn_mfma_f32_16x16x32_bf16(wg0, bf[j][0], ag[j], 0, 0, 0);
          au[j] = __builtin_amdgcn_mfma_f32_16x16x32_bf16(wu0, bf[j][0], au[j], 0, 0, 0);
        }
#pragma unroll
        for (int j = 0; j < 2; ++j) {
          ag[j] = __builtin_amdgcn_mfma_f32_16x16x32_bf16(wg1, bf[j][1], ag[j], 0, 0, 0);
          au[j] = __builtin_amdgcn_mfma_f32_16x16x32_bf16(wu1, bf[j][1], au[j], 0, 0, 0);
        }
        __builtin_amdgcn_s_setprio(0);
#pragma unroll
        for (int j = 0; j < 2; ++j) {
          float hh[4];
#pragma unroll
          for (int rr = 0; rr < 4; ++rr) {
            float gv = ag[j][rr], uu = au[j][rr];
            hh[rr] = gv * uu * frcp(1.f + __expf(-gv));
          }
          hpk[i][j].x = pk2bf(hh[0], hh[1]);
          hpk[i][j].y = pk2bf(hh[2], hh[3]);
        }
      }

      // ---- issue Wd frags (global): land under P3+barrier ----
      bf16x8 bpA[4], bpB[4];
      {
        const unsigned short* wdq = wd + qq * 64 + hi * 8;
#pragma unroll
        for (int j = 0; j < 4; ++j) {
          bpA[j] = *(const bf16x8*)(wdq + (j * 16 + ri) * 256);
          bpB[j] = *(const bf16x8*)(wdq + (j * 16 + ri) * 256 + 32);
        }
      }

      // ---- P3: write h-qtr ----
      {
        int rb4 = hi * 4;
#pragma unroll
        for (int i = 0; i < 2; ++i) {
          int F0 = wmf + i * 16 + rb4;
#pragma unroll
          for (int j = 0; j < 2; ++j) {
            int trow = wnr + j * 16 + ri;
            *(uint2*)(sH + trow * 128 + ((2 * F0) ^ ((trow & 7) << 4))) = hpk[i][j];
          }
        }
      }
      wait_lgkm0();
      sbar();           // h visible

      // ---- P4: h-qtr(LDS) x Wd(regs) -> acc2 (K=64 partial) ----
      {
        int arow = wm2 + ri;
        int asw = (arow & 7) << 4;
        bf16x8 a0 = *(const bf16x8*)(sH + arow * 128 + (kb16 ^ asw));
        bf16x8 a1 = *(const bf16x8*)(sH + arow * 128 + ((64 + kb16) ^ asw));
        __builtin_amdgcn_s_setprio(1);
#pragma unroll
        for (int j = 0; j < 4; ++j)
          acc2[j] = __builtin_amdgcn_mfma_f32_16x16x32_bf16(a0, bpA[j], acc2[j], 0, 0, 0);
#pragma unroll
        for (int j = 0; j < 4; ++j)
          acc2[j] = __builtin_amdgcn_mfma_f32_16x16x32_bf16(a1, bpB[j], acc2[j], 0, 0, 0);
        __builtin_amdgcn_s_setprio(0);
      }
      sbar();           // quarter end: h region free for overwrite
    }

    // ---- P5: residual against sMvh; r0 updates sMvh, r1 writes Mvb (linear) ----
    {
#pragma unroll
      for (int j = 0; j < 4; ++j)
#pragma unroll
        for (int rr = 0; rr < 4; ++rr) {
          int trow = wm2 + hi * 4 + rr;
          int dout = j * 16 + ri;
          int tl = trow >> 3, kb = trow & 7;
          unsigned short* sp = sMvh + tl * 512 + kb * 64 + dout;
          float v = bf2f(*sp) + acc2[j][rr];
          if (r == 0) {
            *sp = f2bf1(v);
          } else {
            Mvb[((long)e * 2048 + bx * 16 + tl) * 512 + kb * 64 + dout] = f2bf1(v);
          }
        }
    }
    wait_lgkm0();
    sbar();   // sMvh updates visible before next round's P1a reads
  }
}

// ---------- fused out-projection + LayerNorm(D=1024), 512 threads/block ----------
// A (mvb) is LINEAR [token][512] bf16; tiled LDS layout derived via per-lane source addr.
__global__ __launch_bounds__(512, 2) void gemm_out_ln_k(
    const unsigned short* __restrict__ Mvb, const unsigned short* __restrict__ Pw,
    float* __restrict__ Out, const float* __restrict__ ow, const float* __restrict__ ob,
    const int* __restrict__ offs) {
  extern __shared__ char smem[];
  int bid = blockIdx.x;
  int wg = (bid & 7) * 64 + (bid >> 3);
  int e = wg >> 5, mb = wg & 31;
  int tid = threadIdx.x, wid = tid >> 6, lane = tid & 63;
  int ri = lane & 15, hi = lane >> 4;
  long bbase = (long)e * 524288;                 // poutT expert base (tiled)
  long arow0 = (long)e * 2048 + (long)mb * 64;   // mvb expert row base (linear)

  auto STAGE = [&](int buf, int kt) {
#pragma unroll
    for (int i = 0; i < 8; ++i) {
      int q = i * 512 + tid;
      int w = q >> 5, c = (q >> 3) & 3, rr = q & 7;
      async16(Pw + bbase + (long)w * 4096 + (kt * 4 + c) * 64 + rr * 8,
              (unsigned short*)(smem + buf * 65536 + q * 16));
    }
    if (tid < 256) {
      int q = tid;
      int w = q >> 5, c = (q >> 3) & 3, rr = q & 7;
      async16(Mvb + (arow0 + w * 8 + rr) * 512 + kt * 32 + c * 8,
              (unsigned short*)(smem + 131072 + buf * 4096 + q * 16));
    }
  };

  f32x4 acc[4][8];
#pragma unroll
  for (int i = 0; i < 4; ++i)
#pragma unroll
    for (int j = 0; j < 8; ++j) acc[i][j] = (f32x4){0.f, 0.f, 0.f, 0.f};

  STAGE(0, 0);
  for (int kt = 0; kt < 16; ++kt) {
    int cur = kt & 1;
    if (kt < 15) {
      STAGE(cur ^ 1, kt + 1);
      asm volatile("s_waitcnt vmcnt(8)" ::: "memory");
    } else {
      asm volatile("s_waitcnt vmcnt(0)" ::: "memory");
    }
    sbar();
    const char* cB = smem + cur * 65536;
    const char* cA = smem + 131072 + cur * 4096;
    bf16x8 a[4], b[8];
#pragma unroll
    for (int i = 0; i < 4; ++i) a[i] = ld_frag(cA, i * 16 + ri, hi);
#pragma unroll
    for (int j = 0; j < 8; ++j) b[j] = ld_frag(cB, wid * 128 + j * 16 + ri, hi);
    __builtin_amdgcn_s_setprio(1);
#pragma unroll
    for (int i = 0; i < 4; ++i)
#pragma unroll
      for (int j = 0; j < 8; ++j)
        acc[i][j] = __builtin_amdgcn_mfma_f32_16x16x32_bf16(a[i], b[j], acc[i][j], 0, 0, 0);
    __builtin_amdgcn_s_setprio(0);
    sbar();
  }

  float* rsum = (float*)(smem + 139264);
  float* rsq  = (float*)(smem + 141312);
  float* mexp = (float*)(smem + 143360);
  float* rstd = (float*)(smem + 143616);
  int hi4 = hi * 4;
#pragma unroll
  for (int i = 0; i < 4; ++i)
#pragma unroll
    for (int rr = 0; rr < 4; ++rr) {
      float s = 0.f, qv = 0.f;
#pragma unroll
      for (int j = 0; j < 8; ++j) { float v = acc[i][j][rr]; s += v; qv += v * v; }
#pragma unroll
      for (int off = 1; off < 16; off <<= 1) {
        s += __shfl_xor(s, off);
        qv += __shfl_xor(qv, off);
      }
      if (ri == 0) {
        int row = i * 16 + hi4 + rr;
        rsum[row * 8 + wid] = s;
        rsq[row * 8 + wid] = qv;
      }
    }
  __syncthreads();
  if (tid < 64) {
    float S = 0.f, Q = 0.f;
#pragma unroll
    for (int w = 0; w < 8; ++w) { S += rsum[tid * 8 + w]; Q += rsq[tid * 8 + w]; }
    float mean = S * (1.f / 1024.f);
    float var = Q * (1.f / 1024.f) - mean * mean;
    mexp[tid] = mean;
    rstd[tid] = rsqrtf(var + 1e-5f);
  }
  __syncthreads();
  long r0 = (long)offs[e] + (long)mb * 64;
  float owv[8], obv[8];
#pragma unroll
  for (int j = 0; j < 8; ++j) {
    int col = wid * 128 + j * 16 + ri;
    owv[j] = ow[col];
    obv[j] = ob[col];
  }
#pragma unroll
  for (int i = 0; i < 4; ++i)
#pragma unroll
    for (int rr = 0; rr < 4; ++rr) {
      int row = i * 16 + hi4 + rr;
      float mu = mexp[row], rs = rstd[row];
#pragma unroll
      for (int j = 0; j < 8; ++j) {
        int col = wid * 128 + j * 16 + ri;
        Out[(r0 + row) * 1024 + col] = (acc[i][j][rr] - mu) * rs * owv[j] + obv[j];
      }
    }
}

// ---------- host ----------
extern "C" void kernel_launch(void* const* d_in, const int* in_sizes, int n_in,
                              void* d_out, int out_size, void* d_ws, size_t ws_size,
                              hipStream_t stream) {
  const float* x    = (const float*)d_in[0];
  const float* pin  = (const float*)d_in[1];
  const float* pout = (const float*)d_in[2];
  const float* iw   = (const float*)d_in[3];
  const float* gg   = (const float*)d_in[4];
  const float* fg   = (const float*)d_in[5];
  const float* fu   = (const float*)d_in[6];
  const float* fd   = (const float*)d_in[7];
  const float* lnw  = (const float*)d_in[8];
  const float* lnb  = (const float*)d_in[9];
  const float* ow   = (const float*)d_in[10];
  const float* ob   = (const float*)d_in[11];
  const int* offs   = (const int*)d_in[12];

  char* ws = (char*)d_ws;
  unsigned short* mvB  = (unsigned short*)(ws + 0L);          //  33,554,432 B (linear bf16)
  unsigned short* mvb  = (unsigned short*)(ws + 33554432L);   //  33,554,432 B (linear bf16)
  unsigned short* pinT = (unsigned short*)(ws + 67108864L);   //  16,777,216 B (tiled)
  unsigned short* poutT= (unsigned short*)(ws + 83886080L);   //  16,777,216 B (tiled)
  unsigned short* wgT  = (unsigned short*)(ws + 100663296L);  //   2,097,152 B (plain [F][DB])
  unsigned short* wuT  = (unsigned short*)(ws + 102760448L);  //   2,097,152 B (plain [F][DB])
  unsigned short* wdT  = (unsigned short*)(ws + 104857600L);  //   2,097,152 B (plain)
  float* wcomb         = (float*)(ws + 106954752L);           //   5,120 B
  unsigned short* xb   = (unsigned short*)(ws + 117440512L);  //  67,108,864 B (tiled)

  // prep
  convert_k<<<dim3(4096), dim3(256), 0, stream>>>(x, xb, 4194304L);
  trans_big_k<<<dim3(8, 16, 16), dim3(256), 0, stream>>>(pin, pinT, 1024, 512);
  trans_big_k<<<dim3(16, 8, 16), dim3(256), 0, stream>>>(pout, poutT, 512, 1024);
  transpose_k<0><<<dim3(8, 2, 32), dim3(256), 0, stream>>>(fg, wgT, 64, 256);
  transpose_k<0><<<dim3(8, 2, 32), dim3(256), 0, stream>>>(fu, wuT, 64, 256);
  transpose_k<0><<<dim3(2, 8, 32), dim3(256), 0, stream>>>(fd, wdT, 256, 64);
  geoprep_k<<<dim3(1), dim3(64), 0, stream>>>(iw, gg, wcomb);

  // mvB = x @ Pin (bf16 linear out; 256x256 quantum-pipelined)
  gemm_in_k<<<dim3(256), dim3(512), 131072, stream>>>(xb, pinT, mvB, offs);

  // both rounds in ONE kernel; 48K LDS -> 3 blocks/CU, W direct-from-global
  rounds_k<<<dim3(2048), dim3(512), 49152, stream>>>(
      mvB, wgT, wuT, wdT, wcomb, lnw, lnb, mvb);

  // out = LN(mvb @ Pout)
  gemm_out_ln_k<<<dim3(512), dim3(512), 143872, stream>>>(
      mvb, poutT, (float*)d_out, ow, ob, offs);
}

// Round 2
// 446.712 us; speedup vs baseline: 1.1971x; 1.1971x over previous
//
#include <hip/hip_runtime.h>

#define DEV __device__ __forceinline__

typedef __attribute__((ext_vector_type(4))) float f32x4;
typedef __attribute__((ext_vector_type(2))) float f32x2;
typedef __attribute__((ext_vector_type(8))) short bf16x8;

// Shapes: E=16, D=1024, ED=512, NB=8, DB=64, R=2, F=256, N=32768, C=2048

// ---------- helpers ----------
DEV unsigned short f2bf(float f) {
  union { float f; unsigned u; } v; v.f = f;
  unsigned r = v.u + 0x7fffu + ((v.u >> 16) & 1u);
  return (unsigned short)(r >> 16);
}

DEV unsigned pk2bf(float lo, float hi) {  // v_cvt_pk_bf16_f32 (RNE)
  unsigned r;
  asm("v_cvt_pk_bf16_f32 %0, %1, %2" : "=v"(r) : "v"(lo), "v"(hi));
  return r;
}
DEV unsigned short f2bf1(float v) { return (unsigned short)pk2bf(v, v); }

DEV float bf2f(unsigned short b) {
  union { unsigned u; float f; } v; v.u = ((unsigned)b) << 16; return v.f;
}

DEV float frcp(float x) { return __builtin_amdgcn_rcpf(x); }

// raw barrier: NO implicit vmcnt drain. "memory" clobber = compiler fence.
DEV void sbar() { asm volatile("s_barrier" ::: "memory"); }
DEV void wait_lgkm0() { asm volatile("s_waitcnt lgkmcnt(0)" ::: "memory"); }
DEV void wait_vm0() { asm volatile("s_waitcnt vmcnt(0)" ::: "memory"); }

DEV void async16(const unsigned short* g, unsigned short* l) {
  __builtin_amdgcn_global_load_lds(
      (__attribute__((address_space(1))) const unsigned int*)g,
      (__attribute__((address_space(3))) unsigned int*)l, 16, 0, 0);
}

// Tiled global layout for GEMM operands: element (n,k) of an [N][K] panel at
//   (n>>3)*8K + (k>>3)*64 + (n&7)*8 + (k&7)
DEV long tiled_off(long n, int k, int K) {
  return (n >> 3) * (8L * K) + (long)(((k >> 3) * 64) + ((int)(n & 7)) * 8 + (k & 7));
}

// frag read from a tiled 32-k LDS subtile (bf16)
DEV bf16x8 ld_frag(const char* s, int row, int hi) {
  return *(const bf16x8*)(s + ((row >> 3) * 512 + hi * 128 + (row & 7) * 16));
}

// ---------- Cayley table at compile time ----------
__host__ __device__ constexpr int km_(int i) { return i==0?0:i==1?1:i==2?2:i==3?4:i==4?3:i==5?5:i==6?6:7; }
__host__ __device__ constexpr int pc_(int x) { int c = 0; while (x) { c += x & 1; x >>= 1; } return c; }
__host__ __device__ constexpr int KIDX(int i, int j) { return km_(km_(i) ^ km_(j)); }
__host__ __device__ constexpr int CSGN(int i, int j) {
  int a = km_(i), b = km_(j), aa = a >> 1, s = 0;
  while (aa) { s += pc_(aa & b); aa >>= 1; }
  return (s & 1) ? -1 : 1;
}
__host__ __device__ constexpr int PIDX(int i, int j) {  // i<=j
  return 8 * i - (i * (i - 1)) / 2 + (j - i);
}

// ---------- small kernels ----------
__global__ __launch_bounds__(64) void geoprep_k(const float* __restrict__ iw,
                                                const float* __restrict__ gg,
                                                float* __restrict__ wcomb) {
  int er = threadIdx.x;
  if (er >= 32) return;
  const float* w = iw + er * 64;
  float gate = frcp(1.f + __expf(-gg[er]));
  float* c = wcomb + er * 40;
  int p = 0;
  for (int i = 0; i < 8; ++i)
    for (int j = i; j < 8; ++j) {
      float v = (float)CSGN(i, j) * frcp(1.f + __expf(-w[i * 8 + j]));
      if (j > i) v += (float)CSGN(j, i) * frcp(1.f + __expf(-w[j * 8 + i]));
      c[p++] = gate * v;
    }
  c[36] = 1.f - gate;
}

// x fp32 [32768][1024] -> xb bf16 in tiled layout (K=1024).
__global__ __launch_bounds__(256) void convert_k(const float* __restrict__ in,
                                                 unsigned short* __restrict__ out,
                                                 long nchunks) {
  long q = (long)blockIdx.x * 256 + threadIdx.x;
  long stride = (long)gridDim.x * 256;
  for (; q < nchunks; q += stride) {
    long n = q >> 7;
    int k8 = (int)(q & 127);
    const float4* p = (const float4*)(in + n * 1024 + k8 * 8);
    float4 v0 = p[0], v1 = p[1];
    uint4 o;
    o.x = pk2bf(v0.x, v0.y);
    o.y = pk2bf(v0.z, v0.w);
    o.z = pk2bf(v1.x, v1.y);
    o.w = pk2bf(v1.z, v1.w);
    *(uint4*)(out + (n >> 3) * 8192 + k8 * 64 + (n & 7) * 8) = o;
  }
}

// small transposes (wg/wu/wd): in (Rr,Cc) fp32 (batch z) -> (Cc,Rr) bf16.
// TI=0 linear; TI=1: k ^= (row&7)<<3 (needs Rr==64).
template<int TI>
__global__ __launch_bounds__(256) void transpose_k(const float* __restrict__ in,
                                                   unsigned short* __restrict__ out,
                                                   int Rr, int Cc) {
  __shared__ unsigned short tile[32][33];
  const float* ib = in + (long)blockIdx.z * Rr * Cc;
  unsigned short* ob = out + (long)blockIdx.z * Rr * Cc;
  int r0 = blockIdx.y * 32, c0 = blockIdx.x * 32;
  int tr = threadIdx.x >> 5, tc = threadIdx.x & 31;
#pragma unroll
  for (int i = 0; i < 4; ++i) {
    int r = tr + i * 8;
    tile[r][tc] = f2bf(ib[(long)(r0 + r) * Cc + c0 + tc]);
  }
  __syncthreads();
#pragma unroll
  for (int i = 0; i < 4; ++i) {
    int c = tr + i * 8;
    int row = c0 + c;
    int k = r0 + tc;
    if (TI == 0) ob[(long)row * Rr + k] = tile[tc][c];
    else ob[(long)row * Rr + (k ^ ((row & 7) << 3))] = tile[tc][c];
  }
}

// big convert+transpose for pin/pout: in [Rr k][Cc n] fp32 -> out tiled bf16 [n][k].
__global__ __launch_bounds__(256) void trans_big_k(const float* __restrict__ in,
                                                   unsigned short* __restrict__ out,
                                                   int Rr, int Cc) {
  __shared__ float t[64][64];
  const float* ib = in + (long)blockIdx.z * Rr * Cc;
  unsigned short* ob = out + (long)blockIdx.z * (long)Rr * Cc;
  int k0 = blockIdx.y * 64, n0 = blockIdx.x * 64;
  int tid = threadIdx.x;
#pragma unroll
  for (int p = 0; p < 4; ++p) {
    int idx = p * 256 + tid;
    int kr = idx >> 4, nc = (idx & 15) * 4;
    *(float4*)&t[kr][nc] = *(const float4*)(ib + (long)(k0 + kr) * Cc + n0 + nc);
  }
  __syncthreads();
#pragma unroll
  for (int p = 0; p < 2; ++p) {
    int idx = p * 256 + tid;
    int n = idx & 63, kc = idx >> 6;       // kc 0..7
    float v[8];
#pragma unroll
    for (int u = 0; u < 8; ++u) v[u] = t[kc * 8 + u][n];
    uint4 o;
    o.x = pk2bf(v[0], v[1]); o.y = pk2bf(v[2], v[3]);
    o.z = pk2bf(v[4], v[5]); o.w = pk2bf(v[6], v[7]);
    *(uint4*)(ob + tiled_off(n0 + n, k0 + kc * 8, Rr)) = o;
  }
}

// GEMM1: mvB(bf16, linear [token][512]) = x @ Pin^T per expert. 256x256 tile, BK=64,
// quantum-pipelined (r10 structure).
__global__ __launch_bounds__(512, 1) void gemm_in_k(const unsigned short* __restrict__ Xb,
                                                    const unsigned short* __restrict__ Bw,
                                                    unsigned short* __restrict__ MvB,
                                                    const int* __restrict__ offs) {
  extern __shared__ char smem[];    // [2 buf][ A 32K | B 32K ], each op as 2 x 16K ksub
  int bid = blockIdx.x;             // 256 blocks
  int wg = (bid & 7) * 32 + (bid >> 3);      // XCD swizzle (256 % 8 == 0)
  int e = wg >> 4, rem = wg & 15, bm = rem >> 1, bn = rem & 1;
  int tid = threadIdx.x, wid = tid >> 6, lane = tid & 63;
  int wm = (wid >> 2) * 128, wn = (wid & 3) * 64;
  int ri = lane & 15, hi = lane >> 4;
  long aw = ((long)offs[e] >> 3) + bm * 32;  // A window base (xb tiled, K=1024)
  long bw = (long)e * 64 + bn * 32;          // B window base (pinT tiled, K=1024)

  auto STG = [&](int b, int kt, int s, int op) {
    const unsigned short* src = op ? Bw : Xb;
    long wbase = op ? bw : aw;
    char* dst = smem + b * 65536 + op * 32768 + s * 16384;
#pragma unroll
    for (int i = 0; i < 2; ++i) {
      int d = i * 512 + tid;
      async16(src + (wbase + (d >> 5)) * 8192 +
                  (long)((kt * 8 + s * 4 + ((d >> 3) & 3)) * 64 + (d & 7) * 8),
              (unsigned short*)(dst + d * 16));
    }
  };

  f32x4 acc[8][4];
#pragma unroll
  for (int i = 0; i < 8; ++i)
#pragma unroll
    for (int j = 0; j < 4; ++j) acc[i][j] = (f32x4){0.f, 0.f, 0.f, 0.f};

  STG(0, 0, 0, 0); STG(0, 0, 0, 1); STG(0, 0, 1, 0); STG(0, 0, 1, 1);

  for (int t = 0; t < 16; ++t) {
    int c = t & 1;
    const char* cA = smem + c * 65536;
    const char* cB = smem + c * 65536 + 32768;
#pragma unroll
    for (int s = 0; s < 2; ++s) {
      if (t < 15) {
        STG(c ^ 1, t + 1, s, 0);
        STG(c ^ 1, t + 1, s, 1);
        asm volatile("s_waitcnt vmcnt(8)" ::: "memory");
      } else if (s == 0) {
        asm volatile("s_waitcnt vmcnt(4)" ::: "memory");
      } else {
        asm volatile("s_waitcnt vmcnt(0)" ::: "memory");
      }
      sbar();
      bf16x8 a[8], b[4];
#pragma unroll
      for (int i = 0; i < 8; ++i) a[i] = ld_frag(cA + s * 16384, wm + i * 16 + ri, hi);
#pragma unroll
      for (int j = 0; j < 4; ++j) b[j] = ld_frag(cB + s * 16384, wn + j * 16 + ri, hi);
      __builtin_amdgcn_s_setprio(1);
#pragma unroll
      for (int i = 0; i < 8; ++i)
#pragma unroll
        for (int j = 0; j < 4; ++j)
          acc[i][j] = __builtin_amdgcn_mfma_f32_16x16x32_bf16(a[i], b[j], acc[i][j], 0, 0, 0);
      __builtin_amdgcn_s_setprio(0);
    }
  }

  unsigned short* Cb = MvB + ((long)e * 2048 + (long)bm * 256) * 512 + bn * 256;
#pragma unroll
  for (int i = 0; i < 8; ++i)
#pragma unroll
    for (int j = 0; j < 4; ++j)
#pragma unroll
      for (int rr = 0; rr < 4; ++rr)
        Cb[(long)(wm + i * 16 + hi * 4 + rr) * 512 + wn + j * 16 + ri] =
            f2bf1(acc[i][j][rr]);
}

// ---------- merged 2-round fused kernel: WAVE-INDEPENDENT tokens ----------
// 16 tokens/block, 512 threads = 8 waves; each wave owns 2 tokens END-TO-END
// (its P1 threads produce exactly the 16 flat-rows its GEMM tiles consume).
// Per quarter (F=64), a wave computes ALL 64 F for its 16 trows (4 zero-waste
// 16x16x32 MFMAs per gate/up k-half) and ALL 64 douts of the down-proj.
// => sFlat / sH / sMvh are all WAVE-PRIVATE (no barriers; same-wave DS order).
// Only Wg/Wu staging is cross-wave: single 16K buffer, 2 barriers/quarter:
//   [vm0;sbar] buffer ready -> read W frags -> [lgkm0;sbar] -> stage(next).
// LDS 48K total -> 3 blocks/CU (24 waves):
//   sFH  @0     16K: 8 waves x 2K  [16 row][128B] xor (row&7)<<4  (flat, then h)
//   sMvh @16K   16K: 8 waves x 2K  [2 tok][8 blade][128B] xor (blade)<<4
//   sWg  @32K    8K, sWu @40K 8K: quarter of Wg/Wu (swizzle baked in global)
// Wd read per-wave from global (L1-resident; proven 18MB FETCH in r0).
__global__ __launch_bounds__(512, 6) void rounds_k(
    const unsigned short* __restrict__ MvB, const unsigned short* __restrict__ WgT,
    const unsigned short* __restrict__ WuT, const unsigned short* __restrict__ WdT,
    const float* __restrict__ wcomb, const float* __restrict__ lnw,
    const float* __restrict__ lnb, unsigned short* __restrict__ Mvb) {
  extern __shared__ char smem[];
  int tid = threadIdx.x, wid = tid >> 6, lane = tid & 63;
  char* sFH = smem + wid * 2048;            // wave-private [16][128B]
  char* sMv = smem + 16384 + wid * 2048;    // wave-private [2 tok][1K]
  char* sWg = smem + 32768;                 // shared 8K
  char* sWu = smem + 40960;                 // shared 8K

  int bid = blockIdx.x;
  int wg = (bid & 7) * 256 + (bid >> 3);    // XCD swizzle (2048 % 8 == 0)
  int e = wg >> 7, bx = wg & 127;

  int t8 = lane >> 5, q = lane & 31;        // P1 coords: token-in-wave, d-pair
  int ri = lane & 15, hi = lane >> 4;       // frag coords
  int sw = (ri & 7) << 4;

  auto STAGE = [&](int ers, int qqs) {
    async16(WgT + (long)ers * 16384 + qqs * 4096 + tid * 8,
            (unsigned short*)(sWg + tid * 16));
    async16(WuT + (long)ers * 16384 + qqs * 4096 + tid * 8,
            (unsigned short*)(sWu + tid * 16));
  };
  STAGE(e * 2, 0);   // prologue: quarter 0 of round 0

#pragma unroll 1
  for (int r = 0; r < 2; ++r) {
    int er = e * 2 + r;
    const unsigned short* wd = WdT + (long)er * 16384;  // [64 dout][256 F]

    // ---- P1a: mv (global bf16 on r0 -> stash to sMvh; sMvh on r1) ----
    f32x2 mv[8];
    if (r == 0) {
      long base = ((long)e * 2048 + bx * 16 + wid * 2 + t8) * 512 + 2 * q;
      unsigned uv[8];
#pragma unroll
      for (int i = 0; i < 8; ++i)
        uv[i] = *(const unsigned*)(MvB + base + i * 64);
#pragma unroll
      for (int i = 0; i < 8; ++i) {
        *(unsigned*)(sMv + t8 * 1024 + i * 128 + ((4 * q) ^ (i << 4))) = uv[i];
        mv[i] = (f32x2){bf2f((unsigned short)(uv[i] & 0xffff)),
                        bf2f((unsigned short)(uv[i] >> 16))};
      }
    } else {
#pragma unroll
      for (int i = 0; i < 8; ++i) {
        unsigned uv = *(const unsigned*)(sMv + t8 * 1024 + i * 128 + ((4 * q) ^ (i << 4)));
        mv[i] = (f32x2){bf2f((unsigned short)(uv & 0xffff)),
                        bf2f((unsigned short)(uv >> 16))};
      }
    }

    // ---- P1b: geo + mix + LN(64) -> sFH (packed f32x2 math; wave-private) ----
    {
      const float* C = wcomb + er * 40;
      f32x2 g[8];
#pragma unroll
      for (int k = 0; k < 8; ++k) g[k] = (f32x2){0.f, 0.f};
#pragma unroll
      for (int i = 0; i < 8; ++i)
#pragma unroll
        for (int j = i; j < 8; ++j) {
          float cc = C[PIDX(i, j)];
          const int k = KIDX(i, j);
          g[k] += cc * (mv[i] * mv[j]);
        }
      float omg = C[36];
#pragma unroll
      for (int k = 0; k < 8; ++k) g[k] = omg * mv[k] + g[k];
      float2 lw = *(const float2*)(lnw + (long)er * 64 + 2 * q);
      float2 lb = *(const float2*)(lnb + (long)er * 64 + 2 * q);
      f32x2 lwv = (f32x2){lw.x, lw.y}, lbv = (f32x2){lb.x, lb.y};
#pragma unroll
      for (int half = 0; half < 2; ++half) {
        f32x2 red[4];
#pragma unroll
        for (int k = 0; k < 4; ++k) {
          f32x2 mx = g[half * 4 + k];
          red[k].x = mx.x + mx.y;
          red[k].y = fmaf(mx.x, mx.x, mx.y * mx.y);
        }
#pragma unroll
        for (int off = 16; off >= 1; off >>= 1)
#pragma unroll
          for (int t = 0; t < 4; ++t) {
            f32x2 o;
            o.x = __shfl_xor(red[t].x, off);
            o.y = __shfl_xor(red[t].y, off);
            red[t] += o;
          }
#pragma unroll
        for (int k = 0; k < 4; ++k) {
          int kk = half * 4 + k;
          float mean = red[k].x * (1.f / 64.f);
          float var = red[k].y * (1.f / 64.f) - mean * mean;
          float rs = rsqrtf(var + 1e-5f);
          f32x2 nv = (g[kk] - mean) * rs;
          f32x2 ov = nv * lwv + lbv;
          unsigned pv = pk2bf(ov.x, ov.y);
          int row = t8 * 8 + kk;                    // row&7 == kk
          *(unsigned*)(sFH + row * 128 + ((4 * q) ^ (kk << 4))) = pv;
        }
      }
    }
    wait_lgkm0();   // own-wave flat writes done (cross-LANE reads next)

    // ---- hoist flat B-frags to regs (sFH gets reused for h afterwards) ----
    bf16x8 bfr[2];
#pragma unroll
    for (int kt = 0; kt < 2; ++kt)
      bfr[kt] = *(const bf16x8*)(sFH + ri * 128 + ((kt * 64 + hi * 16) ^ sw));

    f32x4 acc2[4];
#pragma unroll
    for (int j = 0; j < 4; ++j) acc2[j] = (f32x4){0.f, 0.f, 0.f, 0.f};

#pragma unroll 1
    for (int qq = 0; qq < 4; ++qq) {
      wait_vm0();   // own stage asyncs landed
      sbar();       // everyone's landed -> sWg/sWu hold quarter qq

      // ---- P2: C[F-tile][trow=ri] = Wg/Wu-frag x flat(regs); silu -> sH ----
#pragma unroll 1
      for (int ft = 0; ft < 4; ++ft) {
        const char* bg = sWg + (ft * 16 + ri) * 128;
        const char* bu = sWu + (ft * 16 + ri) * 128;
        bf16x8 wg0 = *(const bf16x8*)(bg + ((0 * 64 + hi * 16) ^ sw));
        bf16x8 wg1 = *(const bf16x8*)(bg + ((1 * 64 + hi * 16) ^ sw));
        bf16x8 wu0 = *(const bf16x8*)(bu + ((0 * 64 + hi * 16) ^ sw));
        bf16x8 wu1 = *(const bf16x8*)(bu + ((1 * 64 + hi * 16) ^ sw));
        f32x4 ag = (f32x4){0.f, 0.f, 0.f, 0.f};
        f32x4 au = (f32x4){0.f, 0.f, 0.f, 0.f};
        __builtin_amdgcn_s_setprio(1);
        ag = __builtin_amdgcn_mfma_f32_16x16x32_bf16(wg0, bfr[0], ag, 0, 0, 0);
        au = __builtin_amdgcn_mfma_f32_16x16x32_bf16(wu0, bfr[0], au, 0, 0, 0);
        ag = __builtin_amdgcn_mfma_f32_16x16x32_bf16(wg1, bfr[1], ag, 0, 0, 0);
        au = __builtin_amdgcn_mfma_f32_16x16x32_bf16(wu1, bfr[1], au, 0, 0, 0);
        __builtin_amdgcn_s_setprio(0);
        float hh[4];
#pragma unroll
        for (int rr = 0; rr < 4; ++rr) {
          float gv = ag[rr], uu = au[rr];
          hh[rr] = gv * uu * frcp(1.f + __expf(-gv));
        }
        // h value (F' = ft*16+hi*4+rr, trow = ri) -> sFH[ri][F'] (swizzled)
        *(unsigned*)(sFH + ri * 128 + ((ft * 32 + hi * 8 + 0) ^ sw)) = pk2bf(hh[0], hh[1]);
        *(unsigned*)(sFH + ri * 128 + ((ft * 32 + hi * 8 + 4) ^ sw)) = pk2bf(hh[2], hh[3]);
      }
      wait_lgkm0();  // all own W-frag reads + h writes complete
      sbar();        // every wave done reading sWg/sWu -> safe to overwrite

      if (!(r == 1 && qq == 3)) {
        int nq = (qq + 1) & 3;
        STAGE(er + (qq == 3), nq);
      }

      // ---- Wd frags (global, per-wave; A-operand: m=dout, k=F) ----
      bf16x8 wdf[4][2];
#pragma unroll
      for (int j = 0; j < 4; ++j)
#pragma unroll
        for (int kg = 0; kg < 2; ++kg)
          wdf[j][kg] = *(const bf16x8*)(wd + (j * 16 + ri) * 256 + qq * 64 + kg * 32 + hi * 8);

      // ---- P4: acc2[dout][trow] += Wd x h (wave-private sH) ----
      bf16x8 h0 = *(const bf16x8*)(sFH + ri * 128 + ((0 * 64 + hi * 16) ^ sw));
      bf16x8 h1 = *(const bf16x8*)(sFH + ri * 128 + ((1 * 64 + hi * 16) ^ sw));
      __builtin_amdgcn_s_setprio(1);
#pragma unroll
      for (int j = 0; j < 4; ++j)
        acc2[j] = __builtin_amdgcn_mfma_f32_16x16x32_bf16(wdf[j][0], h0, acc2[j], 0, 0, 0);
#pragma unroll
      for (int j = 0; j < 4; ++j)
        acc2[j] = __builtin_amdgcn_mfma_f32_16x16x32_bf16(wdf[j][1], h1, acc2[j], 0, 0, 0);
      __builtin_amdgcn_s_setprio(0);
    }

    // ---- P5: residual vs sMvh (wave-private). r0 -> sMvh; r1 -> Mvb ----
    {
#pragma unroll
      for (int j = 0; j < 4; ++j)
#pragma unroll
        for (int u = 0; u < 2; ++u) {
          int off = (j * 32 + hi * 8 + 4 * u) ^ sw;
          unsigned* p = (unsigned*)(sMv + (ri >> 3) * 1024 + (ri & 7) * 128 + off);
          unsigned old = *p;
          float v0 = bf2f((unsigned short)(old & 0xffff)) + acc2[j][2 * u];
          float v1 = bf2f((unsigned short)(old >> 16)) + acc2[j][2 * u + 1];
          unsigned nv = pk2bf(v0, v1);
          if (r == 0) {
            *p = nv;
          } else {
            long row = (long)e * 2048 + bx * 16 + wid * 2 + (ri >> 3);
            *(unsigned*)(Mvb + row * 512 + (ri & 7) * 64 + j * 16 + hi * 4 + 2 * u) = nv;
          }
        }
    }
    wait_lgkm0();   // sMvh updates done before next round's P1a reads
  }
}

// ---------- fused out-projection + LayerNorm(D=1024), 512 threads/block ----------
// A (mvb) is LINEAR [token][512] bf16; tiled LDS layout derived via per-lane source addr.
__global__ __launch_bounds__(512, 2) void gemm_out_ln_k(
    const unsigned short* __restrict__ Mvb, const unsigned short* __restrict__ Pw,
    float* __restrict__ Out, const float* __restrict__ ow, const float* __restrict__ ob,
    const int* __restrict__ offs) {
  extern __shared__ char smem[];
  int bid = blockIdx.x;
  int wg = (bid & 7) * 64 + (bid >> 3);
  int e = wg >> 5, mb = wg & 31;
  int tid = threadIdx.x, wid = tid >> 6, lane = tid & 63;
  int ri = lane & 15, hi = lane >> 4;
  long bbase = (long)e * 524288;                 // poutT expert base (tiled)
  long arow0 = (long)e * 2048 + (long)mb * 64;   // mvb expert row base (linear)

  auto STAGE = [&](int buf, int kt) {
#pragma unroll
    for (int i = 0; i < 8; ++i) {
      int q = i * 512 + tid;
      int w = q >> 5, c = (q >> 3) & 3, rr = q & 7;
      async16(Pw + bbase + (long)w * 4096 + (kt * 4 + c) * 64 + rr * 8,
              (unsigned short*)(smem + buf * 65536 + q * 16));
    }
    if (tid < 256) {
      int q = tid;
      int w = q >> 5, c = (q >> 3) & 3, rr = q & 7;
      async16(Mvb + (arow0 + w * 8 + rr) * 512 + kt * 32 + c * 8,
              (unsigned short*)(smem + 131072 + buf * 4096 + q * 16));
    }
  };

  f32x4 acc[4][8];
#pragma unroll
  for (int i = 0; i < 4; ++i)
#pragma unroll
    for (int j = 0; j < 8; ++j) acc[i][j] = (f32x4){0.f, 0.f, 0.f, 0.f};

  STAGE(0, 0);
  for (int kt = 0; kt < 16; ++kt) {
    int cur = kt & 1;
    if (kt < 15) {
      STAGE(cur ^ 1, kt + 1);
      asm volatile("s_waitcnt vmcnt(8)" ::: "memory");
    } else {
      asm volatile("s_waitcnt vmcnt(0)" ::: "memory");
    }
    sbar();
    const char* cB = smem + cur * 65536;
    const char* cA = smem + 131072 + cur * 4096;
    bf16x8 a[4], b[8];
#pragma unroll
    for (int i = 0; i < 4; ++i) a[i] = ld_frag(cA, i * 16 + ri, hi);
#pragma unroll
    for (int j = 0; j < 8; ++j) b[j] = ld_frag(cB, wid * 128 + j * 16 + ri, hi);
    __builtin_amdgcn_s_setprio(1);
#pragma unroll
    for (int i = 0; i < 4; ++i)
#pragma unroll
      for (int j = 0; j < 8; ++j)
        acc[i][j] = __builtin_amdgcn_mfma_f32_16x16x32_bf16(a[i], b[j], acc[i][j], 0, 0, 0);
    __builtin_amdgcn_s_setprio(0);
    sbar();
  }

  float* rsum = (float*)(smem + 139264);
  float* rsq  = (float*)(smem + 141312);
  float* mexp = (float*)(smem + 143360);
  float* rstd = (float*)(smem + 143616);
  int hi4 = hi * 4;
#pragma unroll
  for (int i = 0; i < 4; ++i)
#pragma unroll
    for (int rr = 0; rr < 4; ++rr) {
      float s = 0.f, qv = 0.f;
#pragma unroll
      for (int j = 0; j < 8; ++j) { float v = acc[i][j][rr]; s += v; qv += v * v; }
#pragma unroll
      for (int off = 1; off < 16; off <<= 1) {
        s += __shfl_xor(s, off);
        qv += __shfl_xor(qv, off);
      }
      if (ri == 0) {
        int row = i * 16 + hi4 + rr;
        rsum[row * 8 + wid] = s;
        rsq[row * 8 + wid] = qv;
      }
    }
  __syncthreads();
  if (tid < 64) {
    float S = 0.f, Q = 0.f;
#pragma unroll
    for (int w = 0; w < 8; ++w) { S += rsum[tid * 8 + w]; Q += rsq[tid * 8 + w]; }
    float mean = S * (1.f / 1024.f);
    float var = Q * (1.f / 1024.f) - mean * mean;
    mexp[tid] = mean;
    rstd[tid] = rsqrtf(var + 1e-5f);
  }
  __syncthreads();
  long r0 = (long)offs[e] + (long)mb * 64;
  float owv[8], obv[8];
#pragma unroll
  for (int j = 0; j < 8; ++j) {
    int col = wid * 128 + j * 16 + ri;
    owv[j] = ow[col];
    obv[j] = ob[col];
  }
#pragma unroll
  for (int i = 0; i < 4; ++i)
#pragma unroll
    for (int rr = 0; rr < 4; ++rr) {
      int row = i * 16 + hi4 + rr;
      float mu = mexp[row], rs = rstd[row];
#pragma unroll
      for (int j = 0; j < 8; ++j) {
        int col = wid * 128 + j * 16 + ri;
        Out[(r0 + row) * 1024 + col] = (acc[i][j][rr] - mu) * rs * owv[j] + obv[j];
      }
    }
}

// ---------- host ----------
extern "C" void kernel_launch(void* const* d_in, const int* in_sizes, int n_in,
                              void* d_out, int out_size, void* d_ws, size_t ws_size,
                              hipStream_t stream) {
  const float* x    = (const float*)d_in[0];
  const float* pin  = (const float*)d_in[1];
  const float* pout = (const float*)d_in[2];
  const float* iw   = (const float*)d_in[3];
  const float* gg   = (const float*)d_in[4];
  const float* fg   = (const float*)d_in[5];
  const float* fu   = (const float*)d_in[6];
  const float* fd   = (const float*)d_in[7];
  const float* lnw  = (const float*)d_in[8];
  const float* lnb  = (const float*)d_in[9];
  const float* ow   = (const float*)d_in[10];
  const float* ob   = (const float*)d_in[11];
  const int* offs   = (const int*)d_in[12];

  char* ws = (char*)d_ws;
  unsigned short* mvB  = (unsigned short*)(ws + 0L);          //  33,554,432 B (linear bf16)
  unsigned short* mvb  = (unsigned short*)(ws + 33554432L);   //  33,554,432 B (linear bf16)
  unsigned short* pinT = (unsigned short*)(ws + 67108864L);   //  16,777,216 B (tiled)
  unsigned short* poutT= (unsigned short*)(ws + 83886080L);   //  16,777,216 B (tiled)
  unsigned short* wgT  = (unsigned short*)(ws + 100663296L);  //   2,097,152 B (swz-64)
  unsigned short* wuT  = (unsigned short*)(ws + 102760448L);  //   2,097,152 B (swz-64)
  unsigned short* wdT  = (unsigned short*)(ws + 104857600L);  //   2,097,152 B (plain)
  float* wcomb         = (float*)(ws + 106954752L);           //   5,120 B
  unsigned short* xb   = (unsigned short*)(ws + 117440512L);  //  67,108,864 B (tiled)

  // prep
  convert_k<<<dim3(4096), dim3(256), 0, stream>>>(x, xb, 4194304L);
  trans_big_k<<<dim3(8, 16, 16), dim3(256), 0, stream>>>(pin, pinT, 1024, 512);
  trans_big_k<<<dim3(16, 8, 16), dim3(256), 0, stream>>>(pout, poutT, 512, 1024);
  transpose_k<1><<<dim3(8, 2, 32), dim3(256), 0, stream>>>(fg, wgT, 64, 256);
  transpose_k<1><<<dim3(8, 2, 32), dim3(256), 0, stream>>>(fu, wuT, 64, 256);
  transpose_k<0><<<dim3(2, 8, 32), dim3(256), 0, stream>>>(fd, wdT, 256, 64);
  geoprep_k<<<dim3(1), dim3(64), 0, stream>>>(iw, gg, wcomb);

  // mvB = x @ Pin (bf16 linear out; 256x256 quantum-pipelined)
  gemm_in_k<<<dim3(256), dim3(512), 131072, stream>>>(xb, pinT, mvB, offs);

  // both rounds in ONE kernel; wave-independent tokens, 48K LDS -> 3 blocks/CU
  rounds_k<<<dim3(2048), dim3(512), 49152, stream>>>(
      mvB, wgT, wuT, wdT, wcomb, lnw, lnb, mvb);

  // out = LN(mvb @ Pout)
  gemm_out_ln_k<<<dim3(512), dim3(512), 143872, stream>>>(
      mvb, poutT, (float*)d_out, ow, ob, offs);
}

// Round 3
// 405.969 us; speedup vs baseline: 1.3173x; 1.1004x over previous
//
#include <hip/hip_runtime.h>

#define DEV __device__ __forceinline__

typedef __attribute__((ext_vector_type(4))) float f32x4;
typedef __attribute__((ext_vector_type(2))) float f32x2;
typedef __attribute__((ext_vector_type(8))) short bf16x8;

// Shapes: E=16, D=1024, ED=512, NB=8, DB=64, R=2, F=256, N=32768, C=2048

// ---------- helpers ----------
DEV unsigned short f2bf(float f) {
  union { float f; unsigned u; } v; v.f = f;
  unsigned r = v.u + 0x7fffu + ((v.u >> 16) & 1u);
  return (unsigned short)(r >> 16);
}

DEV unsigned pk2bf(float lo, float hi) {  // v_cvt_pk_bf16_f32 (RNE)
  unsigned r;
  asm("v_cvt_pk_bf16_f32 %0, %1, %2" : "=v"(r) : "v"(lo), "v"(hi));
  return r;
}
DEV unsigned short f2bf1(float v) { return (unsigned short)pk2bf(v, v); }

DEV float bf2f(unsigned short b) {
  union { unsigned u; float f; } v; v.u = ((unsigned)b) << 16; return v.f;
}

DEV float frcp(float x) { return __builtin_amdgcn_rcpf(x); }

// raw barrier: NO implicit vmcnt drain. "memory" clobber = compiler fence.
DEV void sbar() { asm volatile("s_barrier" ::: "memory"); }
DEV void wait_lgkm0() { asm volatile("s_waitcnt lgkmcnt(0)" ::: "memory"); }
DEV void wait_vm0() { asm volatile("s_waitcnt vmcnt(0)" ::: "memory"); }

DEV void async16(const unsigned short* g, unsigned short* l) {
  __builtin_amdgcn_global_load_lds(
      (__attribute__((address_space(1))) const unsigned int*)g,
      (__attribute__((address_space(3))) unsigned int*)l, 16, 0, 0);
}

// Tiled global layout for GEMM operands: element (n,k) of an [N][K] panel at
//   (n>>3)*8K + (k>>3)*64 + (n&7)*8 + (k&7)
DEV long tiled_off(long n, int k, int K) {
  return (n >> 3) * (8L * K) + (long)(((k >> 3) * 64) + ((int)(n & 7)) * 8 + (k & 7));
}

// frag read from a tiled 32-k LDS subtile (bf16)
DEV bf16x8 ld_frag(const char* s, int row, int hi) {
  return *(const bf16x8*)(s + ((row >> 3) * 512 + hi * 128 + (row & 7) * 16));
}

// ---------- Cayley table at compile time ----------
__host__ __device__ constexpr int km_(int i) { return i==0?0:i==1?1:i==2?2:i==3?4:i==4?3:i==5?5:i==6?6:7; }
__host__ __device__ constexpr int pc_(int x) { int c = 0; while (x) { c += x & 1; x >>= 1; } return c; }
__host__ __device__ constexpr int KIDX(int i, int j) { return km_(km_(i) ^ km_(j)); }
__host__ __device__ constexpr int CSGN(int i, int j) {
  int a = km_(i), b = km_(j), aa = a >> 1, s = 0;
  while (aa) { s += pc_(aa & b); aa >>= 1; }
  return (s & 1) ? -1 : 1;
}
__host__ __device__ constexpr int PIDX(int i, int j) {  // i<=j
  return 8 * i - (i * (i - 1)) / 2 + (j - i);
}

// ---------- small kernels ----------
__global__ __launch_bounds__(64) void geoprep_k(const float* __restrict__ iw,
                                                const float* __restrict__ gg,
                                                float* __restrict__ wcomb) {
  int er = threadIdx.x;
  if (er >= 32) return;
  const float* w = iw + er * 64;
  float gate = frcp(1.f + __expf(-gg[er]));
  float* c = wcomb + er * 40;
  int p = 0;
  for (int i = 0; i < 8; ++i)
    for (int j = i; j < 8; ++j) {
      float v = (float)CSGN(i, j) * frcp(1.f + __expf(-w[i * 8 + j]));
      if (j > i) v += (float)CSGN(j, i) * frcp(1.f + __expf(-w[j * 8 + i]));
      c[p++] = gate * v;
    }
  c[36] = 1.f - gate;
}

// x fp32 [32768][1024] -> xb bf16 in tiled layout (K=1024).
__global__ __launch_bounds__(256) void convert_k(const float* __restrict__ in,
                                                 unsigned short* __restrict__ out,
                                                 long nchunks) {
  long q = (long)blockIdx.x * 256 + threadIdx.x;
  long stride = (long)gridDim.x * 256;
  for (; q < nchunks; q += stride) {
    long n = q >> 7;
    int k8 = (int)(q & 127);
    const float4* p = (const float4*)(in + n * 1024 + k8 * 8);
    float4 v0 = p[0], v1 = p[1];
    uint4 o;
    o.x = pk2bf(v0.x, v0.y);
    o.y = pk2bf(v0.z, v0.w);
    o.z = pk2bf(v1.x, v1.y);
    o.w = pk2bf(v1.z, v1.w);
    *(uint4*)(out + (n >> 3) * 8192 + k8 * 64 + (n & 7) * 8) = o;
  }
}

// small transposes (wg/wu/wd): in (Rr,Cc) fp32 (batch z) -> (Cc,Rr) bf16.
// TI=0 linear; TI=1: k ^= (row&7)<<3 (needs Rr==64).
template<int TI>
__global__ __launch_bounds__(256) void transpose_k(const float* __restrict__ in,
                                                   unsigned short* __restrict__ out,
                                                   int Rr, int Cc) {
  __shared__ unsigned short tile[32][33];
  const float* ib = in + (long)blockIdx.z * Rr * Cc;
  unsigned short* ob = out + (long)blockIdx.z * Rr * Cc;
  int r0 = blockIdx.y * 32, c0 = blockIdx.x * 32;
  int tr = threadIdx.x >> 5, tc = threadIdx.x & 31;
#pragma unroll
  for (int i = 0; i < 4; ++i) {
    int r = tr + i * 8;
    tile[r][tc] = f2bf(ib[(long)(r0 + r) * Cc + c0 + tc]);
  }
  __syncthreads();
#pragma unroll
  for (int i = 0; i < 4; ++i) {
    int c = tr + i * 8;
    int row = c0 + c;
    int k = r0 + tc;
    if (TI == 0) ob[(long)row * Rr + k] = tile[tc][c];
    else ob[(long)row * Rr + (k ^ ((row & 7) << 3))] = tile[tc][c];
  }
}

// big convert+transpose for pin/pout: in [Rr k][Cc n] fp32 -> out tiled bf16 [n][k].
__global__ __launch_bounds__(256) void trans_big_k(const float* __restrict__ in,
                                                   unsigned short* __restrict__ out,
                                                   int Rr, int Cc) {
  __shared__ float t[64][64];
  const float* ib = in + (long)blockIdx.z * Rr * Cc;
  unsigned short* ob = out + (long)blockIdx.z * (long)Rr * Cc;
  int k0 = blockIdx.y * 64, n0 = blockIdx.x * 64;
  int tid = threadIdx.x;
#pragma unroll
  for (int p = 0; p < 4; ++p) {
    int idx = p * 256 + tid;
    int kr = idx >> 4, nc = (idx & 15) * 4;
    *(float4*)&t[kr][nc] = *(const float4*)(ib + (long)(k0 + kr) * Cc + n0 + nc);
  }
  __syncthreads();
#pragma unroll
  for (int p = 0; p < 2; ++p) {
    int idx = p * 256 + tid;
    int n = idx & 63, kc = idx >> 6;       // kc 0..7
    float v[8];
#pragma unroll
    for (int u = 0; u < 8; ++u) v[u] = t[kc * 8 + u][n];
    uint4 o;
    o.x = pk2bf(v[0], v[1]); o.y = pk2bf(v[2], v[3]);
    o.z = pk2bf(v[4], v[5]); o.w = pk2bf(v[6], v[7]);
    *(uint4*)(ob + tiled_off(n0 + n, k0 + kc * 8, Rr)) = o;
  }
}

// GEMM1: mvB(bf16, linear [token][512]) = x @ Pin^T per expert. 256x256 tile, BK=64,
// quantum-pipelined (r10 structure).
__global__ __launch_bounds__(512, 1) void gemm_in_k(const unsigned short* __restrict__ Xb,
                                                    const unsigned short* __restrict__ Bw,
                                                    unsigned short* __restrict__ MvB,
                                                    const int* __restrict__ offs) {
  extern __shared__ char smem[];    // [2 buf][ A 32K | B 32K ], each op as 2 x 16K ksub
  int bid = blockIdx.x;             // 256 blocks
  int wg = (bid & 7) * 32 + (bid >> 3);      // XCD swizzle (256 % 8 == 0)
  int e = wg >> 4, rem = wg & 15, bm = rem >> 1, bn = rem & 1;
  int tid = threadIdx.x, wid = tid >> 6, lane = tid & 63;
  int wm = (wid >> 2) * 128, wn = (wid & 3) * 64;
  int ri = lane & 15, hi = lane >> 4;
  long aw = ((long)offs[e] >> 3) + bm * 32;  // A window base (xb tiled, K=1024)
  long bw = (long)e * 64 + bn * 32;          // B window base (pinT tiled, K=1024)

  auto STG = [&](int b, int kt, int s, int op) {
    const unsigned short* src = op ? Bw : Xb;
    long wbase = op ? bw : aw;
    char* dst = smem + b * 65536 + op * 32768 + s * 16384;
#pragma unroll
    for (int i = 0; i < 2; ++i) {
      int d = i * 512 + tid;
      async16(src + (wbase + (d >> 5)) * 8192 +
                  (long)((kt * 8 + s * 4 + ((d >> 3) & 3)) * 64 + (d & 7) * 8),
              (unsigned short*)(dst + d * 16));
    }
  };

  f32x4 acc[8][4];
#pragma unroll
  for (int i = 0; i < 8; ++i)
#pragma unroll
    for (int j = 0; j < 4; ++j) acc[i][j] = (f32x4){0.f, 0.f, 0.f, 0.f};

  STG(0, 0, 0, 0); STG(0, 0, 0, 1); STG(0, 0, 1, 0); STG(0, 0, 1, 1);

  for (int t = 0; t < 16; ++t) {
    int c = t & 1;
    const char* cA = smem + c * 65536;
    const char* cB = smem + c * 65536 + 32768;
#pragma unroll
    for (int s = 0; s < 2; ++s) {
      if (t < 15) {
        STG(c ^ 1, t + 1, s, 0);
        STG(c ^ 1, t + 1, s, 1);
        asm volatile("s_waitcnt vmcnt(8)" ::: "memory");
      } else if (s == 0) {
        asm volatile("s_waitcnt vmcnt(4)" ::: "memory");
      } else {
        asm volatile("s_waitcnt vmcnt(0)" ::: "memory");
      }
      sbar();
      bf16x8 a[8], b[4];
#pragma unroll
      for (int i = 0; i < 8; ++i) a[i] = ld_frag(cA + s * 16384, wm + i * 16 + ri, hi);
#pragma unroll
      for (int j = 0; j < 4; ++j) b[j] = ld_frag(cB + s * 16384, wn + j * 16 + ri, hi);
      __builtin_amdgcn_s_setprio(1);
#pragma unroll
      for (int i = 0; i < 8; ++i)
#pragma unroll
        for (int j = 0; j < 4; ++j)
          acc[i][j] = __builtin_amdgcn_mfma_f32_16x16x32_bf16(a[i], b[j], acc[i][j], 0, 0, 0);
      __builtin_amdgcn_s_setprio(0);
    }
  }

  unsigned short* Cb = MvB + ((long)e * 2048 + (long)bm * 256) * 512 + bn * 256;
#pragma unroll
  for (int i = 0; i < 8; ++i)
#pragma unroll
    for (int j = 0; j < 4; ++j)
#pragma unroll
      for (int rr = 0; rr < 4; ++rr)
        Cb[(long)(wm + i * 16 + hi * 4 + rr) * 512 + wn + j * 16 + ri] =
            f2bf1(acc[i][j][rr]);
}

// ---------- merged 2-round fused kernel: WAVE-INDEPENDENT tokens ----------
// 8 tokens/block, 256 threads = 4 waves; each wave owns 2 tokens END-TO-END.
// Per quarter (F=64), a wave computes ALL 64 F for its 16 trows and the full
// down-proj partial. sFlat/sH/sMvh are WAVE-PRIVATE (no barriers; same-wave
// DS order). Only the Wg/Wu quarter stage is cross-wave: single 16K buffer,
// 2 barriers/quarter: [vm0;sbar] ready -> read W frags -> [lgkm0;sbar] ->
// stage(next quarter) hides under P4 (+P5/P1 at round boundary).
// LDS 32K/block -> 5 blocks/CU (20 waves, 62.5% cap) with VGPR budget ~102
// at __launch_bounds__(256,5) -> no spill (round-1/2 lesson: (512,6)'s ~85
// budget spilled -> 120-160MB scratch writes).
//   sFH  @0      8K: 4 waves x 2K  [16 row][128B] xor (row&7)<<4 (flat, then h)
//   sMvh @8K     8K: 4 waves x 2K  [2 tok][8 blade][128B] xor (blade)<<4
//   sWg  @16K    8K, sWu @24K 8K: quarter of Wg/Wu (swizzle baked in global)
// Wd read per-wave from global (L1/L2-resident). Mvb written via coalesced
// uint4 epilogue from sMvh (r2 lesson: avoid scattered 4B stores).
__global__ __launch_bounds__(256, 5) void rounds_k(
    const unsigned short* __restrict__ MvB, const unsigned short* __restrict__ WgT,
    const unsigned short* __restrict__ WuT, const unsigned short* __restrict__ WdT,
    const float* __restrict__ wcomb, const float* __restrict__ lnw,
    const float* __restrict__ lnb, unsigned short* __restrict__ Mvb) {
  extern __shared__ char smem[];
  int tid = threadIdx.x, wid = tid >> 6, lane = tid & 63;
  char* sFH = smem + wid * 2048;            // wave-private [16][128B]
  char* sMv = smem + 8192 + wid * 2048;     // wave-private [2 tok][1K]
  char* sWg = smem + 16384;                 // shared 8K
  char* sWu = smem + 24576;                 // shared 8K

  int bid = blockIdx.x;
  int wg = (bid & 7) * 512 + (bid >> 3);    // XCD swizzle (4096 % 8 == 0)
  int e = wg >> 8, bx = wg & 255;

  int t8 = lane >> 5, q = lane & 31;        // P1 coords: token-in-wave, d-pair
  int ri = lane & 15, hi = lane >> 4;       // frag coords
  int sw = (ri & 7) << 4;

  auto STAGE = [&](int ers, int qqs) {
    long base = (long)ers * 16384 + qqs * 4096;
    async16(WgT + base + tid * 8, (unsigned short*)(sWg + tid * 16));
    async16(WgT + base + 2048 + tid * 8, (unsigned short*)(sWg + 4096 + tid * 16));
    async16(WuT + base + tid * 8, (unsigned short*)(sWu + tid * 16));
    async16(WuT + base + 2048 + tid * 8, (unsigned short*)(sWu + 4096 + tid * 16));
  };
  STAGE(e * 2, 0);   // prologue: quarter 0 of round 0

#pragma unroll 1
  for (int r = 0; r < 2; ++r) {
    int er = e * 2 + r;
    const unsigned short* wd = WdT + (long)er * 16384;  // [64 dout][256 F]

    // ---- P1a: mv (global bf16 on r0 -> stash to sMvh; sMvh on r1) ----
    f32x2 mv[8];
    if (r == 0) {
      long base = ((long)e * 2048 + bx * 8 + wid * 2 + t8) * 512 + 2 * q;
      unsigned uv[8];
#pragma unroll
      for (int i = 0; i < 8; ++i)
        uv[i] = *(const unsigned*)(MvB + base + i * 64);
#pragma unroll
      for (int i = 0; i < 8; ++i) {
        *(unsigned*)(sMv + t8 * 1024 + i * 128 + ((4 * q) ^ (i << 4))) = uv[i];
        mv[i] = (f32x2){bf2f((unsigned short)(uv[i] & 0xffff)),
                        bf2f((unsigned short)(uv[i] >> 16))};
      }
    } else {
#pragma unroll
      for (int i = 0; i < 8; ++i) {
        unsigned uv = *(const unsigned*)(sMv + t8 * 1024 + i * 128 + ((4 * q) ^ (i << 4)));
        mv[i] = (f32x2){bf2f((unsigned short)(uv & 0xffff)),
                        bf2f((unsigned short)(uv >> 16))};
      }
    }

    // ---- P1b: geo + mix + LN(64) -> sFH (packed f32x2 math; wave-private) ----
    {
      const float* C = wcomb + er * 40;
      f32x2 g[8];
#pragma unroll
      for (int k = 0; k < 8; ++k) g[k] = (f32x2){0.f, 0.f};
#pragma unroll
      for (int i = 0; i < 8; ++i)
#pragma unroll
        for (int j = i; j < 8; ++j) {
          float cc = C[PIDX(i, j)];
          const int k = KIDX(i, j);
          g[k] += cc * (mv[i] * mv[j]);
        }
      float omg = C[36];
#pragma unroll
      for (int k = 0; k < 8; ++k) g[k] = omg * mv[k] + g[k];
      float2 lw = *(const float2*)(lnw + (long)er * 64 + 2 * q);
      float2 lb = *(const float2*)(lnb + (long)er * 64 + 2 * q);
      f32x2 lwv = (f32x2){lw.x, lw.y}, lbv = (f32x2){lb.x, lb.y};
#pragma unroll
      for (int half = 0; half < 2; ++half) {
        f32x2 red[4];
#pragma unroll
        for (int k = 0; k < 4; ++k) {
          f32x2 mx = g[half * 4 + k];
          red[k].x = mx.x + mx.y;
          red[k].y = fmaf(mx.x, mx.x, mx.y * mx.y);
        }
#pragma unroll
        for (int off = 16; off >= 1; off >>= 1)
#pragma unroll
          for (int t = 0; t < 4; ++t) {
            f32x2 o;
            o.x = __shfl_xor(red[t].x, off);
            o.y = __shfl_xor(red[t].y, off);
            red[t] += o;
          }
#pragma unroll
        for (int k = 0; k < 4; ++k) {
          int kk = half * 4 + k;
          float mean = red[k].x * (1.f / 64.f);
          float var = red[k].y * (1.f / 64.f) - mean * mean;
          float rs = rsqrtf(var + 1e-5f);
          f32x2 nv = (g[kk] - mean) * rs;
          f32x2 ov = nv * lwv + lbv;
          unsigned pv = pk2bf(ov.x, ov.y);
          int row = t8 * 8 + kk;                    // row&7 == kk
          *(unsigned*)(sFH + row * 128 + ((4 * q) ^ (kk << 4))) = pv;
        }
      }
    }
    wait_lgkm0();   // own-wave flat writes done (cross-LANE reads next)

    // ---- hoist flat B-frags to regs (sFH gets reused for h afterwards) ----
    bf16x8 bfr[2];
#pragma unroll
    for (int kt = 0; kt < 2; ++kt)
      bfr[kt] = *(const bf16x8*)(sFH + ri * 128 + ((kt * 64 + hi * 16) ^ sw));

    f32x4 acc2[4];
#pragma unroll
    for (int j = 0; j < 4; ++j) acc2[j] = (f32x4){0.f, 0.f, 0.f, 0.f};

#pragma unroll 1
    for (int qq = 0; qq < 4; ++qq) {
      wait_vm0();   // own stage asyncs landed
      sbar();       // everyone's landed -> sWg/sWu hold quarter qq

      // ---- P2: C[F-tile][trow=ri] = Wg/Wu-frag x flat(regs); silu -> sH ----
#pragma unroll 1
      for (int ft = 0; ft < 4; ++ft) {
        const char* bg = sWg + (ft * 16 + ri) * 128;
        const char* bu = sWu + (ft * 16 + ri) * 128;
        f32x4 ag = (f32x4){0.f, 0.f, 0.f, 0.f};
        f32x4 au = (f32x4){0.f, 0.f, 0.f, 0.f};
        {
          bf16x8 wg0 = *(const bf16x8*)(bg + ((hi * 16) ^ sw));
          bf16x8 wu0 = *(const bf16x8*)(bu + ((hi * 16) ^ sw));
          __builtin_amdgcn_s_setprio(1);
          ag = __builtin_amdgcn_mfma_f32_16x16x32_bf16(wg0, bfr[0], ag, 0, 0, 0);
          au = __builtin_amdgcn_mfma_f32_16x16x32_bf16(wu0, bfr[0], au, 0, 0, 0);
          __builtin_amdgcn_s_setprio(0);
        }
        {
          bf16x8 wg1 = *(const bf16x8*)(bg + ((64 + hi * 16) ^ sw));
          bf16x8 wu1 = *(const bf16x8*)(bu + ((64 + hi * 16) ^ sw));
          __builtin_amdgcn_s_setprio(1);
          ag = __builtin_amdgcn_mfma_f32_16x16x32_bf16(wg1, bfr[1], ag, 0, 0, 0);
          au = __builtin_amdgcn_mfma_f32_16x16x32_bf16(wu1, bfr[1], au, 0, 0, 0);
          __builtin_amdgcn_s_setprio(0);
        }
        float hh[4];
#pragma unroll
        for (int rr = 0; rr < 4; ++rr) {
          float gv = ag[rr], uu = au[rr];
          hh[rr] = gv * uu * frcp(1.f + __expf(-gv));
        }
        // h value (F' = ft*16+hi*4+rr, trow = ri) -> sFH[ri][F'] (swizzled)
        *(unsigned*)(sFH + ri * 128 + ((ft * 32 + hi * 8 + 0) ^ sw)) = pk2bf(hh[0], hh[1]);
        *(unsigned*)(sFH + ri * 128 + ((ft * 32 + hi * 8 + 4) ^ sw)) = pk2bf(hh[2], hh[3]);
      }
      wait_lgkm0();  // all own W-frag reads + h writes complete
      sbar();        // every wave done reading sWg/sWu -> safe to overwrite

      if (!(r == 1 && qq == 3)) {
        int nq = (qq + 1) & 3;
        STAGE(er + (qq == 3), nq);
      }

      // ---- P4: acc2[dout][trow] += Wd x h, split in 2 k-halves (reg cap) ----
#pragma unroll
      for (int kg = 0; kg < 2; ++kg) {
        bf16x8 wdf[4];
#pragma unroll
        for (int j = 0; j < 4; ++j)
          wdf[j] = *(const bf16x8*)(wd + (j * 16 + ri) * 256 + qq * 64 + kg * 32 + hi * 8);
        bf16x8 hk = *(const bf16x8*)(sFH + ri * 128 + ((kg * 64 + hi * 16) ^ sw));
        __builtin_amdgcn_s_setprio(1);
#pragma unroll
        for (int j = 0; j < 4; ++j)
          acc2[j] = __builtin_amdgcn_mfma_f32_16x16x32_bf16(wdf[j], hk, acc2[j], 0, 0, 0);
        __builtin_amdgcn_s_setprio(0);
      }
    }

    // ---- P5: residual vs sMvh (wave-private, in place both rounds) ----
    {
#pragma unroll
      for (int j = 0; j < 4; ++j)
#pragma unroll
        for (int u = 0; u < 2; ++u) {
          int off = (j * 32 + hi * 8 + 4 * u) ^ sw;
          unsigned* p = (unsigned*)(sMv + (ri >> 3) * 1024 + (ri & 7) * 128 + off);
          unsigned old = *p;
          float v0 = bf2f((unsigned short)(old & 0xffff)) + acc2[j][2 * u];
          float v1 = bf2f((unsigned short)(old >> 16)) + acc2[j][2 * u + 1];
          *p = pk2bf(v0, v1);
        }
    }
    wait_lgkm0();   // sMvh updates done (next round's P1a / epilogue reads)

    // ---- r1: coalesced uint4 dump sMvh -> Mvb (linear [token][512]) ----
    if (r == 1) {
      int tt = lane >> 5;              // token-in-wave
      int bl = (lane & 31) >> 2;       // blade 0..7
      int cc = lane & 3;               // 32B chunk 0..3
      const char* src = sMv + tt * 1024 + bl * 128;
      long row = (long)e * 2048 + bx * 8 + wid * 2 + tt;
      unsigned short* dst = Mvb + row * 512 + bl * 64 + cc * 16;
#pragma unroll
      for (int h = 0; h < 2; ++h) {
        uint4 v = *(const uint4*)(src + ((cc * 32 + h * 16) ^ (bl << 4)));
        *(uint4*)(dst + h * 8) = v;
      }
    }
  }
}

// ---------- fused out-projection + LayerNorm(D=1024), 512 threads/block ----------
// A (mvb) is LINEAR [token][512] bf16; tiled LDS layout derived via per-lane source addr.
__global__ __launch_bounds__(512, 2) void gemm_out_ln_k(
    const unsigned short* __restrict__ Mvb, const unsigned short* __restrict__ Pw,
    float* __restrict__ Out, const float* __restrict__ ow, const float* __restrict__ ob,
    const int* __restrict__ offs) {
  extern __shared__ char smem[];
  int bid = blockIdx.x;
  int wg = (bid & 7) * 64 + (bid >> 3);
  int e = wg >> 5, mb = wg & 31;
  int tid = threadIdx.x, wid = tid >> 6, lane = tid & 63;
  int ri = lane & 15, hi = lane >> 4;
  long bbase = (long)e * 524288;                 // poutT expert base (tiled)
  long arow0 = (long)e * 2048 + (long)mb * 64;   // mvb expert row base (linear)

  auto STAGE = [&](int buf, int kt) {
#pragma unroll
    for (int i = 0; i < 8; ++i) {
      int q = i * 512 + tid;
      int w = q >> 5, c = (q >> 3) & 3, rr = q & 7;
      async16(Pw + bbase + (long)w * 4096 + (kt * 4 + c) * 64 + rr * 8,
              (unsigned short*)(smem + buf * 65536 + q * 16));
    }
    if (tid < 256) {
      int q = tid;
      int w = q >> 5, c = (q >> 3) & 3, rr = q & 7;
      async16(Mvb + (arow0 + w * 8 + rr) * 512 + kt * 32 + c * 8,
              (unsigned short*)(smem + 131072 + buf * 4096 + q * 16));
    }
  };

  f32x4 acc[4][8];
#pragma unroll
  for (int i = 0; i < 4; ++i)
#pragma unroll
    for (int j = 0; j < 8; ++j) acc[i][j] = (f32x4){0.f, 0.f, 0.f, 0.f};

  STAGE(0, 0);
  for (int kt = 0; kt < 16; ++kt) {
    int cur = kt & 1;
    if (kt < 15) {
      STAGE(cur ^ 1, kt + 1);
      asm volatile("s_waitcnt vmcnt(8)" ::: "memory");
    } else {
      asm volatile("s_waitcnt vmcnt(0)" ::: "memory");
    }
    sbar();
    const char* cB = smem + cur * 65536;
    const char* cA = smem + 131072 + cur * 4096;
    bf16x8 a[4], b[8];
#pragma unroll
    for (int i = 0; i < 4; ++i) a[i] = ld_frag(cA, i * 16 + ri, hi);
#pragma unroll
    for (int j = 0; j < 8; ++j) b[j] = ld_frag(cB, wid * 128 + j * 16 + ri, hi);
    __builtin_amdgcn_s_setprio(1);
#pragma unroll
    for (int i = 0; i < 4; ++i)
#pragma unroll
      for (int j = 0; j < 8; ++j)
        acc[i][j] = __builtin_amdgcn_mfma_f32_16x16x32_bf16(a[i], b[j], acc[i][j], 0, 0, 0);
    __builtin_amdgcn_s_setprio(0);
    sbar();
  }

  float* rsum = (float*)(smem + 139264);
  float* rsq  = (float*)(smem + 141312);
  float* mexp = (float*)(smem + 143360);
  float* rstd = (float*)(smem + 143616);
  int hi4 = hi * 4;
#pragma unroll
  for (int i = 0; i < 4; ++i)
#pragma unroll
    for (int rr = 0; rr < 4; ++rr) {
      float s = 0.f, qv = 0.f;
#pragma unroll
      for (int j = 0; j < 8; ++j) { float v = acc[i][j][rr]; s += v; qv += v * v; }
#pragma unroll
      for (int off = 1; off < 16; off <<= 1) {
        s += __shfl_xor(s, off);
        qv += __shfl_xor(qv, off);
      }
      if (ri == 0) {
        int row = i * 16 + hi4 + rr;
        rsum[row * 8 + wid] = s;
        rsq[row * 8 + wid] = qv;
      }
    }
  __syncthreads();
  if (tid < 64) {
    float S = 0.f, Q = 0.f;
#pragma unroll
    for (int w = 0; w < 8; ++w) { S += rsum[tid * 8 + w]; Q += rsq[tid * 8 + w]; }
    float mean = S * (1.f / 1024.f);
    float var = Q * (1.f / 1024.f) - mean * mean;
    mexp[tid] = mean;
    rstd[tid] = rsqrtf(var + 1e-5f);
  }
  __syncthreads();
  long r0 = (long)offs[e] + (long)mb * 64;
  float owv[8], obv[8];
#pragma unroll
  for (int j = 0; j < 8; ++j) {
    int col = wid * 128 + j * 16 + ri;
    owv[j] = ow[col];
    obv[j] = ob[col];
  }
#pragma unroll
  for (int i = 0; i < 4; ++i)
#pragma unroll
    for (int rr = 0; rr < 4; ++rr) {
      int row = i * 16 + hi4 + rr;
      float mu = mexp[row], rs = rstd[row];
#pragma unroll
      for (int j = 0; j < 8; ++j) {
        int col = wid * 128 + j * 16 + ri;
        Out[(r0 + row) * 1024 + col] = (acc[i][j][rr] - mu) * rs * owv[j] + obv[j];
      }
    }
}

// ---------- host ----------
extern "C" void kernel_launch(void* const* d_in, const int* in_sizes, int n_in,
                              void* d_out, int out_size, void* d_ws, size_t ws_size,
                              hipStream_t stream) {
  const float* x    = (const float*)d_in[0];
  const float* pin  = (const float*)d_in[1];
  const float* pout = (const float*)d_in[2];
  const float* iw   = (const float*)d_in[3];
  const float* gg   = (const float*)d_in[4];
  const float* fg   = (const float*)d_in[5];
  const float* fu   = (const float*)d_in[6];
  const float* fd   = (const float*)d_in[7];
  const float* lnw  = (const float*)d_in[8];
  const float* lnb  = (const float*)d_in[9];
  const float* ow   = (const float*)d_in[10];
  const float* ob   = (const float*)d_in[11];
  const int* offs   = (const int*)d_in[12];

  char* ws = (char*)d_ws;
  unsigned short* mvB  = (unsigned short*)(ws + 0L);          //  33,554,432 B (linear bf16)
  unsigned short* mvb  = (unsigned short*)(ws + 33554432L);   //  33,554,432 B (linear bf16)
  unsigned short* pinT = (unsigned short*)(ws + 67108864L);   //  16,777,216 B (tiled)
  unsigned short* poutT= (unsigned short*)(ws + 83886080L);   //  16,777,216 B (tiled)
  unsigned short* wgT  = (unsigned short*)(ws + 100663296L);  //   2,097,152 B (swz-64)
  unsigned short* wuT  = (unsigned short*)(ws + 102760448L);  //   2,097,152 B (swz-64)
  unsigned short* wdT  = (unsigned short*)(ws + 104857600L);  //   2,097,152 B (plain)
  float* wcomb         = (float*)(ws + 106954752L);           //   5,120 B
  unsigned short* xb   = (unsigned short*)(ws + 117440512L);  //  67,108,864 B (tiled)

  // prep
  convert_k<<<dim3(4096), dim3(256), 0, stream>>>(x, xb, 4194304L);
  trans_big_k<<<dim3(8, 16, 16), dim3(256), 0, stream>>>(pin, pinT, 1024, 512);
  trans_big_k<<<dim3(16, 8, 16), dim3(256), 0, stream>>>(pout, poutT, 512, 1024);
  transpose_k<1><<<dim3(8, 2, 32), dim3(256), 0, stream>>>(fg, wgT, 64, 256);
  transpose_k<1><<<dim3(8, 2, 32), dim3(256), 0, stream>>>(fu, wuT, 64, 256);
  transpose_k<0><<<dim3(2, 8, 32), dim3(256), 0, stream>>>(fd, wdT, 256, 64);
  geoprep_k<<<dim3(1), dim3(64), 0, stream>>>(iw, gg, wcomb);

  // mvB = x @ Pin (bf16 linear out; 256x256 quantum-pipelined)
  gemm_in_k<<<dim3(256), dim3(512), 131072, stream>>>(xb, pinT, mvB, offs);

  // both rounds in ONE kernel; wave-independent tokens, 32K LDS -> 5 blocks/CU
  rounds_k<<<dim3(4096), dim3(256), 32768, stream>>>(
      mvB, wgT, wuT, wdT, wcomb, lnw, lnb, mvb);

  // out = LN(mvb @ Pout)
  gemm_out_ln_k<<<dim3(512), dim3(512), 143872, stream>>>(
      mvb, poutT, (float*)d_out, ow, ob, offs);
}

// Round 4
// 404.870 us; speedup vs baseline: 1.3208x; 1.0027x over previous
//
#include <hip/hip_runtime.h>

#define DEV __device__ __forceinline__

typedef __attribute__((ext_vector_type(4))) float f32x4;
typedef __attribute__((ext_vector_type(2))) float f32x2;
typedef __attribute__((ext_vector_type(8))) short bf16x8;

// Shapes: E=16, D=1024, ED=512, NB=8, DB=64, R=2, F=256, N=32768, C=2048

// ---------- helpers ----------
DEV unsigned short f2bf(float f) {
  union { float f; unsigned u; } v; v.f = f;
  unsigned r = v.u + 0x7fffu + ((v.u >> 16) & 1u);
  return (unsigned short)(r >> 16);
}

DEV unsigned pk2bf(float lo, float hi) {  // v_cvt_pk_bf16_f32 (RNE)
  unsigned r;
  asm("v_cvt_pk_bf16_f32 %0, %1, %2" : "=v"(r) : "v"(lo), "v"(hi));
  return r;
}
DEV unsigned short f2bf1(float v) { return (unsigned short)pk2bf(v, v); }

DEV float bf2f(unsigned short b) {
  union { unsigned u; float f; } v; v.u = ((unsigned)b) << 16; return v.f;
}

DEV float frcp(float x) { return __builtin_amdgcn_rcpf(x); }

// raw barrier: NO implicit vmcnt drain. "memory" clobber = compiler fence.
DEV void sbar() { asm volatile("s_barrier" ::: "memory"); }
DEV void wait_lgkm0() { asm volatile("s_waitcnt lgkmcnt(0)" ::: "memory"); }
DEV void wait_vm0() { asm volatile("s_waitcnt vmcnt(0)" ::: "memory"); }

DEV void async16(const unsigned short* g, unsigned short* l) {
  __builtin_amdgcn_global_load_lds(
      (__attribute__((address_space(1))) const unsigned int*)g,
      (__attribute__((address_space(3))) unsigned int*)l, 16, 0, 0);
}

// Tiled global layout for GEMM operands: element (n,k) of an [N][K] panel at
//   (n>>3)*8K + (k>>3)*64 + (n&7)*8 + (k&7)
DEV long tiled_off(long n, int k, int K) {
  return (n >> 3) * (8L * K) + (long)(((k >> 3) * 64) + ((int)(n & 7)) * 8 + (k & 7));
}

// frag read from a tiled 32-k LDS subtile (bf16)
DEV bf16x8 ld_frag(const char* s, int row, int hi) {
  return *(const bf16x8*)(s + ((row >> 3) * 512 + hi * 128 + (row & 7) * 16));
}

// ---------- Cayley table at compile time ----------
__host__ __device__ constexpr int km_(int i) { return i==0?0:i==1?1:i==2?2:i==3?4:i==4?3:i==5?5:i==6?6:7; }
__host__ __device__ constexpr int pc_(int x) { int c = 0; while (x) { c += x & 1; x >>= 1; } return c; }
__host__ __device__ constexpr int KIDX(int i, int j) { return km_(km_(i) ^ km_(j)); }
__host__ __device__ constexpr int CSGN(int i, int j) {
  int a = km_(i), b = km_(j), aa = a >> 1, s = 0;
  while (aa) { s += pc_(aa & b); aa >>= 1; }
  return (s & 1) ? -1 : 1;
}
__host__ __device__ constexpr int PIDX(int i, int j) {  // i<=j
  return 8 * i - (i * (i - 1)) / 2 + (j - i);
}

// ---------- small kernels ----------
__global__ __launch_bounds__(64) void geoprep_k(const float* __restrict__ iw,
                                                const float* __restrict__ gg,
                                                float* __restrict__ wcomb) {
  int er = threadIdx.x;
  if (er >= 32) return;
  const float* w = iw + er * 64;
  float gate = frcp(1.f + __expf(-gg[er]));
  float* c = wcomb + er * 40;
  int p = 0;
  for (int i = 0; i < 8; ++i)
    for (int j = i; j < 8; ++j) {
      float v = (float)CSGN(i, j) * frcp(1.f + __expf(-w[i * 8 + j]));
      if (j > i) v += (float)CSGN(j, i) * frcp(1.f + __expf(-w[j * 8 + i]));
      c[p++] = gate * v;
    }
  c[36] = 1.f - gate;
}

// x fp32 [32768][1024] -> xb bf16 in tiled layout (K=1024).
__global__ __launch_bounds__(256) void convert_k(const float* __restrict__ in,
                                                 unsigned short* __restrict__ out,
                                                 long nchunks) {
  long q = (long)blockIdx.x * 256 + threadIdx.x;
  long stride = (long)gridDim.x * 256;
  for (; q < nchunks; q += stride) {
    long n = q >> 7;
    int k8 = (int)(q & 127);
    const float4* p = (const float4*)(in + n * 1024 + k8 * 8);
    float4 v0 = p[0], v1 = p[1];
    uint4 o;
    o.x = pk2bf(v0.x, v0.y);
    o.y = pk2bf(v0.z, v0.w);
    o.z = pk2bf(v1.x, v1.y);
    o.w = pk2bf(v1.z, v1.w);
    *(uint4*)(out + (n >> 3) * 8192 + k8 * 64 + (n & 7) * 8) = o;
  }
}

// small transposes (wg/wu/wd): in (Rr,Cc) fp32 (batch z) -> (Cc,Rr) bf16.
// TI=0 linear; TI=1: k ^= (row&7)<<3 (needs Rr==64).
template<int TI>
__global__ __launch_bounds__(256) void transpose_k(const float* __restrict__ in,
                                                   unsigned short* __restrict__ out,
                                                   int Rr, int Cc) {
  __shared__ unsigned short tile[32][33];
  const float* ib = in + (long)blockIdx.z * Rr * Cc;
  unsigned short* ob = out + (long)blockIdx.z * Rr * Cc;
  int r0 = blockIdx.y * 32, c0 = blockIdx.x * 32;
  int tr = threadIdx.x >> 5, tc = threadIdx.x & 31;
#pragma unroll
  for (int i = 0; i < 4; ++i) {
    int r = tr + i * 8;
    tile[r][tc] = f2bf(ib[(long)(r0 + r) * Cc + c0 + tc]);
  }
  __syncthreads();
#pragma unroll
  for (int i = 0; i < 4; ++i) {
    int c = tr + i * 8;
    int row = c0 + c;
    int k = r0 + tc;
    if (TI == 0) ob[(long)row * Rr + k] = tile[tc][c];
    else ob[(long)row * Rr + (k ^ ((row & 7) << 3))] = tile[tc][c];
  }
}

// big convert+transpose for pin/pout: in [Rr k][Cc n] fp32 -> out tiled bf16 [n][k].
__global__ __launch_bounds__(256) void trans_big_k(const float* __restrict__ in,
                                                   unsigned short* __restrict__ out,
                                                   int Rr, int Cc) {
  __shared__ float t[64][64];
  const float* ib = in + (long)blockIdx.z * Rr * Cc;
  unsigned short* ob = out + (long)blockIdx.z * (long)Rr * Cc;
  int k0 = blockIdx.y * 64, n0 = blockIdx.x * 64;
  int tid = threadIdx.x;
#pragma unroll
  for (int p = 0; p < 4; ++p) {
    int idx = p * 256 + tid;
    int kr = idx >> 4, nc = (idx & 15) * 4;
    *(float4*)&t[kr][nc] = *(const float4*)(ib + (long)(k0 + kr) * Cc + n0 + nc);
  }
  __syncthreads();
#pragma unroll
  for (int p = 0; p < 2; ++p) {
    int idx = p * 256 + tid;
    int n = idx & 63, kc = idx >> 6;       // kc 0..7
    float v[8];
#pragma unroll
    for (int u = 0; u < 8; ++u) v[u] = t[kc * 8 + u][n];
    uint4 o;
    o.x = pk2bf(v[0], v[1]); o.y = pk2bf(v[2], v[3]);
    o.z = pk2bf(v[4], v[5]); o.w = pk2bf(v[6], v[7]);
    *(uint4*)(ob + tiled_off(n0 + n, k0 + kc * 8, Rr)) = o;
  }
}

// GEMM1: mvB(bf16, linear [token][512]) = x @ Pin^T per expert. 256x256 tile, BK=64,
// quantum-pipelined (r10 structure).
__global__ __launch_bounds__(512, 1) void gemm_in_k(const unsigned short* __restrict__ Xb,
                                                    const unsigned short* __restrict__ Bw,
                                                    unsigned short* __restrict__ MvB,
                                                    const int* __restrict__ offs) {
  extern __shared__ char smem[];    // [2 buf][ A 32K | B 32K ], each op as 2 x 16K ksub
  int bid = blockIdx.x;             // 256 blocks
  int wg = (bid & 7) * 32 + (bid >> 3);      // XCD swizzle (256 % 8 == 0)
  int e = wg >> 4, rem = wg & 15, bm = rem >> 1, bn = rem & 1;
  int tid = threadIdx.x, wid = tid >> 6, lane = tid & 63;
  int wm = (wid >> 2) * 128, wn = (wid & 3) * 64;
  int ri = lane & 15, hi = lane >> 4;
  long aw = ((long)offs[e] >> 3) + bm * 32;  // A window base (xb tiled, K=1024)
  long bw = (long)e * 64 + bn * 32;          // B window base (pinT tiled, K=1024)

  auto STG = [&](int b, int kt, int s, int op) {
    const unsigned short* src = op ? Bw : Xb;
    long wbase = op ? bw : aw;
    char* dst = smem + b * 65536 + op * 32768 + s * 16384;
#pragma unroll
    for (int i = 0; i < 2; ++i) {
      int d = i * 512 + tid;
      async16(src + (wbase + (d >> 5)) * 8192 +
                  (long)((kt * 8 + s * 4 + ((d >> 3) & 3)) * 64 + (d & 7) * 8),
              (unsigned short*)(dst + d * 16));
    }
  };

  f32x4 acc[8][4];
#pragma unroll
  for (int i = 0; i < 8; ++i)
#pragma unroll
    for (int j = 0; j < 4; ++j) acc[i][j] = (f32x4){0.f, 0.f, 0.f, 0.f};

  STG(0, 0, 0, 0); STG(0, 0, 0, 1); STG(0, 0, 1, 0); STG(0, 0, 1, 1);

  for (int t = 0; t < 16; ++t) {
    int c = t & 1;
    const char* cA = smem + c * 65536;
    const char* cB = smem + c * 65536 + 32768;
#pragma unroll
    for (int s = 0; s < 2; ++s) {
      if (t < 15) {
        STG(c ^ 1, t + 1, s, 0);
        STG(c ^ 1, t + 1, s, 1);
        asm volatile("s_waitcnt vmcnt(8)" ::: "memory");
      } else if (s == 0) {
        asm volatile("s_waitcnt vmcnt(4)" ::: "memory");
      } else {
        asm volatile("s_waitcnt vmcnt(0)" ::: "memory");
      }
      sbar();
      bf16x8 a[8], b[4];
#pragma unroll
      for (int i = 0; i < 8; ++i) a[i] = ld_frag(cA + s * 16384, wm + i * 16 + ri, hi);
#pragma unroll
      for (int j = 0; j < 4; ++j) b[j] = ld_frag(cB + s * 16384, wn + j * 16 + ri, hi);
      __builtin_amdgcn_s_setprio(1);
#pragma unroll
      for (int i = 0; i < 8; ++i)
#pragma unroll
        for (int j = 0; j < 4; ++j)
          acc[i][j] = __builtin_amdgcn_mfma_f32_16x16x32_bf16(a[i], b[j], acc[i][j], 0, 0, 0);
      __builtin_amdgcn_s_setprio(0);
    }
  }

  unsigned short* Cb = MvB + ((long)e * 2048 + (long)bm * 256) * 512 + bn * 256;
#pragma unroll
  for (int i = 0; i < 8; ++i)
#pragma unroll
    for (int j = 0; j < 4; ++j)
#pragma unroll
      for (int rr = 0; rr < 4; ++rr)
        Cb[(long)(wm + i * 16 + hi * 4 + rr) * 512 + wn + j * 16 + ri] =
            f2bf1(acc[i][j][rr]);
}

// ---------- merged 2-round fused kernel: WAVE-INDEPENDENT tokens ----------
// 8 tokens/block, 256 threads = 4 waves; each wave owns 2 tokens END-TO-END.
// F processed in EIGHTHS (32 F-rows): per eighth a wave does 2 F-tiles of
// gate/up (8 MFMA), silu, and one 32-k down-proj chunk (4 MFMA).
// sFlat/sH/sMvh WAVE-PRIVATE (no barriers). W staging DOUBLE-BUFFERED in
// eighths with ONE barrier per eighth and a full-eighth prefetch distance:
//   top of eighth i: vmcnt(0)  (stage(i) was issued a whole eighth ago)
//                    s_barrier (all waves' stage(i) landed AND all done
//                               reading buf((i+1)&1) during eighth i-1)
//                    issue stage(i+1) -> buf((i+1)&1)   (safe by the above)
// This takes the W-stage L2 latency off the critical path (r0-r3 all paid
// a partial-quarter-covered vmcnt(0) drain 8x/round -> invariant ~190us).
// LDS 32K -> 5 blocks/CU at __launch_bounds__(256,5) (VGPR cap 102, no
// spill; r1/r2 lesson: (512,6)'s 85 cap spilled).
//   sFH  @0      8K: 4 waves x 2K  [16 row][128B] xor (row&7)<<4 (flat, then h)
//   sMvh @8K     8K: 4 waves x 2K  [2 tok][8 blade][128B] xor (blade)<<4
//   sW   @16K   16K: dbuf x (Wg 4K | Wu 4K) eighth (swizzle baked in global)
// Wd read per-wave from global (L1/L2-resident). Mvb written via coalesced
// uint4 epilogue from sMvh.
__global__ __launch_bounds__(256, 5) void rounds_k(
    const unsigned short* __restrict__ MvB, const unsigned short* __restrict__ WgT,
    const unsigned short* __restrict__ WuT, const unsigned short* __restrict__ WdT,
    const float* __restrict__ wcomb, const float* __restrict__ lnw,
    const float* __restrict__ lnb, unsigned short* __restrict__ Mvb) {
  extern __shared__ char smem[];
  int tid = threadIdx.x, wid = tid >> 6, lane = tid & 63;
  char* sFH = smem + wid * 2048;            // wave-private [16][128B]
  char* sMv = smem + 8192 + wid * 2048;     // wave-private [2 tok][1K]
  char* sW  = smem + 16384;                 // dbuf 2 x 8K (Wg 4K | Wu 4K)

  int bid = blockIdx.x;
  int wg = (bid & 7) * 512 + (bid >> 3);    // XCD swizzle (4096 % 8 == 0)
  int e = wg >> 8, bx = wg & 255;

  int t8 = lane >> 5, q = lane & 31;        // P1 coords: token-in-wave, d-pair
  int ri = lane & 15, hi = lane >> 4;       // frag coords
  int sw = (ri & 7) << 4;

  // stage global eighth i8 (0..15; round = i8>>3, slice = i8&7)
  auto STAGE = [&](int i8) {
    long base = (long)(e * 2 + (i8 >> 3)) * 16384 + (i8 & 7) * 2048;
    char* dst = sW + (i8 & 1) * 8192;
    async16(WgT + base + tid * 8, (unsigned short*)(dst + tid * 16));
    async16(WuT + base + tid * 8, (unsigned short*)(dst + 4096 + tid * 16));
  };
  STAGE(0);   // prologue: lands under P1 of round 0

#pragma unroll 1
  for (int r = 0; r < 2; ++r) {
    int er = e * 2 + r;
    const unsigned short* wd = WdT + (long)er * 16384;  // [64 dout][256 F]

    // ---- P1a: mv (global bf16 on r0 -> stash to sMvh; sMvh on r1) ----
    f32x2 mv[8];
    if (r == 0) {
      long base = ((long)e * 2048 + bx * 8 + wid * 2 + t8) * 512 + 2 * q;
      unsigned uv[8];
#pragma unroll
      for (int i = 0; i < 8; ++i)
        uv[i] = *(const unsigned*)(MvB + base + i * 64);
#pragma unroll
      for (int i = 0; i < 8; ++i) {
        *(unsigned*)(sMv + t8 * 1024 + i * 128 + ((4 * q) ^ (i << 4))) = uv[i];
        mv[i] = (f32x2){bf2f((unsigned short)(uv[i] & 0xffff)),
                        bf2f((unsigned short)(uv[i] >> 16))};
      }
    } else {
#pragma unroll
      for (int i = 0; i < 8; ++i) {
        unsigned uv = *(const unsigned*)(sMv + t8 * 1024 + i * 128 + ((4 * q) ^ (i << 4)));
        mv[i] = (f32x2){bf2f((unsigned short)(uv & 0xffff)),
                        bf2f((unsigned short)(uv >> 16))};
      }
    }

    // ---- P1b: geo + mix + LN(64) -> sFH (packed f32x2 math; wave-private) ----
    {
      const float* C = wcomb + er * 40;
      f32x2 g[8];
#pragma unroll
      for (int k = 0; k < 8; ++k) g[k] = (f32x2){0.f, 0.f};
#pragma unroll
      for (int i = 0; i < 8; ++i)
#pragma unroll
        for (int j = i; j < 8; ++j) {
          float cc = C[PIDX(i, j)];
          const int k = KIDX(i, j);
          g[k] += cc * (mv[i] * mv[j]);
        }
      float omg = C[36];
#pragma unroll
      for (int k = 0; k < 8; ++k) g[k] = omg * mv[k] + g[k];
      float2 lw = *(const float2*)(lnw + (long)er * 64 + 2 * q);
      float2 lb = *(const float2*)(lnb + (long)er * 64 + 2 * q);
      f32x2 lwv = (f32x2){lw.x, lw.y}, lbv = (f32x2){lb.x, lb.y};
#pragma unroll
      for (int half = 0; half < 2; ++half) {
        f32x2 red[4];
#pragma unroll
        for (int k = 0; k < 4; ++k) {
          f32x2 mx = g[half * 4 + k];
          red[k].x = mx.x + mx.y;
          red[k].y = fmaf(mx.x, mx.x, mx.y * mx.y);
        }
#pragma unroll
        for (int off = 16; off >= 1; off >>= 1)
#pragma unroll
          for (int t = 0; t < 4; ++t) {
            f32x2 o;
            o.x = __shfl_xor(red[t].x, off);
            o.y = __shfl_xor(red[t].y, off);
            red[t] += o;
          }
#pragma unroll
        for (int k = 0; k < 4; ++k) {
          int kk = half * 4 + k;
          float mean = red[k].x * (1.f / 64.f);
          float var = red[k].y * (1.f / 64.f) - mean * mean;
          float rs = rsqrtf(var + 1e-5f);
          f32x2 nv = (g[kk] - mean) * rs;
          f32x2 ov = nv * lwv + lbv;
          unsigned pv = pk2bf(ov.x, ov.y);
          int row = t8 * 8 + kk;                    // row&7 == kk
          *(unsigned*)(sFH + row * 128 + ((4 * q) ^ (kk << 4))) = pv;
        }
      }
    }
    wait_lgkm0();   // own-wave flat writes done (cross-LANE reads next)

    // ---- hoist flat B-frags to regs (sFH gets reused for h afterwards) ----
    bf16x8 bfr[2];
#pragma unroll
    for (int kt = 0; kt < 2; ++kt)
      bfr[kt] = *(const bf16x8*)(sFH + ri * 128 + ((kt * 64 + hi * 16) ^ sw));

    f32x4 acc2[4];
#pragma unroll
    for (int j = 0; j < 4; ++j) acc2[j] = (f32x4){0.f, 0.f, 0.f, 0.f};

#pragma unroll 2
    for (int q8 = 0; q8 < 8; ++q8) {
      int i8 = r * 8 + q8;
      wait_vm0();   // stage(i8) landed (issued a full eighth ago)
      sbar();       // all waves: stage(i8) in LDS; eighth i8-1 reads done
      if (i8 < 15) STAGE(i8 + 1);   // -> buf((i8+1)&1): free per the barrier
      const char* bufW = sW + (i8 & 1) * 8192;

      // ---- P2: 2 F-tiles: D[F][trow=ri] = W-frag x flat(regs); silu -> h ----
#pragma unroll
      for (int ftl = 0; ftl < 2; ++ftl) {
        const char* bg = bufW + (ftl * 16 + ri) * 128;
        const char* bu = bg + 4096;
        bf16x8 wg0 = *(const bf16x8*)(bg + ((hi * 16) ^ sw));
        bf16x8 wg1 = *(const bf16x8*)(bg + ((64 + hi * 16) ^ sw));
        bf16x8 wu0 = *(const bf16x8*)(bu + ((hi * 16) ^ sw));
        bf16x8 wu1 = *(const bf16x8*)(bu + ((64 + hi * 16) ^ sw));
        f32x4 ag = (f32x4){0.f, 0.f, 0.f, 0.f};
        f32x4 au = (f32x4){0.f, 0.f, 0.f, 0.f};
        __builtin_amdgcn_s_setprio(1);
        ag = __builtin_amdgcn_mfma_f32_16x16x32_bf16(wg0, bfr[0], ag, 0, 0, 0);
        au = __builtin_amdgcn_mfma_f32_16x16x32_bf16(wu0, bfr[0], au, 0, 0, 0);
        ag = __builtin_amdgcn_mfma_f32_16x16x32_bf16(wg1, bfr[1], ag, 0, 0, 0);
        au = __builtin_amdgcn_mfma_f32_16x16x32_bf16(wu1, bfr[1], au, 0, 0, 0);
        __builtin_amdgcn_s_setprio(0);
        float hh[4];
#pragma unroll
        for (int rr = 0; rr < 4; ++rr) {
          float gv = ag[rr], uu = au[rr];
          hh[rr] = gv * uu * frcp(1.f + __expf(-gv));
        }
        // h (F_loc = ftl*16+hi*4+rr, trow = ri) -> sFH[ri][2*F_loc] (swizzled)
        uint2 hwv;
        hwv.x = pk2bf(hh[0], hh[1]);
        hwv.y = pk2bf(hh[2], hh[3]);
        *(uint2*)(sFH + ri * 128 + ((ftl * 32 + hi * 8) ^ sw)) = hwv;
      }

      // ---- Wd frags (global, per-wave; A-operand: m=dout, k=F eighth) ----
      bf16x8 wdf[4];
#pragma unroll
      for (int j = 0; j < 4; ++j)
        wdf[j] = *(const bf16x8*)(wd + (j * 16 + ri) * 256 + q8 * 32 + hi * 8);

      wait_lgkm0();  // own h writes (and W reads) complete before hk read

      // ---- P4: acc2[dout][trow] += Wd x h (one 32-k chunk) ----
      bf16x8 hk = *(const bf16x8*)(sFH + ri * 128 + ((hi * 16) ^ sw));
      __builtin_amdgcn_s_setprio(1);
#pragma unroll
      for (int j = 0; j < 4; ++j)
        acc2[j] = __builtin_amdgcn_mfma_f32_16x16x32_bf16(wdf[j], hk, acc2[j], 0, 0, 0);
      __builtin_amdgcn_s_setprio(0);
    }

    // ---- P5: residual vs sMvh (wave-private, in place both rounds) ----
    {
#pragma unroll
      for (int j = 0; j < 4; ++j)
#pragma unroll
        for (int u = 0; u < 2; ++u) {
          int off = (j * 32 + hi * 8 + 4 * u) ^ sw;
          unsigned* p = (unsigned*)(sMv + (ri >> 3) * 1024 + (ri & 7) * 128 + off);
          unsigned old = *p;
          float v0 = bf2f((unsigned short)(old & 0xffff)) + acc2[j][2 * u];
          float v1 = bf2f((unsigned short)(old >> 16)) + acc2[j][2 * u + 1];
          *p = pk2bf(v0, v1);
        }
    }
    wait_lgkm0();   // sMvh updates done (next round's P1a / epilogue reads)

    // ---- r1: coalesced uint4 dump sMvh -> Mvb (linear [token][512]) ----
    if (r == 1) {
      int tt = lane >> 5;              // token-in-wave
      int bl = (lane & 31) >> 2;       // blade 0..7
      int cc = lane & 3;               // 32B chunk 0..3
      const char* src = sMv + tt * 1024 + bl * 128;
      long row = (long)e * 2048 + bx * 8 + wid * 2 + tt;
      unsigned short* dst = Mvb + row * 512 + bl * 64 + cc * 16;
#pragma unroll
      for (int h = 0; h < 2; ++h) {
        uint4 v = *(const uint4*)(src + ((cc * 32 + h * 16) ^ (bl << 4)));
        *(uint4*)(dst + h * 8) = v;
      }
    }
  }
}

// ---------- fused out-projection + LayerNorm(D=1024), 512 threads/block ----------
// A (mvb) is LINEAR [token][512] bf16; tiled LDS layout derived via per-lane source addr.
__global__ __launch_bounds__(512, 2) void gemm_out_ln_k(
    const unsigned short* __restrict__ Mvb, const unsigned short* __restrict__ Pw,
    float* __restrict__ Out, const float* __restrict__ ow, const float* __restrict__ ob,
    const int* __restrict__ offs) {
  extern __shared__ char smem[];
  int bid = blockIdx.x;
  int wg = (bid & 7) * 64 + (bid >> 3);
  int e = wg >> 5, mb = wg & 31;
  int tid = threadIdx.x, wid = tid >> 6, lane = tid & 63;
  int ri = lane & 15, hi = lane >> 4;
  long bbase = (long)e * 524288;                 // poutT expert base (tiled)
  long arow0 = (long)e * 2048 + (long)mb * 64;   // mvb expert row base (linear)

  auto STAGE = [&](int buf, int kt) {
#pragma unroll
    for (int i = 0; i < 8; ++i) {
      int q = i * 512 + tid;
      int w = q >> 5, c = (q >> 3) & 3, rr = q & 7;
      async16(Pw + bbase + (long)w * 4096 + (kt * 4 + c) * 64 + rr * 8,
              (unsigned short*)(smem + buf * 65536 + q * 16));
    }
    if (tid < 256) {
      int q = tid;
      int w = q >> 5, c = (q >> 3) & 3, rr = q & 7;
      async16(Mvb + (arow0 + w * 8 + rr) * 512 + kt * 32 + c * 8,
              (unsigned short*)(smem + 131072 + buf * 4096 + q * 16));
    }
  };

  f32x4 acc[4][8];
#pragma unroll
  for (int i = 0; i < 4; ++i)
#pragma unroll
    for (int j = 0; j < 8; ++j) acc[i][j] = (f32x4){0.f, 0.f, 0.f, 0.f};

  STAGE(0, 0);
  for (int kt = 0; kt < 16; ++kt) {
    int cur = kt & 1;
    if (kt < 15) {
      STAGE(cur ^ 1, kt + 1);
      asm volatile("s_waitcnt vmcnt(8)" ::: "memory");
    } else {
      asm volatile("s_waitcnt vmcnt(0)" ::: "memory");
    }
    sbar();
    const char* cB = smem + cur * 65536;
    const char* cA = smem + 131072 + cur * 4096;
    bf16x8 a[4], b[8];
#pragma unroll
    for (int i = 0; i < 4; ++i) a[i] = ld_frag(cA, i * 16 + ri, hi);
#pragma unroll
    for (int j = 0; j < 8; ++j) b[j] = ld_frag(cB, wid * 128 + j * 16 + ri, hi);
    __builtin_amdgcn_s_setprio(1);
#pragma unroll
    for (int i = 0; i < 4; ++i)
#pragma unroll
      for (int j = 0; j < 8; ++j)
        acc[i][j] = __builtin_amdgcn_mfma_f32_16x16x32_bf16(a[i], b[j], acc[i][j], 0, 0, 0);
    __builtin_amdgcn_s_setprio(0);
    sbar();
  }

  float* rsum = (float*)(smem + 139264);
  float* rsq  = (float*)(smem + 141312);
  float* mexp = (float*)(smem + 143360);
  float* rstd = (float*)(smem + 143616);
  int hi4 = hi * 4;
#pragma unroll
  for (int i = 0; i < 4; ++i)
#pragma unroll
    for (int rr = 0; rr < 4; ++rr) {
      float s = 0.f, qv = 0.f;
#pragma unroll
      for (int j = 0; j < 8; ++j) { float v = acc[i][j][rr]; s += v; qv += v * v; }
#pragma unroll
      for (int off = 1; off < 16; off <<= 1) {
        s += __shfl_xor(s, off);
        qv += __shfl_xor(qv, off);
      }
      if (ri == 0) {
        int row = i * 16 + hi4 + rr;
        rsum[row * 8 + wid] = s;
        rsq[row * 8 + wid] = qv;
      }
    }
  __syncthreads();
  if (tid < 64) {
    float S = 0.f, Q = 0.f;
#pragma unroll
    for (int w = 0; w < 8; ++w) { S += rsum[tid * 8 + w]; Q += rsq[tid * 8 + w]; }
    float mean = S * (1.f / 1024.f);
    float var = Q * (1.f / 1024.f) - mean * mean;
    mexp[tid] = mean;
    rstd[tid] = rsqrtf(var + 1e-5f);
  }
  __syncthreads();
  long r0 = (long)offs[e] + (long)mb * 64;
  float owv[8], obv[8];
#pragma unroll
  for (int j = 0; j < 8; ++j) {
    int col = wid * 128 + j * 16 + ri;
    owv[j] = ow[col];
    obv[j] = ob[col];
  }
#pragma unroll
  for (int i = 0; i < 4; ++i)
#pragma unroll
    for (int rr = 0; rr < 4; ++rr) {
      int row = i * 16 + hi4 + rr;
      float mu = mexp[row], rs = rstd[row];
#pragma unroll
      for (int j = 0; j < 8; ++j) {
        int col = wid * 128 + j * 16 + ri;
        Out[(r0 + row) * 1024 + col] = (acc[i][j][rr] - mu) * rs * owv[j] + obv[j];
      }
    }
}

// ---------- host ----------
extern "C" void kernel_launch(void* const* d_in, const int* in_sizes, int n_in,
                              void* d_out, int out_size, void* d_ws, size_t ws_size,
                              hipStream_t stream) {
  const float* x    = (const float*)d_in[0];
  const float* pin  = (const float*)d_in[1];
  const float* pout = (const float*)d_in[2];
  const float* iw   = (const float*)d_in[3];
  const float* gg   = (const float*)d_in[4];
  const float* fg   = (const float*)d_in[5];
  const float* fu   = (const float*)d_in[6];
  const float* fd   = (const float*)d_in[7];
  const float* lnw  = (const float*)d_in[8];
  const float* lnb  = (const float*)d_in[9];
  const float* ow   = (const float*)d_in[10];
  const float* ob   = (const float*)d_in[11];
  const int* offs   = (const int*)d_in[12];

  char* ws = (char*)d_ws;
  unsigned short* mvB  = (unsigned short*)(ws + 0L);          //  33,554,432 B (linear bf16)
  unsigned short* mvb  = (unsigned short*)(ws + 33554432L);   //  33,554,432 B (linear bf16)
  unsigned short* pinT = (unsigned short*)(ws + 67108864L);   //  16,777,216 B (tiled)
  unsigned short* poutT= (unsigned short*)(ws + 83886080L);   //  16,777,216 B (tiled)
  unsigned short* wgT  = (unsigned short*)(ws + 100663296L);  //   2,097,152 B (swz-64)
  unsigned short* wuT  = (unsigned short*)(ws + 102760448L);  //   2,097,152 B (swz-64)
  unsigned short* wdT  = (unsigned short*)(ws + 104857600L);  //   2,097,152 B (plain)
  float* wcomb         = (float*)(ws + 106954752L);           //   5,120 B
  unsigned short* xb   = (unsigned short*)(ws + 117440512L);  //  67,108,864 B (tiled)

  // prep
  convert_k<<<dim3(4096), dim3(256), 0, stream>>>(x, xb, 4194304L);
  trans_big_k<<<dim3(8, 16, 16), dim3(256), 0, stream>>>(pin, pinT, 1024, 512);
  trans_big_k<<<dim3(16, 8, 16), dim3(256), 0, stream>>>(pout, poutT, 512, 1024);
  transpose_k<1><<<dim3(8, 2, 32), dim3(256), 0, stream>>>(fg, wgT, 64, 256);
  transpose_k<1><<<dim3(8, 2, 32), dim3(256), 0, stream>>>(fu, wuT, 64, 256);
  transpose_k<0><<<dim3(2, 8, 32), dim3(256), 0, stream>>>(fd, wdT, 256, 64);
  geoprep_k<<<dim3(1), dim3(64), 0, stream>>>(iw, gg, wcomb);

  // mvB = x @ Pin (bf16 linear out; 256x256 quantum-pipelined)
  gemm_in_k<<<dim3(256), dim3(512), 131072, stream>>>(xb, pinT, mvB, offs);

  // both rounds in ONE kernel; wave-independent tokens, W dbuf in eighths
  rounds_k<<<dim3(4096), dim3(256), 32768, stream>>>(
      mvB, wgT, wuT, wdT, wcomb, lnw, lnb, mvb);

  // out = LN(mvb @ Pout)
  gemm_out_ln_k<<<dim3(512), dim3(512), 143872, stream>>>(
      mvb, poutT, (float*)d_out, ow, ob, offs);
}

// Round 5
// 329.115 us; speedup vs baseline: 1.6249x; 1.2302x over previous
//
#include <hip/hip_runtime.h>

#define DEV __device__ __forceinline__

typedef __attribute__((ext_vector_type(4))) float f32x4;
typedef __attribute__((ext_vector_type(2))) float f32x2;
typedef __attribute__((ext_vector_type(8))) short bf16x8;

// Shapes: E=16, D=1024, ED=512, NB=8, DB=64, R=2, F=256, N=32768, C=2048

// ---------- helpers ----------
DEV unsigned short f2bf(float f) {
  union { float f; unsigned u; } v; v.f = f;
  unsigned r = v.u + 0x7fffu + ((v.u >> 16) & 1u);
  return (unsigned short)(r >> 16);
}

DEV unsigned pk2bf(float lo, float hi) {  // v_cvt_pk_bf16_f32 (RNE)
  unsigned r;
  asm("v_cvt_pk_bf16_f32 %0, %1, %2" : "=v"(r) : "v"(lo), "v"(hi));
  return r;
}
DEV unsigned short f2bf1(float v) { return (unsigned short)pk2bf(v, v); }

DEV float bf2f(unsigned short b) {
  union { unsigned u; float f; } v; v.u = ((unsigned)b) << 16; return v.f;
}

DEV float frcp(float x) { return __builtin_amdgcn_rcpf(x); }

// raw barrier: NO implicit vmcnt drain. "memory" clobber = compiler fence.
DEV void sbar() { asm volatile("s_barrier" ::: "memory"); }
DEV void wait_lgkm0() { asm volatile("s_waitcnt lgkmcnt(0)" ::: "memory"); }
DEV void wait_vm0() { asm volatile("s_waitcnt vmcnt(0)" ::: "memory"); }

DEV void async16(const unsigned short* g, unsigned short* l) {
  __builtin_amdgcn_global_load_lds(
      (__attribute__((address_space(1))) const unsigned int*)g,
      (__attribute__((address_space(3))) unsigned int*)l, 16, 0, 0);
}

// Tiled global layout for GEMM operands: element (n,k) of an [N][K] panel at
//   (n>>3)*8K + (k>>3)*64 + (n&7)*8 + (k&7)
DEV long tiled_off(long n, int k, int K) {
  return (n >> 3) * (8L * K) + (long)(((k >> 3) * 64) + ((int)(n & 7)) * 8 + (k & 7));
}

// frag read from a tiled 32-k LDS subtile (bf16)
DEV bf16x8 ld_frag(const char* s, int row, int hi) {
  return *(const bf16x8*)(s + ((row >> 3) * 512 + hi * 128 + (row & 7) * 16));
}

// ---------- Cayley table at compile time ----------
__host__ __device__ constexpr int km_(int i) { return i==0?0:i==1?1:i==2?2:i==3?4:i==4?3:i==5?5:i==6?6:7; }
__host__ __device__ constexpr int pc_(int x) { int c = 0; while (x) { c += x & 1; x >>= 1; } return c; }
__host__ __device__ constexpr int KIDX(int i, int j) { return km_(km_(i) ^ km_(j)); }
__host__ __device__ constexpr int CSGN(int i, int j) {
  int a = km_(i), b = km_(j), aa = a >> 1, s = 0;
  while (aa) { s += pc_(aa & b); aa >>= 1; }
  return (s & 1) ? -1 : 1;
}
__host__ __device__ constexpr int PIDX(int i, int j) {  // i<=j
  return 8 * i - (i * (i - 1)) / 2 + (j - i);
}

// ---------- small kernels ----------
__global__ __launch_bounds__(64) void geoprep_k(const float* __restrict__ iw,
                                                const float* __restrict__ gg,
                                                float* __restrict__ wcomb) {
  int er = threadIdx.x;
  if (er >= 32) return;
  const float* w = iw + er * 64;
  float gate = frcp(1.f + __expf(-gg[er]));
  float* c = wcomb + er * 40;
  int p = 0;
  for (int i = 0; i < 8; ++i)
    for (int j = i; j < 8; ++j) {
      float v = (float)CSGN(i, j) * frcp(1.f + __expf(-w[i * 8 + j]));
      if (j > i) v += (float)CSGN(j, i) * frcp(1.f + __expf(-w[j * 8 + i]));
      c[p++] = gate * v;
    }
  c[36] = 1.f - gate;
}

// x fp32 [32768][1024] -> xb bf16 in tiled layout (K=1024).
__global__ __launch_bounds__(256) void convert_k(const float* __restrict__ in,
                                                 unsigned short* __restrict__ out,
                                                 long nchunks) {
  long q = (long)blockIdx.x * 256 + threadIdx.x;
  long stride = (long)gridDim.x * 256;
  for (; q < nchunks; q += stride) {
    long n = q >> 7;
    int k8 = (int)(q & 127);
    const float4* p = (const float4*)(in + n * 1024 + k8 * 8);
    float4 v0 = p[0], v1 = p[1];
    uint4 o;
    o.x = pk2bf(v0.x, v0.y);
    o.y = pk2bf(v0.z, v0.w);
    o.z = pk2bf(v1.x, v1.y);
    o.w = pk2bf(v1.z, v1.w);
    *(uint4*)(out + (n >> 3) * 8192 + k8 * 64 + (n & 7) * 8) = o;
  }
}

// small transposes (wg/wu/wd): in (Rr,Cc) fp32 (batch z) -> (Cc,Rr) bf16.
// TI=0 linear; TI=1: k ^= (row&7)<<3 (needs Rr==64).
template<int TI>
__global__ __launch_bounds__(256) void transpose_k(const float* __restrict__ in,
                                                   unsigned short* __restrict__ out,
                                                   int Rr, int Cc) {
  __shared__ unsigned short tile[32][33];
  const float* ib = in + (long)blockIdx.z * Rr * Cc;
  unsigned short* ob = out + (long)blockIdx.z * Rr * Cc;
  int r0 = blockIdx.y * 32, c0 = blockIdx.x * 32;
  int tr = threadIdx.x >> 5, tc = threadIdx.x & 31;
#pragma unroll
  for (int i = 0; i < 4; ++i) {
    int r = tr + i * 8;
    tile[r][tc] = f2bf(ib[(long)(r0 + r) * Cc + c0 + tc]);
  }
  __syncthreads();
#pragma unroll
  for (int i = 0; i < 4; ++i) {
    int c = tr + i * 8;
    int row = c0 + c;
    int k = r0 + tc;
    if (TI == 0) ob[(long)row * Rr + k] = tile[tc][c];
    else ob[(long)row * Rr + (k ^ ((row & 7) << 3))] = tile[tc][c];
  }
}

// big convert+transpose for pin/pout: in [Rr k][Cc n] fp32 -> out tiled bf16 [n][k].
__global__ __launch_bounds__(256) void trans_big_k(const float* __restrict__ in,
                                                   unsigned short* __restrict__ out,
                                                   int Rr, int Cc) {
  __shared__ float t[64][64];
  const float* ib = in + (long)blockIdx.z * Rr * Cc;
  unsigned short* ob = out + (long)blockIdx.z * (long)Rr * Cc;
  int k0 = blockIdx.y * 64, n0 = blockIdx.x * 64;
  int tid = threadIdx.x;
#pragma unroll
  for (int p = 0; p < 4; ++p) {
    int idx = p * 256 + tid;
    int kr = idx >> 4, nc = (idx & 15) * 4;
    *(float4*)&t[kr][nc] = *(const float4*)(ib + (long)(k0 + kr) * Cc + n0 + nc);
  }
  __syncthreads();
#pragma unroll
  for (int p = 0; p < 2; ++p) {
    int idx = p * 256 + tid;
    int n = idx & 63, kc = idx >> 6;       // kc 0..7
    float v[8];
#pragma unroll
    for (int u = 0; u < 8; ++u) v[u] = t[kc * 8 + u][n];
    uint4 o;
    o.x = pk2bf(v[0], v[1]); o.y = pk2bf(v[2], v[3]);
    o.z = pk2bf(v[4], v[5]); o.w = pk2bf(v[6], v[7]);
    *(uint4*)(ob + tiled_off(n0 + n, k0 + kc * 8, Rr)) = o;
  }
}

// GEMM1: mvB(bf16, linear [token][512]) = x @ Pin^T per expert. 256x256 tile, BK=64,
// quantum-pipelined (r10 structure).
__global__ __launch_bounds__(512, 1) void gemm_in_k(const unsigned short* __restrict__ Xb,
                                                    const unsigned short* __restrict__ Bw,
                                                    unsigned short* __restrict__ MvB,
                                                    const int* __restrict__ offs) {
  extern __shared__ char smem[];    // [2 buf][ A 32K | B 32K ], each op as 2 x 16K ksub
  int bid = blockIdx.x;             // 256 blocks
  int wg = (bid & 7) * 32 + (bid >> 3);      // XCD swizzle (256 % 8 == 0)
  int e = wg >> 4, rem = wg & 15, bm = rem >> 1, bn = rem & 1;
  int tid = threadIdx.x, wid = tid >> 6, lane = tid & 63;
  int wm = (wid >> 2) * 128, wn = (wid & 3) * 64;
  int ri = lane & 15, hi = lane >> 4;
  long aw = ((long)offs[e] >> 3) + bm * 32;  // A window base (xb tiled, K=1024)
  long bw = (long)e * 64 + bn * 32;          // B window base (pinT tiled, K=1024)

  auto STG = [&](int b, int kt, int s, int op) {
    const unsigned short* src = op ? Bw : Xb;
    long wbase = op ? bw : aw;
    char* dst = smem + b * 65536 + op * 32768 + s * 16384;
#pragma unroll
    for (int i = 0; i < 2; ++i) {
      int d = i * 512 + tid;
      async16(src + (wbase + (d >> 5)) * 8192 +
                  (long)((kt * 8 + s * 4 + ((d >> 3) & 3)) * 64 + (d & 7) * 8),
              (unsigned short*)(dst + d * 16));
    }
  };

  f32x4 acc[8][4];
#pragma unroll
  for (int i = 0; i < 8; ++i)
#pragma unroll
    for (int j = 0; j < 4; ++j) acc[i][j] = (f32x4){0.f, 0.f, 0.f, 0.f};

  STG(0, 0, 0, 0); STG(0, 0, 0, 1); STG(0, 0, 1, 0); STG(0, 0, 1, 1);

  for (int t = 0; t < 16; ++t) {
    int c = t & 1;
    const char* cA = smem + c * 65536;
    const char* cB = smem + c * 65536 + 32768;
#pragma unroll
    for (int s = 0; s < 2; ++s) {
      if (t < 15) {
        STG(c ^ 1, t + 1, s, 0);
        STG(c ^ 1, t + 1, s, 1);
        asm volatile("s_waitcnt vmcnt(8)" ::: "memory");
      } else if (s == 0) {
        asm volatile("s_waitcnt vmcnt(4)" ::: "memory");
      } else {
        asm volatile("s_waitcnt vmcnt(0)" ::: "memory");
      }
      sbar();
      bf16x8 a[8], b[4];
#pragma unroll
      for (int i = 0; i < 8; ++i) a[i] = ld_frag(cA + s * 16384, wm + i * 16 + ri, hi);
#pragma unroll
      for (int j = 0; j < 4; ++j) b[j] = ld_frag(cB + s * 16384, wn + j * 16 + ri, hi);
      __builtin_amdgcn_s_setprio(1);
#pragma unroll
      for (int i = 0; i < 8; ++i)
#pragma unroll
        for (int j = 0; j < 4; ++j)
          acc[i][j] = __builtin_amdgcn_mfma_f32_16x16x32_bf16(a[i], b[j], acc[i][j], 0, 0, 0);
      __builtin_amdgcn_s_setprio(0);
    }
  }

  unsigned short* Cb = MvB + ((long)e * 2048 + (long)bm * 256) * 512 + bn * 256;
#pragma unroll
  for (int i = 0; i < 8; ++i)
#pragma unroll
    for (int j = 0; j < 4; ++j)
#pragma unroll
      for (int rr = 0; rr < 4; ++rr)
        Cb[(long)(wm + i * 16 + hi * 4 + rr) * 512 + wn + j * 16 + ri] =
            f2bf1(acc[i][j][rr]);
}

// ---------- merged 2-round fused kernel: 4 TOKENS PER WAVE ----------
// 16 tokens/block, 256 threads = 4 waves; each wave owns 4 tokens (32 trows)
// END-TO-END. Per F-eighth a wave runs 24 MFMAs (16 gate/up over 2 trow-tiles
// + 8 down) against the SAME per-phase fixed costs as 2-tok/wave (8 W ds_reads,
// 4 Wd global loads, 1 stage, 1 barrier, addressing) -> per-phase-fixed
// instruction count per unit work HALVES (r4 lesson: aggregate-issue-bound,
// VALU inst/wave ~3x source estimate). Wd loads issued at PHASE TOP ->
// full-phase (~400cy) latency cover instead of ~100cy.
// sFlat/sH/sMvh WAVE-PRIVATE (no barriers). W staging dbuf in eighths, one
// barrier per phase, full-phase prefetch distance (r4 structure).
// LDS 48K -> 3 blocks/CU at __launch_bounds__(256,3): VGPR cap 170 (~140
// needed, no spill; r1/r2 lesson: starved caps spill to scratch).
//   sFH  @0     16K: 4 waves x 4K  [32 trow][128B] xor (ri&7)<<4 (flat, then h)
//   sMv  @16K   16K: 4 waves x 4K  [4 tok][8 blade][128B] xor (blade)<<4
//   sW   @32K   16K: dbuf x (Wg 4K | Wu 4K) eighth (swizzle baked in global)
__global__ __launch_bounds__(256, 3) void rounds_k(
    const unsigned short* __restrict__ MvB, const unsigned short* __restrict__ WgT,
    const unsigned short* __restrict__ WuT, const unsigned short* __restrict__ WdT,
    const float* __restrict__ wcomb, const float* __restrict__ lnw,
    const float* __restrict__ lnb, unsigned short* __restrict__ Mvb) {
  extern __shared__ char smem[];
  int tid = threadIdx.x, wid = tid >> 6, lane = tid & 63;
  char* sFH = smem + wid * 4096;            // wave-private [32 trow][128B]
  char* sMv = smem + 16384 + wid * 4096;    // wave-private [4 tok][1K]
  char* sW  = smem + 32768;                 // dbuf 2 x 8K (Wg 4K | Wu 4K)

  int bid = blockIdx.x;
  int wg = (bid & 7) * 256 + (bid >> 3);    // XCD swizzle (2048 % 8 == 0)
  int e = wg >> 7, bx = wg & 127;

  int t4 = lane >> 4, q = lane & 15;        // P1 coords: token-in-wave, d-quad
  int ri = lane & 15, hi = lane >> 4;       // frag coords
  int sw = (ri & 7) << 4;

  // stage global eighth i8 (0..15; round = i8>>3, slice = i8&7)
  auto STAGE = [&](int i8) {
    long base = (long)(e * 2 + (i8 >> 3)) * 16384 + (i8 & 7) * 2048;
    char* dst = sW + (i8 & 1) * 8192;
    async16(WgT + base + tid * 8, (unsigned short*)(dst + tid * 16));
    async16(WuT + base + tid * 8, (unsigned short*)(dst + 4096 + tid * 16));
  };
  STAGE(0);   // prologue: lands under P1 of round 0

#pragma unroll 1
  for (int r = 0; r < 2; ++r) {
    int er = e * 2 + r;
    const unsigned short* wd = WdT + (long)er * 16384;  // [64 dout][256 F]

    // ---- P1a: mv (global bf16 on r0 -> stash to sMvh; sMvh on r1) ----
    f32x4 mv[8];
    if (r == 0) {
      long base = ((long)e * 2048 + bx * 16 + wid * 4 + t4) * 512 + 4 * q;
      uint2 uv[8];
#pragma unroll
      for (int i = 0; i < 8; ++i)
        uv[i] = *(const uint2*)(MvB + base + i * 64);
#pragma unroll
      for (int i = 0; i < 8; ++i) {
        *(uint2*)(sMv + t4 * 1024 + i * 128 + ((8 * q) ^ (i << 4))) = uv[i];
        mv[i] = (f32x4){bf2f((unsigned short)(uv[i].x & 0xffff)),
                        bf2f((unsigned short)(uv[i].x >> 16)),
                        bf2f((unsigned short)(uv[i].y & 0xffff)),
                        bf2f((unsigned short)(uv[i].y >> 16))};
      }
    } else {
#pragma unroll
      for (int i = 0; i < 8; ++i) {
        uint2 uv = *(const uint2*)(sMv + t4 * 1024 + i * 128 + ((8 * q) ^ (i << 4)));
        mv[i] = (f32x4){bf2f((unsigned short)(uv.x & 0xffff)),
                        bf2f((unsigned short)(uv.x >> 16)),
                        bf2f((unsigned short)(uv.y & 0xffff)),
                        bf2f((unsigned short)(uv.y >> 16))};
      }
    }

    // ---- P1b: geo + mix + LN(64) -> sFH (packed f32x4 math; wave-private) ----
    {
      const float* C = wcomb + er * 40;
      f32x4 g[8];
#pragma unroll
      for (int k = 0; k < 8; ++k) g[k] = (f32x4){0.f, 0.f, 0.f, 0.f};
#pragma unroll
      for (int i = 0; i < 8; ++i)
#pragma unroll
        for (int j = i; j < 8; ++j) {
          float cc = C[PIDX(i, j)];
          const int k = KIDX(i, j);
          g[k] += cc * (mv[i] * mv[j]);
        }
      float omg = C[36];
#pragma unroll
      for (int k = 0; k < 8; ++k) g[k] = omg * mv[k] + g[k];
      float4 lw = *(const float4*)(lnw + (long)er * 64 + 4 * q);
      float4 lb = *(const float4*)(lnb + (long)er * 64 + 4 * q);
      f32x4 lwv = (f32x4){lw.x, lw.y, lw.z, lw.w};
      f32x4 lbv = (f32x4){lb.x, lb.y, lb.z, lb.w};
#pragma unroll
      for (int half = 0; half < 2; ++half) {
        f32x2 red[4];
#pragma unroll
        for (int k = 0; k < 4; ++k) {
          f32x4 m = g[half * 4 + k];
          red[k].x = (m.x + m.y) + (m.z + m.w);
          red[k].y = fmaf(m.x, m.x, m.y * m.y) + fmaf(m.z, m.z, m.w * m.w);
        }
#pragma unroll
        for (int off = 8; off >= 1; off >>= 1)
#pragma unroll
          for (int t = 0; t < 4; ++t) {
            f32x2 o;
            o.x = __shfl_xor(red[t].x, off);
            o.y = __shfl_xor(red[t].y, off);
            red[t] += o;
          }
#pragma unroll
        for (int k = 0; k < 4; ++k) {
          int kk = half * 4 + k;
          float mean = red[k].x * (1.f / 64.f);
          float var = red[k].y * (1.f / 64.f) - mean * mean;
          float rs = rsqrtf(var + 1e-5f);
          f32x4 nv = (g[kk] - mean) * rs;
          f32x4 ov = nv * lwv + lbv;
          uint2 pv;
          pv.x = pk2bf(ov.x, ov.y);
          pv.y = pk2bf(ov.z, ov.w);
          int row = t4 * 8 + kk;                    // row&7 == kk
          *(uint2*)(sFH + row * 128 + ((8 * q) ^ (kk << 4))) = pv;
        }
      }
    }
    wait_lgkm0();   // own-wave flat writes done (cross-LANE reads next)

    // ---- hoist flat B-frags to regs (sFH gets reused for h afterwards) ----
    bf16x8 bfr[2][2];   // [trow-tile][k-half]
#pragma unroll
    for (int tt = 0; tt < 2; ++tt)
#pragma unroll
      for (int kt = 0; kt < 2; ++kt)
        bfr[tt][kt] = *(const bf16x8*)(sFH + (tt * 16 + ri) * 128 + ((kt * 64 + hi * 16) ^ sw));

    f32x4 acc2[4][2];
#pragma unroll
    for (int j = 0; j < 4; ++j)
#pragma unroll
      for (int tt = 0; tt < 2; ++tt) acc2[j][tt] = (f32x4){0.f, 0.f, 0.f, 0.f};

#pragma unroll 1
    for (int q8 = 0; q8 < 8; ++q8) {
      int i8 = r * 8 + q8;
      wait_vm0();   // stage(i8) landed (issued a full eighth ago)
      sbar();       // all waves: stage(i8) in LDS; eighth i8-1 reads done
      if (i8 < 15) STAGE(i8 + 1);   // -> buf((i8+1)&1): free per the barrier

      // ---- Wd frags at PHASE TOP (global; full-phase latency cover) ----
      bf16x8 wdf[4];
#pragma unroll
      for (int j = 0; j < 4; ++j)
        wdf[j] = *(const bf16x8*)(wd + (j * 16 + ri) * 256 + q8 * 32 + hi * 8);

      const char* bufW = sW + (i8 & 1) * 8192;

      // ---- P2: 2 F-tiles x 2 trow-tiles; silu -> h ----
#pragma unroll
      for (int ftl = 0; ftl < 2; ++ftl) {
        const char* bg = bufW + (ftl * 16 + ri) * 128;
        const char* bu = bg + 4096;
        bf16x8 wg0 = *(const bf16x8*)(bg + ((hi * 16) ^ sw));
        bf16x8 wg1 = *(const bf16x8*)(bg + ((64 + hi * 16) ^ sw));
        bf16x8 wu0 = *(const bf16x8*)(bu + ((hi * 16) ^ sw));
        bf16x8 wu1 = *(const bf16x8*)(bu + ((64 + hi * 16) ^ sw));
        f32x4 ag[2], au[2];
#pragma unroll
        for (int tt = 0; tt < 2; ++tt) {
          ag[tt] = (f32x4){0.f, 0.f, 0.f, 0.f};
          au[tt] = (f32x4){0.f, 0.f, 0.f, 0.f};
        }
        __builtin_amdgcn_s_setprio(1);
#pragma unroll
        for (int tt = 0; tt < 2; ++tt) {
          ag[tt] = __builtin_amdgcn_mfma_f32_16x16x32_bf16(wg0, bfr[tt][0], ag[tt], 0, 0, 0);
          au[tt] = __builtin_amdgcn_mfma_f32_16x16x32_bf16(wu0, bfr[tt][0], au[tt], 0, 0, 0);
          ag[tt] = __builtin_amdgcn_mfma_f32_16x16x32_bf16(wg1, bfr[tt][1], ag[tt], 0, 0, 0);
          au[tt] = __builtin_amdgcn_mfma_f32_16x16x32_bf16(wu1, bfr[tt][1], au[tt], 0, 0, 0);
        }
        __builtin_amdgcn_s_setprio(0);
#pragma unroll
        for (int tt = 0; tt < 2; ++tt) {
          float hh[4];
#pragma unroll
          for (int rr = 0; rr < 4; ++rr) {
            float gv = ag[tt][rr], uu = au[tt][rr];
            hh[rr] = gv * uu * frcp(1.f + __expf(-gv));
          }
          uint2 hwv;
          hwv.x = pk2bf(hh[0], hh[1]);
          hwv.y = pk2bf(hh[2], hh[3]);
          // h (F_loc = ftl*16+hi*4+rr, trow = tt*16+ri) -> swizzled
          *(uint2*)(sFH + (tt * 16 + ri) * 128 + ((ftl * 32 + hi * 8) ^ sw)) = hwv;
        }
      }
      wait_lgkm0();  // own h writes complete before hk reads

      // ---- P4: acc2[dout][trow-tile] += Wd x h (one 32-k chunk) ----
      bf16x8 hk0 = *(const bf16x8*)(sFH + ri * 128 + ((hi * 16) ^ sw));
      bf16x8 hk1 = *(const bf16x8*)(sFH + (16 + ri) * 128 + ((hi * 16) ^ sw));
      __builtin_amdgcn_s_setprio(1);
#pragma unroll
      for (int j = 0; j < 4; ++j)
        acc2[j][0] = __builtin_amdgcn_mfma_f32_16x16x32_bf16(wdf[j], hk0, acc2[j][0], 0, 0, 0);
#pragma unroll
      for (int j = 0; j < 4; ++j)
        acc2[j][1] = __builtin_amdgcn_mfma_f32_16x16x32_bf16(wdf[j], hk1, acc2[j][1], 0, 0, 0);
      __builtin_amdgcn_s_setprio(0);
    }

    // ---- P5: residual vs sMvh (wave-private, in place both rounds) ----
    {
#pragma unroll
      for (int tt = 0; tt < 2; ++tt) {
        int tl = tt * 2 + (ri >> 3);
        int kb = ri & 7;
#pragma unroll
        for (int j = 0; j < 4; ++j)
#pragma unroll
          for (int u = 0; u < 2; ++u) {
            int off = (j * 32 + hi * 8 + 4 * u) ^ sw;
            unsigned* p = (unsigned*)(sMv + tl * 1024 + kb * 128 + off);
            unsigned old = *p;
            float v0 = bf2f((unsigned short)(old & 0xffff)) + acc2[j][tt][2 * u];
            float v1 = bf2f((unsigned short)(old >> 16)) + acc2[j][tt][2 * u + 1];
            *p = pk2bf(v0, v1);
          }
      }
    }
    wait_lgkm0();   // sMvh updates done (next round's P1a / epilogue reads)

    // ---- r1: coalesced uint4 dump sMvh -> Mvb (linear [token][512]) ----
    if (r == 1) {
      int tt = lane >> 4;              // token-in-wave 0..3
      int idx = lane & 15;
      int bl = idx >> 1;               // blade 0..7
      int c2 = idx & 1;                // 64B chunk 0..1
      const char* src = sMv + tt * 1024 + bl * 128;
      long row = (long)e * 2048 + bx * 16 + wid * 4 + tt;
      unsigned short* dst = Mvb + row * 512 + bl * 64 + c2 * 32;
#pragma unroll
      for (int h = 0; h < 4; ++h) {
        uint4 v = *(const uint4*)(src + ((c2 * 64 + h * 16) ^ (bl << 4)));
        *(uint4*)(dst + h * 8) = v;
      }
    }
  }
}

// ---------- fused out-projection + LayerNorm(D=1024), 512 threads/block ----------
// A (mvb) is LINEAR [token][512] bf16; tiled LDS layout derived via per-lane source addr.
__global__ __launch_bounds__(512, 2) void gemm_out_ln_k(
    const unsigned short* __restrict__ Mvb, const unsigned short* __restrict__ Pw,
    float* __restrict__ Out, const float* __restrict__ ow, const float* __restrict__ ob,
    const int* __restrict__ offs) {
  extern __shared__ char smem[];
  int bid = blockIdx.x;
  int wg = (bid & 7) * 64 + (bid >> 3);
  int e = wg >> 5, mb = wg & 31;
  int tid = threadIdx.x, wid = tid >> 6, lane = tid & 63;
  int ri = lane & 15, hi = lane >> 4;
  long bbase = (long)e * 524288;                 // poutT expert base (tiled)
  long arow0 = (long)e * 2048 + (long)mb * 64;   // mvb expert row base (linear)

  auto STAGE = [&](int buf, int kt) {
#pragma unroll
    for (int i = 0; i < 8; ++i) {
      int q = i * 512 + tid;
      int w = q >> 5, c = (q >> 3) & 3, rr = q & 7;
      async16(Pw + bbase + (long)w * 4096 + (kt * 4 + c) * 64 + rr * 8,
              (unsigned short*)(smem + buf * 65536 + q * 16));
    }
    if (tid < 256) {
      int q = tid;
      int w = q >> 5, c = (q >> 3) & 3, rr = q & 7;
      async16(Mvb + (arow0 + w * 8 + rr) * 512 + kt * 32 + c * 8,
              (unsigned short*)(smem + 131072 + buf * 4096 + q * 16));
    }
  };

  f32x4 acc[4][8];
#pragma unroll
  for (int i = 0; i < 4; ++i)
#pragma unroll
    for (int j = 0; j < 8; ++j) acc[i][j] = (f32x4){0.f, 0.f, 0.f, 0.f};

  STAGE(0, 0);
  for (int kt = 0; kt < 16; ++kt) {
    int cur = kt & 1;
    if (kt < 15) {
      STAGE(cur ^ 1, kt + 1);
      asm volatile("s_waitcnt vmcnt(8)" ::: "memory");
    } else {
      asm volatile("s_waitcnt vmcnt(0)" ::: "memory");
    }
    sbar();
    const char* cB = smem + cur * 65536;
    const char* cA = smem + 131072 + cur * 4096;
    bf16x8 a[4], b[8];
#pragma unroll
    for (int i = 0; i < 4; ++i) a[i] = ld_frag(cA, i * 16 + ri, hi);
#pragma unroll
    for (int j = 0; j < 8; ++j) b[j] = ld_frag(cB, wid * 128 + j * 16 + ri, hi);
    __builtin_amdgcn_s_setprio(1);
#pragma unroll
    for (int i = 0; i < 4; ++i)
#pragma unroll
      for (int j = 0; j < 8; ++j)
        acc[i][j] = __builtin_amdgcn_mfma_f32_16x16x32_bf16(a[i], b[j], acc[i][j], 0, 0, 0);
    __builtin_amdgcn_s_setprio(0);
    sbar();
  }

  float* rsum = (float*)(smem + 139264);
  float* rsq  = (float*)(smem + 141312);
  float* mexp = (float*)(smem + 143360);
  float* rstd = (float*)(smem + 143616);
  int hi4 = hi * 4;
#pragma unroll
  for (int i = 0; i < 4; ++i)
#pragma unroll
    for (int rr = 0; rr < 4; ++rr) {
      float s = 0.f, qv = 0.f;
#pragma unroll
      for (int j = 0; j < 8; ++j) { float v = acc[i][j][rr]; s += v; qv += v * v; }
#pragma unroll
      for (int off = 1; off < 16; off <<= 1) {
        s += __shfl_xor(s, off);
        qv += __shfl_xor(qv, off);
      }
      if (ri == 0) {
        int row = i * 16 + hi4 + rr;
        rsum[row * 8 + wid] = s;
        rsq[row * 8 + wid] = qv;
      }
    }
  __syncthreads();
  if (tid < 64) {
    float S = 0.f, Q = 0.f;
#pragma unroll
    for (int w = 0; w < 8; ++w) { S += rsum[tid * 8 + w]; Q += rsq[tid * 8 + w]; }
    float mean = S * (1.f / 1024.f);
    float var = Q * (1.f / 1024.f) - mean * mean;
    mexp[tid] = mean;
    rstd[tid] = rsqrtf(var + 1e-5f);
  }
  __syncthreads();
  long r0 = (long)offs[e] + (long)mb * 64;
  float owv[8], obv[8];
#pragma unroll
  for (int j = 0; j < 8; ++j) {
    int col = wid * 128 + j * 16 + ri;
    owv[j] = ow[col];
    obv[j] = ob[col];
  }
#pragma unroll
  for (int i = 0; i < 4; ++i)
#pragma unroll
    for (int rr = 0; rr < 4; ++rr) {
      int row = i * 16 + hi4 + rr;
      float mu = mexp[row], rs = rstd[row];
#pragma unroll
      for (int j = 0; j < 8; ++j) {
        int col = wid * 128 + j * 16 + ri;
        Out[(r0 + row) * 1024 + col] = (acc[i][j][rr] - mu) * rs * owv[j] + obv[j];
      }
    }
}

// ---------- host ----------
extern "C" void kernel_launch(void* const* d_in, const int* in_sizes, int n_in,
                              void* d_out, int out_size, void* d_ws, size_t ws_size,
                              hipStream_t stream) {
  const float* x    = (const float*)d_in[0];
  const float* pin  = (const float*)d_in[1];
  const float* pout = (const float*)d_in[2];
  const float* iw   = (const float*)d_in[3];
  const float* gg   = (const float*)d_in[4];
  const float* fg   = (const float*)d_in[5];
  const float* fu   = (const float*)d_in[6];
  const float* fd   = (const float*)d_in[7];
  const float* lnw  = (const float*)d_in[8];
  const float* lnb  = (const float*)d_in[9];
  const float* ow   = (const float*)d_in[10];
  const float* ob   = (const float*)d_in[11];
  const int* offs   = (const int*)d_in[12];

  char* ws = (char*)d_ws;
  unsigned short* mvB  = (unsigned short*)(ws + 0L);          //  33,554,432 B (linear bf16)
  unsigned short* mvb  = (unsigned short*)(ws + 33554432L);   //  33,554,432 B (linear bf16)
  unsigned short* pinT = (unsigned short*)(ws + 67108864L);   //  16,777,216 B (tiled)
  unsigned short* poutT= (unsigned short*)(ws + 83886080L);   //  16,777,216 B (tiled)
  unsigned short* wgT  = (unsigned short*)(ws + 100663296L);  //   2,097,152 B (swz-64)
  unsigned short* wuT  = (unsigned short*)(ws + 102760448L);  //   2,097,152 B (swz-64)
  unsigned short* wdT  = (unsigned short*)(ws + 104857600L);  //   2,097,152 B (plain)
  float* wcomb         = (float*)(ws + 106954752L);           //   5,120 B
  unsigned short* xb   = (unsigned short*)(ws + 117440512L);  //  67,108,864 B (tiled)

  // prep
  convert_k<<<dim3(4096), dim3(256), 0, stream>>>(x, xb, 4194304L);
  trans_big_k<<<dim3(8, 16, 16), dim3(256), 0, stream>>>(pin, pinT, 1024, 512);
  trans_big_k<<<dim3(16, 8, 16), dim3(256), 0, stream>>>(pout, poutT, 512, 1024);
  transpose_k<1><<<dim3(8, 2, 32), dim3(256), 0, stream>>>(fg, wgT, 64, 256);
  transpose_k<1><<<dim3(8, 2, 32), dim3(256), 0, stream>>>(fu, wuT, 64, 256);
  transpose_k<0><<<dim3(2, 8, 32), dim3(256), 0, stream>>>(fd, wdT, 256, 64);
  geoprep_k<<<dim3(1), dim3(64), 0, stream>>>(iw, gg, wcomb);

  // mvB = x @ Pin (bf16 linear out; 256x256 quantum-pipelined)
  gemm_in_k<<<dim3(256), dim3(512), 131072, stream>>>(xb, pinT, mvB, offs);

  // both rounds in ONE kernel; 4 tokens/wave, W dbuf in eighths, 48K LDS
  rounds_k<<<dim3(2048), dim3(256), 49152, stream>>>(
      mvB, wgT, wuT, wdT, wcomb, lnw, lnb, mvb);

  // out = LN(mvb @ Pout)
  gemm_out_ln_k<<<dim3(512), dim3(512), 143872, stream>>>(
      mvb, poutT, (float*)d_out, ow, ob, offs);
}

// Round 6
// 274.375 us; speedup vs baseline: 1.9490x; 1.1995x over previous
//
#include <hip/hip_runtime.h>

#define DEV __device__ __forceinline__

typedef __attribute__((ext_vector_type(4))) float f32x4;
typedef __attribute__((ext_vector_type(2))) float f32x2;
typedef __attribute__((ext_vector_type(8))) short bf16x8;

// Shapes: E=16, D=1024, ED=512, NB=8, DB=64, R=2, F=256, N=32768, C=2048

// ---------- helpers ----------
DEV unsigned short f2bf(float f) {
  union { float f; unsigned u; } v; v.f = f;
  unsigned r = v.u + 0x7fffu + ((v.u >> 16) & 1u);
  return (unsigned short)(r >> 16);
}

DEV unsigned pk2bf(float lo, float hi) {  // v_cvt_pk_bf16_f32 (RNE)
  unsigned r;
  asm("v_cvt_pk_bf16_f32 %0, %1, %2" : "=v"(r) : "v"(lo), "v"(hi));
  return r;
}
DEV unsigned short f2bf1(float v) { return (unsigned short)pk2bf(v, v); }

DEV float bf2f(unsigned short b) {
  union { unsigned u; float f; } v; v.u = ((unsigned)b) << 16; return v.f;
}

DEV float frcp(float x) { return __builtin_amdgcn_rcpf(x); }

// raw barrier: NO implicit vmcnt drain. "memory" clobber = compiler fence.
DEV void sbar() { asm volatile("s_barrier" ::: "memory"); }
DEV void wait_lgkm0() { asm volatile("s_waitcnt lgkmcnt(0)" ::: "memory"); }
DEV void wait_vm0() { asm volatile("s_waitcnt vmcnt(0)" ::: "memory"); }

DEV void async16(const unsigned short* g, unsigned short* l) {
  __builtin_amdgcn_global_load_lds(
      (__attribute__((address_space(1))) const unsigned int*)g,
      (__attribute__((address_space(3))) unsigned int*)l, 16, 0, 0);
}

// Tiled global layout for GEMM operands: element (n,k) of an [N][K] panel at
//   (n>>3)*8K + (k>>3)*64 + (n&7)*8 + (k&7)
DEV long tiled_off(long n, int k, int K) {
  return (n >> 3) * (8L * K) + (long)(((k >> 3) * 64) + ((int)(n & 7)) * 8 + (k & 7));
}

// frag read from a tiled 32-k LDS subtile (bf16)
DEV bf16x8 ld_frag(const char* s, int row, int hi) {
  return *(const bf16x8*)(s + ((row >> 3) * 512 + hi * 128 + (row & 7) * 16));
}

// ---------- Cayley table at compile time ----------
__host__ __device__ constexpr int km_(int i) { return i==0?0:i==1?1:i==2?2:i==3?4:i==4?3:i==5?5:i==6?6:7; }
__host__ __device__ constexpr int pc_(int x) { int c = 0; while (x) { c += x & 1; x >>= 1; } return c; }
__host__ __device__ constexpr int KIDX(int i, int j) { return km_(km_(i) ^ km_(j)); }
__host__ __device__ constexpr int CSGN(int i, int j) {
  int a = km_(i), b = km_(j), aa = a >> 1, s = 0;
  while (aa) { s += pc_(aa & b); aa >>= 1; }
  return (s & 1) ? -1 : 1;
}
__host__ __device__ constexpr int PIDX(int i, int j) {  // i<=j
  return 8 * i - (i * (i - 1)) / 2 + (j - i);
}

// ---------- small kernels ----------
__global__ __launch_bounds__(64) void geoprep_k(const float* __restrict__ iw,
                                                const float* __restrict__ gg,
                                                float* __restrict__ wcomb) {
  int er = threadIdx.x;
  if (er >= 32) return;
  const float* w = iw + er * 64;
  float gate = frcp(1.f + __expf(-gg[er]));
  float* c = wcomb + er * 40;
  int p = 0;
  for (int i = 0; i < 8; ++i)
    for (int j = i; j < 8; ++j) {
      float v = (float)CSGN(i, j) * frcp(1.f + __expf(-w[i * 8 + j]));
      if (j > i) v += (float)CSGN(j, i) * frcp(1.f + __expf(-w[j * 8 + i]));
      c[p++] = gate * v;
    }
  c[36] = 1.f - gate;
}

// small transposes (wg/wu/wd): in (Rr,Cc) fp32 (batch z) -> (Cc,Rr) bf16.
// TI=0 linear; TI=1: k ^= (row&7)<<3 (needs Rr==64).
template<int TI>
__global__ __launch_bounds__(256) void transpose_k(const float* __restrict__ in,
                                                   unsigned short* __restrict__ out,
                                                   int Rr, int Cc) {
  __shared__ unsigned short tile[32][33];
  const float* ib = in + (long)blockIdx.z * Rr * Cc;
  unsigned short* ob = out + (long)blockIdx.z * Rr * Cc;
  int r0 = blockIdx.y * 32, c0 = blockIdx.x * 32;
  int tr = threadIdx.x >> 5, tc = threadIdx.x & 31;
#pragma unroll
  for (int i = 0; i < 4; ++i) {
    int r = tr + i * 8;
    tile[r][tc] = f2bf(ib[(long)(r0 + r) * Cc + c0 + tc]);
  }
  __syncthreads();
#pragma unroll
  for (int i = 0; i < 4; ++i) {
    int c = tr + i * 8;
    int row = c0 + c;
    int k = r0 + tc;
    if (TI == 0) ob[(long)row * Rr + k] = tile[tc][c];
    else ob[(long)row * Rr + (k ^ ((row & 7) << 3))] = tile[tc][c];
  }
}

// big convert+transpose for pin/pout: in [Rr k][Cc n] fp32 -> out tiled bf16 [n][k].
__global__ __launch_bounds__(256) void trans_big_k(const float* __restrict__ in,
                                                   unsigned short* __restrict__ out,
                                                   int Rr, int Cc) {
  __shared__ float t[64][64];
  const float* ib = in + (long)blockIdx.z * Rr * Cc;
  unsigned short* ob = out + (long)blockIdx.z * (long)Rr * Cc;
  int k0 = blockIdx.y * 64, n0 = blockIdx.x * 64;
  int tid = threadIdx.x;
#pragma unroll
  for (int p = 0; p < 4; ++p) {
    int idx = p * 256 + tid;
    int kr = idx >> 4, nc = (idx & 15) * 4;
    *(float4*)&t[kr][nc] = *(const float4*)(ib + (long)(k0 + kr) * Cc + n0 + nc);
  }
  __syncthreads();
#pragma unroll
  for (int p = 0; p < 2; ++p) {
    int idx = p * 256 + tid;
    int n = idx & 63, kc = idx >> 6;       // kc 0..7
    float v[8];
#pragma unroll
    for (int u = 0; u < 8; ++u) v[u] = t[kc * 8 + u][n];
    uint4 o;
    o.x = pk2bf(v[0], v[1]); o.y = pk2bf(v[2], v[3]);
    o.z = pk2bf(v[4], v[5]); o.w = pk2bf(v[6], v[7]);
    *(uint4*)(ob + tiled_off(n0 + n, k0 + kc * 8, Rr)) = o;
  }
}

// GEMM1 (convert FUSED): mvB(bf16, linear [token][512]) = x @ Pin^T per expert.
// 256x256 tile, BK=64 in two 32-sub-phases. B staged via async16 from tiled
// pinT (unchanged). A staged from x fp32 DIRECTLY: reg-load (4x dwordx4) ->
// v_cvt_pk_bf16_f32 -> ds_write_b128 into the IDENTICAL tiled LDS layout
// (T14 split: loads for phase p+2 issued at phase top; cvt+write after MFMA;
// compiler auto-waits the A-regs). Kills convert_k + the xb buffer (~200 MB
// round-trip). bn-pair blocks share A lines in the same XCD L2 (swizzle maps
// bid,bid+8 to one XCD) so HBM A-fetch stays ~1x.
__global__ __launch_bounds__(512, 1) void gemm_in_k(const float* __restrict__ X,
                                                    const unsigned short* __restrict__ Bw,
                                                    unsigned short* __restrict__ MvB,
                                                    const int* __restrict__ offs) {
  extern __shared__ char smem[];    // [2 buf][ A 32K | B 32K ], each op as 2 x 16K ksub
  int bid = blockIdx.x;             // 256 blocks
  int wg = (bid & 7) * 32 + (bid >> 3);      // XCD swizzle (256 % 8 == 0)
  int e = wg >> 4, rem = wg & 15, bm = rem >> 1, bn = rem & 1;
  int tid = threadIdx.x, wid = tid >> 6, lane = tid & 63;
  int wm = (wid >> 2) * 128, wn = (wid & 3) * 64;
  int ri = lane & 15, hi = lane >> 4;
  long rowbase = (long)offs[e] + bm * 256;   // A row base (x fp32 linear)
  long bw = (long)e * 64 + bn * 32;          // B window base (pinT tiled, K=1024)

  // phase p = t*2+s (t=K-tile 0..15, s=32-k sub 0..1)
  auto STGB = [&](int p) {
    int t = p >> 1, s = p & 1, b = t & 1;
    char* dst = smem + b * 65536 + 32768 + s * 16384;
#pragma unroll
    for (int i = 0; i < 2; ++i) {
      int d = i * 512 + tid;
      async16(Bw + (bw + (d >> 5)) * 8192 +
                  (long)((t * 8 + s * 4 + ((d >> 3) & 3)) * 64 + (d & 7) * 8),
              (unsigned short*)(dst + d * 16));
    }
  };
  auto A_LOAD = [&](int p, float4 ar[2][2]) {
    int t = p >> 1, s = p & 1;
#pragma unroll
    for (int i = 0; i < 2; ++i) {
      int d = i * 512 + tid;
      const float* src = X + (rowbase + ((d >> 5) * 8 + (d & 7))) * 1024 +
                         t * 64 + s * 32 + ((d >> 3) & 3) * 8;
      ar[i][0] = *(const float4*)src;
      ar[i][1] = *(const float4*)(src + 4);
    }
  };
  auto A_WRITE = [&](int p, float4 ar[2][2]) {
    int t = p >> 1, s = p & 1, b = t & 1;
    char* dst = smem + b * 65536 + s * 16384;
#pragma unroll
    for (int i = 0; i < 2; ++i) {
      int d = i * 512 + tid;
      uint4 o;
      o.x = pk2bf(ar[i][0].x, ar[i][0].y);
      o.y = pk2bf(ar[i][0].z, ar[i][0].w);
      o.z = pk2bf(ar[i][1].x, ar[i][1].y);
      o.w = pk2bf(ar[i][1].z, ar[i][1].w);
      *(uint4*)(dst + d * 16) = o;
    }
  };

  f32x4 acc[8][4];
#pragma unroll
  for (int i = 0; i < 8; ++i)
#pragma unroll
    for (int j = 0; j < 4; ++j) acc[i][j] = (f32x4){0.f, 0.f, 0.f, 0.f};

  // prologue: phases 0 and 1 staged (A via regs, B via async16)
  float4 ar[2][2];
  A_LOAD(0, ar); STGB(0); STGB(1);
  A_WRITE(0, ar);                 // compiler auto-waits the A regs
  A_LOAD(1, ar);
  A_WRITE(1, ar);                 // auto vmcnt drains B(0)/B(1) too (landed早 ok)
  wait_lgkm0();

#pragma unroll 2
  for (int p = 0; p < 32; ++p) {
    int t = p >> 1, s = p & 1, c = t & 1;
    if (p < 30) { A_LOAD(p + 2, ar); STGB(p + 2); }
    // drain B(p): outstanding after issue = B(p)2,B(p+1)2,A(p+2)4,B(p+2)2
    if (p < 30) asm volatile("s_waitcnt vmcnt(8)" ::: "memory");
    else if (p == 30) asm volatile("s_waitcnt vmcnt(2)" ::: "memory");
    else asm volatile("s_waitcnt vmcnt(0)" ::: "memory");
    sbar();
    const char* cA = smem + c * 65536 + s * 16384;
    const char* cB = smem + c * 65536 + 32768 + s * 16384;
    bf16x8 a[8], b[4];
#pragma unroll
    for (int i = 0; i < 8; ++i) a[i] = ld_frag(cA, wm + i * 16 + ri, hi);
#pragma unroll
    for (int j = 0; j < 4; ++j) b[j] = ld_frag(cB, wn + j * 16 + ri, hi);
    __builtin_amdgcn_s_setprio(1);
#pragma unroll
    for (int i = 0; i < 8; ++i)
#pragma unroll
      for (int j = 0; j < 4; ++j)
        acc[i][j] = __builtin_amdgcn_mfma_f32_16x16x32_bf16(a[i], b[j], acc[i][j], 0, 0, 0);
    __builtin_amdgcn_s_setprio(0);
    if (p < 30) A_WRITE(p + 2, ar);  // -> buf c^1 sub s (disjoint from any reader)
    wait_lgkm0();                    // ds_writes visible before next barrier
  }

  unsigned short* Cb = MvB + ((long)e * 2048 + (long)bm * 256) * 512 + bn * 256;
#pragma unroll
  for (int i = 0; i < 8; ++i)
#pragma unroll
    for (int j = 0; j < 4; ++j)
#pragma unroll
      for (int rr = 0; rr < 4; ++rr)
        Cb[(long)(wm + i * 16 + hi * 4 + rr) * 512 + wn + j * 16 + ri] =
            f2bf1(acc[i][j][rr]);
}

// ---------- merged 2-round fused kernel: 4 TOKENS PER WAVE ----------
// (unchanged from round 5: 121 us, MfmaUtil 17.7, VGPR 72, no spill)
__global__ __launch_bounds__(256, 3) void rounds_k(
    const unsigned short* __restrict__ MvB, const unsigned short* __restrict__ WgT,
    const unsigned short* __restrict__ WuT, const unsigned short* __restrict__ WdT,
    const float* __restrict__ wcomb, const float* __restrict__ lnw,
    const float* __restrict__ lnb, unsigned short* __restrict__ Mvb) {
  extern __shared__ char smem[];
  int tid = threadIdx.x, wid = tid >> 6, lane = tid & 63;
  char* sFH = smem + wid * 4096;            // wave-private [32 trow][128B]
  char* sMv = smem + 16384 + wid * 4096;    // wave-private [4 tok][1K]
  char* sW  = smem + 32768;                 // dbuf 2 x 8K (Wg 4K | Wu 4K)

  int bid = blockIdx.x;
  int wg = (bid & 7) * 256 + (bid >> 3);    // XCD swizzle (2048 % 8 == 0)
  int e = wg >> 7, bx = wg & 127;

  int t4 = lane >> 4, q = lane & 15;        // P1 coords: token-in-wave, d-quad
  int ri = lane & 15, hi = lane >> 4;       // frag coords
  int sw = (ri & 7) << 4;

  // stage global eighth i8 (0..15; round = i8>>3, slice = i8&7)
  auto STAGE = [&](int i8) {
    long base = (long)(e * 2 + (i8 >> 3)) * 16384 + (i8 & 7) * 2048;
    char* dst = sW + (i8 & 1) * 8192;
    async16(WgT + base + tid * 8, (unsigned short*)(dst + tid * 16));
    async16(WuT + base + tid * 8, (unsigned short*)(dst + 4096 + tid * 16));
  };
  STAGE(0);   // prologue: lands under P1 of round 0

#pragma unroll 1
  for (int r = 0; r < 2; ++r) {
    int er = e * 2 + r;
    const unsigned short* wd = WdT + (long)er * 16384;  // [64 dout][256 F]

    // ---- P1a: mv (global bf16 on r0 -> stash to sMvh; sMvh on r1) ----
    f32x4 mv[8];
    if (r == 0) {
      long base = ((long)e * 2048 + bx * 16 + wid * 4 + t4) * 512 + 4 * q;
      uint2 uv[8];
#pragma unroll
      for (int i = 0; i < 8; ++i)
        uv[i] = *(const uint2*)(MvB + base + i * 64);
#pragma unroll
      for (int i = 0; i < 8; ++i) {
        *(uint2*)(sMv + t4 * 1024 + i * 128 + ((8 * q) ^ (i << 4))) = uv[i];
        mv[i] = (f32x4){bf2f((unsigned short)(uv[i].x & 0xffff)),
                        bf2f((unsigned short)(uv[i].x >> 16)),
                        bf2f((unsigned short)(uv[i].y & 0xffff)),
                        bf2f((unsigned short)(uv[i].y >> 16))};
      }
    } else {
#pragma unroll
      for (int i = 0; i < 8; ++i) {
        uint2 uv = *(const uint2*)(sMv + t4 * 1024 + i * 128 + ((8 * q) ^ (i << 4)));
        mv[i] = (f32x4){bf2f((unsigned short)(uv.x & 0xffff)),
                        bf2f((unsigned short)(uv.x >> 16)),
                        bf2f((unsigned short)(uv.y & 0xffff)),
                        bf2f((unsigned short)(uv.y >> 16))};
      }
    }

    // ---- P1b: geo + mix + LN(64) -> sFH (packed f32x4 math; wave-private) ----
    {
      const float* C = wcomb + er * 40;
      f32x4 g[8];
#pragma unroll
      for (int k = 0; k < 8; ++k) g[k] = (f32x4){0.f, 0.f, 0.f, 0.f};
#pragma unroll
      for (int i = 0; i < 8; ++i)
#pragma unroll
        for (int j = i; j < 8; ++j) {
          float cc = C[PIDX(i, j)];
          const int k = KIDX(i, j);
          g[k] += cc * (mv[i] * mv[j]);
        }
      float omg = C[36];
#pragma unroll
      for (int k = 0; k < 8; ++k) g[k] = omg * mv[k] + g[k];
      float4 lw = *(const float4*)(lnw + (long)er * 64 + 4 * q);
      float4 lb = *(const float4*)(lnb + (long)er * 64 + 4 * q);
      f32x4 lwv = (f32x4){lw.x, lw.y, lw.z, lw.w};
      f32x4 lbv = (f32x4){lb.x, lb.y, lb.z, lb.w};
#pragma unroll
      for (int half = 0; half < 2; ++half) {
        f32x2 red[4];
#pragma unroll
        for (int k = 0; k < 4; ++k) {
          f32x4 m = g[half * 4 + k];
          red[k].x = (m.x + m.y) + (m.z + m.w);
          red[k].y = fmaf(m.x, m.x, m.y * m.y) + fmaf(m.z, m.z, m.w * m.w);
        }
#pragma unroll
        for (int off = 8; off >= 1; off >>= 1)
#pragma unroll
          for (int t = 0; t < 4; ++t) {
            f32x2 o;
            o.x = __shfl_xor(red[t].x, off);
            o.y = __shfl_xor(red[t].y, off);
            red[t] += o;
          }
#pragma unroll
        for (int k = 0; k < 4; ++k) {
          int kk = half * 4 + k;
          float mean = red[k].x * (1.f / 64.f);
          float var = red[k].y * (1.f / 64.f) - mean * mean;
          float rs = rsqrtf(var + 1e-5f);
          f32x4 nv = (g[kk] - mean) * rs;
          f32x4 ov = nv * lwv + lbv;
          uint2 pv;
          pv.x = pk2bf(ov.x, ov.y);
          pv.y = pk2bf(ov.z, ov.w);
          int row = t4 * 8 + kk;                    // row&7 == kk
          *(uint2*)(sFH + row * 128 + ((8 * q) ^ (kk << 4))) = pv;
        }
      }
    }
    wait_lgkm0();   // own-wave flat writes done (cross-LANE reads next)

    // ---- hoist flat B-frags to regs (sFH gets reused for h afterwards) ----
    bf16x8 bfr[2][2];   // [trow-tile][k-half]
#pragma unroll
    for (int tt = 0; tt < 2; ++tt)
#pragma unroll
      for (int kt = 0; kt < 2; ++kt)
        bfr[tt][kt] = *(const bf16x8*)(sFH + (tt * 16 + ri) * 128 + ((kt * 64 + hi * 16) ^ sw));

    f32x4 acc2[4][2];
#pragma unroll
    for (int j = 0; j < 4; ++j)
#pragma unroll
      for (int tt = 0; tt < 2; ++tt) acc2[j][tt] = (f32x4){0.f, 0.f, 0.f, 0.f};

#pragma unroll 1
    for (int q8 = 0; q8 < 8; ++q8) {
      int i8 = r * 8 + q8;
      wait_vm0();   // stage(i8) landed (issued a full eighth ago)
      sbar();       // all waves: stage(i8) in LDS; eighth i8-1 reads done
      if (i8 < 15) STAGE(i8 + 1);   // -> buf((i8+1)&1): free per the barrier

      // ---- Wd frags at PHASE TOP (global; full-phase latency cover) ----
      bf16x8 wdf[4];
#pragma unroll
      for (int j = 0; j < 4; ++j)
        wdf[j] = *(const bf16x8*)(wd + (j * 16 + ri) * 256 + q8 * 32 + hi * 8);

      const char* bufW = sW + (i8 & 1) * 8192;

      // ---- P2: 2 F-tiles x 2 trow-tiles; silu -> h ----
#pragma unroll
      for (int ftl = 0; ftl < 2; ++ftl) {
        const char* bg = bufW + (ftl * 16 + ri) * 128;
        const char* bu = bg + 4096;
        bf16x8 wg0 = *(const bf16x8*)(bg + ((hi * 16) ^ sw));
        bf16x8 wg1 = *(const bf16x8*)(bg + ((64 + hi * 16) ^ sw));
        bf16x8 wu0 = *(const bf16x8*)(bu + ((hi * 16) ^ sw));
        bf16x8 wu1 = *(const bf16x8*)(bu + ((64 + hi * 16) ^ sw));
        f32x4 ag[2], au[2];
#pragma unroll
        for (int tt = 0; tt < 2; ++tt) {
          ag[tt] = (f32x4){0.f, 0.f, 0.f, 0.f};
          au[tt] = (f32x4){0.f, 0.f, 0.f, 0.f};
        }
        __builtin_amdgcn_s_setprio(1);
#pragma unroll
        for (int tt = 0; tt < 2; ++tt) {
          ag[tt] = __builtin_amdgcn_mfma_f32_16x16x32_bf16(wg0, bfr[tt][0], ag[tt], 0, 0, 0);
          au[tt] = __builtin_amdgcn_mfma_f32_16x16x32_bf16(wu0, bfr[tt][0], au[tt], 0, 0, 0);
          ag[tt] = __builtin_amdgcn_mfma_f32_16x16x32_bf16(wg1, bfr[tt][1], ag[tt], 0, 0, 0);
          au[tt] = __builtin_amdgcn_mfma_f32_16x16x32_bf16(wu1, bfr[tt][1], au[tt], 0, 0, 0);
        }
        __builtin_amdgcn_s_setprio(0);
#pragma unroll
        for (int tt = 0; tt < 2; ++tt) {
          float hh[4];
#pragma unroll
          for (int rr = 0; rr < 4; ++rr) {
            float gv = ag[tt][rr], uu = au[tt][rr];
            hh[rr] = gv * uu * frcp(1.f + __expf(-gv));
          }
          uint2 hwv;
          hwv.x = pk2bf(hh[0], hh[1]);
          hwv.y = pk2bf(hh[2], hh[3]);
          // h (F_loc = ftl*16+hi*4+rr, trow = tt*16+ri) -> swizzled
          *(uint2*)(sFH + (tt * 16 + ri) * 128 + ((ftl * 32 + hi * 8) ^ sw)) = hwv;
        }
      }
      wait_lgkm0();  // own h writes complete before hk reads

      // ---- P4: acc2[dout][trow-tile] += Wd x h (one 32-k chunk) ----
      bf16x8 hk0 = *(const bf16x8*)(sFH + ri * 128 + ((hi * 16) ^ sw));
      bf16x8 hk1 = *(const bf16x8*)(sFH + (16 + ri) * 128 + ((hi * 16) ^ sw));
      __builtin_amdgcn_s_setprio(1);
#pragma unroll
      for (int j = 0; j < 4; ++j)
        acc2[j][0] = __builtin_amdgcn_mfma_f32_16x16x32_bf16(wdf[j], hk0, acc2[j][0], 0, 0, 0);
#pragma unroll
      for (int j = 0; j < 4; ++j)
        acc2[j][1] = __builtin_amdgcn_mfma_f32_16x16x32_bf16(wdf[j], hk1, acc2[j][1], 0, 0, 0);
      __builtin_amdgcn_s_setprio(0);
    }

    // ---- P5: residual vs sMvh (wave-private, in place both rounds) ----
    {
#pragma unroll
      for (int tt = 0; tt < 2; ++tt) {
        int tl = tt * 2 + (ri >> 3);
        int kb = ri & 7;
#pragma unroll
        for (int j = 0; j < 4; ++j)
#pragma unroll
          for (int u = 0; u < 2; ++u) {
            int off = (j * 32 + hi * 8 + 4 * u) ^ sw;
            unsigned* p = (unsigned*)(sMv + tl * 1024 + kb * 128 + off);
            unsigned old = *p;
            float v0 = bf2f((unsigned short)(old & 0xffff)) + acc2[j][tt][2 * u];
            float v1 = bf2f((unsigned short)(old >> 16)) + acc2[j][tt][2 * u + 1];
            *p = pk2bf(v0, v1);
          }
      }
    }
    wait_lgkm0();   // sMvh updates done (next round's P1a / epilogue reads)

    // ---- r1: coalesced uint4 dump sMvh -> Mvb (linear [token][512]) ----
    if (r == 1) {
      int tt = lane >> 4;              // token-in-wave 0..3
      int idx = lane & 15;
      int bl = idx >> 1;               // blade 0..7
      int c2 = idx & 1;                // 64B chunk 0..1
      const char* src = sMv + tt * 1024 + bl * 128;
      long row = (long)e * 2048 + bx * 16 + wid * 4 + tt;
      unsigned short* dst = Mvb + row * 512 + bl * 64 + c2 * 32;
#pragma unroll
      for (int h = 0; h < 4; ++h) {
        uint4 v = *(const uint4*)(src + ((c2 * 64 + h * 16) ^ (bl << 4)));
        *(uint4*)(dst + h * 8) = v;
      }
    }
  }
}

// ---------- fused out-projection + LayerNorm(D=1024), 512 threads/block ----------
// A (mvb) is LINEAR [token][512] bf16; tiled LDS layout derived via per-lane source addr.
__global__ __launch_bounds__(512, 2) void gemm_out_ln_k(
    const unsigned short* __restrict__ Mvb, const unsigned short* __restrict__ Pw,
    float* __restrict__ Out, const float* __restrict__ ow, const float* __restrict__ ob,
    const int* __restrict__ offs) {
  extern __shared__ char smem[];
  int bid = blockIdx.x;
  int wg = (bid & 7) * 64 + (bid >> 3);
  int e = wg >> 5, mb = wg & 31;
  int tid = threadIdx.x, wid = tid >> 6, lane = tid & 63;
  int ri = lane & 15, hi = lane >> 4;
  long bbase = (long)e * 524288;                 // poutT expert base (tiled)
  long arow0 = (long)e * 2048 + (long)mb * 64;   // mvb expert row base (linear)

  auto STAGE = [&](int buf, int kt) {
#pragma unroll
    for (int i = 0; i < 8; ++i) {
      int q = i * 512 + tid;
      int w = q >> 5, c = (q >> 3) & 3, rr = q & 7;
      async16(Pw + bbase + (long)w * 4096 + (kt * 4 + c) * 64 + rr * 8,
              (unsigned short*)(smem + buf * 65536 + q * 16));
    }
    if (tid < 256) {
      int q = tid;
      int w = q >> 5, c = (q >> 3) & 3, rr = q & 7;
      async16(Mvb + (arow0 + w * 8 + rr) * 512 + kt * 32 + c * 8,
              (unsigned short*)(smem + 131072 + buf * 4096 + q * 16));
    }
  };

  f32x4 acc[4][8];
#pragma unroll
  for (int i = 0; i < 4; ++i)
#pragma unroll
    for (int j = 0; j < 8; ++j) acc[i][j] = (f32x4){0.f, 0.f, 0.f, 0.f};

  STAGE(0, 0);
  for (int kt = 0; kt < 16; ++kt) {
    int cur = kt & 1;
    if (kt < 15) {
      STAGE(cur ^ 1, kt + 1);
      asm volatile("s_waitcnt vmcnt(8)" ::: "memory");
    } else {
      asm volatile("s_waitcnt vmcnt(0)" ::: "memory");
    }
    sbar();
    const char* cB = smem + cur * 65536;
    const char* cA = smem + 131072 + cur * 4096;
    bf16x8 a[4], b[8];
#pragma unroll
    for (int i = 0; i < 4; ++i) a[i] = ld_frag(cA, i * 16 + ri, hi);
#pragma unroll
    for (int j = 0; j < 8; ++j) b[j] = ld_frag(cB, wid * 128 + j * 16 + ri, hi);
    __builtin_amdgcn_s_setprio(1);
#pragma unroll
    for (int i = 0; i < 4; ++i)
#pragma unroll
      for (int j = 0; j < 8; ++j)
        acc[i][j] = __builtin_amdgcn_mfma_f32_16x16x32_bf16(a[i], b[j], acc[i][j], 0, 0, 0);
    __builtin_amdgcn_s_setprio(0);
    sbar();
  }

  float* rsum = (float*)(smem + 139264);
  float* rsq  = (float*)(smem + 141312);
  float* mexp = (float*)(smem + 143360);
  float* rstd = (float*)(smem + 143616);
  int hi4 = hi * 4;
#pragma unroll
  for (int i = 0; i < 4; ++i)
#pragma unroll
    for (int rr = 0; rr < 4; ++rr) {
      float s = 0.f, qv = 0.f;
#pragma unroll
      for (int j = 0; j < 8; ++j) { float v = acc[i][j][rr]; s += v; qv += v * v; }
#pragma unroll
      for (int off = 1; off < 16; off <<= 1) {
        s += __shfl_xor(s, off);
        qv += __shfl_xor(qv, off);
      }
      if (ri == 0) {
        int row = i * 16 + hi4 + rr;
        rsum[row * 8 + wid] = s;
        rsq[row * 8 + wid] = qv;
      }
    }
  __syncthreads();
  if (tid < 64) {
    float S = 0.f, Q = 0.f;
#pragma unroll
    for (int w = 0; w < 8; ++w) { S += rsum[tid * 8 + w]; Q += rsq[tid * 8 + w]; }
    float mean = S * (1.f / 1024.f);
    float var = Q * (1.f / 1024.f) - mean * mean;
    mexp[tid] = mean;
    rstd[tid] = rsqrtf(var + 1e-5f);
  }
  __syncthreads();
  long r0 = (long)offs[e] + (long)mb * 64;
  float owv[8], obv[8];
#pragma unroll
  for (int j = 0; j < 8; ++j) {
    int col = wid * 128 + j * 16 + ri;
    owv[j] = ow[col];
    obv[j] = ob[col];
  }
#pragma unroll
  for (int i = 0; i < 4; ++i)
#pragma unroll
    for (int rr = 0; rr < 4; ++rr) {
      int row = i * 16 + hi4 + rr;
      float mu = mexp[row], rs = rstd[row];
#pragma unroll
      for (int j = 0; j < 8; ++j) {
        int col = wid * 128 + j * 16 + ri;
        Out[(r0 + row) * 1024 + col] = (acc[i][j][rr] - mu) * rs * owv[j] + obv[j];
      }
    }
}

// ---------- host ----------
extern "C" void kernel_launch(void* const* d_in, const int* in_sizes, int n_in,
                              void* d_out, int out_size, void* d_ws, size_t ws_size,
                              hipStream_t stream) {
  const float* x    = (const float*)d_in[0];
  const float* pin  = (const float*)d_in[1];
  const float* pout = (const float*)d_in[2];
  const float* iw   = (const float*)d_in[3];
  const float* gg   = (const float*)d_in[4];
  const float* fg   = (const float*)d_in[5];
  const float* fu   = (const float*)d_in[6];
  const float* fd   = (const float*)d_in[7];
  const float* lnw  = (const float*)d_in[8];
  const float* lnb  = (const float*)d_in[9];
  const float* ow   = (const float*)d_in[10];
  const float* ob   = (const float*)d_in[11];
  const int* offs   = (const int*)d_in[12];

  char* ws = (char*)d_ws;
  unsigned short* mvB  = (unsigned short*)(ws + 0L);          //  33,554,432 B (linear bf16)
  unsigned short* mvb  = (unsigned short*)(ws + 33554432L);   //  33,554,432 B (linear bf16)
  unsigned short* pinT = (unsigned short*)(ws + 67108864L);   //  16,777,216 B (tiled)
  unsigned short* poutT= (unsigned short*)(ws + 83886080L);   //  16,777,216 B (tiled)
  unsigned short* wgT  = (unsigned short*)(ws + 100663296L);  //   2,097,152 B (swz-64)
  unsigned short* wuT  = (unsigned short*)(ws + 102760448L);  //   2,097,152 B (swz-64)
  unsigned short* wdT  = (unsigned short*)(ws + 104857600L);  //   2,097,152 B (plain)
  float* wcomb         = (float*)(ws + 106954752L);           //   5,120 B

  // prep (convert_k REMOVED: A-conversion fused into gemm_in_k)
  trans_big_k<<<dim3(8, 16, 16), dim3(256), 0, stream>>>(pin, pinT, 1024, 512);
  trans_big_k<<<dim3(16, 8, 16), dim3(256), 0, stream>>>(pout, poutT, 512, 1024);
  transpose_k<1><<<dim3(8, 2, 32), dim3(256), 0, stream>>>(fg, wgT, 64, 256);
  transpose_k<1><<<dim3(8, 2, 32), dim3(256), 0, stream>>>(fu, wuT, 64, 256);
  transpose_k<0><<<dim3(2, 8, 32), dim3(256), 0, stream>>>(fd, wdT, 256, 64);
  geoprep_k<<<dim3(1), dim3(64), 0, stream>>>(iw, gg, wcomb);

  // mvB = x @ Pin (A fp32->bf16 reg-staged in-kernel; B from tiled pinT)
  gemm_in_k<<<dim3(256), dim3(512), 131072, stream>>>(x, pinT, mvB, offs);

  // both rounds in ONE kernel; 4 tokens/wave, W dbuf in eighths, 48K LDS
  rounds_k<<<dim3(2048), dim3(256), 49152, stream>>>(
      mvB, wgT, wuT, wdT, wcomb, lnw, lnb, mvb);

  // out = LN(mvb @ Pout)
  gemm_out_ln_k<<<dim3(512), dim3(512), 143872, stream>>>(
      mvb, poutT, (float*)d_out, ow, ob, offs);
}

// Round 7
// 264.367 us; speedup vs baseline: 2.0228x; 1.0379x over previous
//
#include <hip/hip_runtime.h>

#define DEV __device__ __forceinline__

typedef __attribute__((ext_vector_type(4))) float f32x4;
typedef __attribute__((ext_vector_type(2))) float f32x2;
typedef __attribute__((ext_vector_type(8))) short bf16x8;

// Shapes: E=16, D=1024, ED=512, NB=8, DB=64, R=2, F=256, N=32768, C=2048

// ---------- helpers ----------
DEV unsigned short f2bf(float f) {
  union { float f; unsigned u; } v; v.f = f;
  unsigned r = v.u + 0x7fffu + ((v.u >> 16) & 1u);
  return (unsigned short)(r >> 16);
}

DEV unsigned pk2bf(float lo, float hi) {  // v_cvt_pk_bf16_f32 (RNE)
  unsigned r;
  asm("v_cvt_pk_bf16_f32 %0, %1, %2" : "=v"(r) : "v"(lo), "v"(hi));
  return r;
}
DEV unsigned short f2bf1(float v) { return (unsigned short)pk2bf(v, v); }

DEV float bf2f(unsigned short b) {
  union { unsigned u; float f; } v; v.u = ((unsigned)b) << 16; return v.f;
}

DEV float frcp(float x) { return __builtin_amdgcn_rcpf(x); }

// raw barrier: NO implicit vmcnt drain. "memory" clobber = compiler fence.
DEV void sbar() { asm volatile("s_barrier" ::: "memory"); }
DEV void wait_lgkm0() { asm volatile("s_waitcnt lgkmcnt(0)" ::: "memory"); }
DEV void wait_vm0() { asm volatile("s_waitcnt vmcnt(0)" ::: "memory"); }

DEV void async16(const unsigned short* g, unsigned short* l) {
  __builtin_amdgcn_global_load_lds(
      (__attribute__((address_space(1))) const unsigned int*)g,
      (__attribute__((address_space(3))) unsigned int*)l, 16, 0, 0);
}

// Tiled global layout for GEMM operands: element (n,k) of an [N][K] panel at
//   (n>>3)*8K + (k>>3)*64 + (n&7)*8 + (k&7)
DEV long tiled_off(long n, int k, int K) {
  return (n >> 3) * (8L * K) + (long)(((k >> 3) * 64) + ((int)(n & 7)) * 8 + (k & 7));
}

// frag read from a tiled 32-k LDS subtile (bf16)
DEV bf16x8 ld_frag(const char* s, int row, int hi) {
  return *(const bf16x8*)(s + ((row >> 3) * 512 + hi * 128 + (row & 7) * 16));
}

// ---------- Cayley table at compile time ----------
__host__ __device__ constexpr int km_(int i) { return i==0?0:i==1?1:i==2?2:i==3?4:i==4?3:i==5?5:i==6?6:7; }
__host__ __device__ constexpr int pc_(int x) { int c = 0; while (x) { c += x & 1; x >>= 1; } return c; }
__host__ __device__ constexpr int KIDX(int i, int j) { return km_(km_(i) ^ km_(j)); }
__host__ __device__ constexpr int CSGN(int i, int j) {
  int a = km_(i), b = km_(j), aa = a >> 1, s = 0;
  while (aa) { s += pc_(aa & b); aa >>= 1; }
  return (s & 1) ? -1 : 1;
}
__host__ __device__ constexpr int PIDX(int i, int j) {  // i<=j
  return 8 * i - (i * (i - 1)) / 2 + (j - i);
}

// ---------- small kernels ----------
__global__ __launch_bounds__(64) void geoprep_k(const float* __restrict__ iw,
                                                const float* __restrict__ gg,
                                                float* __restrict__ wcomb) {
  int er = threadIdx.x;
  if (er >= 32) return;
  const float* w = iw + er * 64;
  float gate = frcp(1.f + __expf(-gg[er]));
  float* c = wcomb + er * 40;
  int p = 0;
  for (int i = 0; i < 8; ++i)
    for (int j = i; j < 8; ++j) {
      float v = (float)CSGN(i, j) * frcp(1.f + __expf(-w[i * 8 + j]));
      if (j > i) v += (float)CSGN(j, i) * frcp(1.f + __expf(-w[j * 8 + i]));
      c[p++] = gate * v;
    }
  c[36] = 1.f - gate;
}

// small transposes (wg/wu/wd): in (Rr,Cc) fp32 (batch z) -> (Cc,Rr) bf16.
// TI=0 linear; TI=1: k ^= (row&7)<<3 (needs Rr==64).
template<int TI>
__global__ __launch_bounds__(256) void transpose_k(const float* __restrict__ in,
                                                   unsigned short* __restrict__ out,
                                                   int Rr, int Cc) {
  __shared__ unsigned short tile[32][33];
  const float* ib = in + (long)blockIdx.z * Rr * Cc;
  unsigned short* ob = out + (long)blockIdx.z * Rr * Cc;
  int r0 = blockIdx.y * 32, c0 = blockIdx.x * 32;
  int tr = threadIdx.x >> 5, tc = threadIdx.x & 31;
#pragma unroll
  for (int i = 0; i < 4; ++i) {
    int r = tr + i * 8;
    tile[r][tc] = f2bf(ib[(long)(r0 + r) * Cc + c0 + tc]);
  }
  __syncthreads();
#pragma unroll
  for (int i = 0; i < 4; ++i) {
    int c = tr + i * 8;
    int row = c0 + c;
    int k = r0 + tc;
    if (TI == 0) ob[(long)row * Rr + k] = tile[tc][c];
    else ob[(long)row * Rr + (k ^ ((row & 7) << 3))] = tile[tc][c];
  }
}

// big convert+transpose for pin/pout: in [Rr k][Cc n] fp32 -> out tiled bf16 [n][k].
__global__ __launch_bounds__(256) void trans_big_k(const float* __restrict__ in,
                                                   unsigned short* __restrict__ out,
                                                   int Rr, int Cc) {
  __shared__ float t[64][64];
  const float* ib = in + (long)blockIdx.z * Rr * Cc;
  unsigned short* ob = out + (long)blockIdx.z * (long)Rr * Cc;
  int k0 = blockIdx.y * 64, n0 = blockIdx.x * 64;
  int tid = threadIdx.x;
#pragma unroll
  for (int p = 0; p < 4; ++p) {
    int idx = p * 256 + tid;
    int kr = idx >> 4, nc = (idx & 15) * 4;
    *(float4*)&t[kr][nc] = *(const float4*)(ib + (long)(k0 + kr) * Cc + n0 + nc);
  }
  __syncthreads();
#pragma unroll
  for (int p = 0; p < 2; ++p) {
    int idx = p * 256 + tid;
    int n = idx & 63, kc = idx >> 6;       // kc 0..7
    float v[8];
#pragma unroll
    for (int u = 0; u < 8; ++u) v[u] = t[kc * 8 + u][n];
    uint4 o;
    o.x = pk2bf(v[0], v[1]); o.y = pk2bf(v[2], v[3]);
    o.z = pk2bf(v[4], v[5]); o.w = pk2bf(v[6], v[7]);
    *(uint4*)(ob + tiled_off(n0 + n, k0 + kc * 8, Rr)) = o;
  }
}

// GEMM1 (convert FUSED): mvB(bf16, linear [token][512]) = x @ Pin^T per expert.
// 256x256 tile, BK=64 in two 32-sub-phases. B staged via async16 from tiled
// pinT; A staged from x fp32 directly (reg-load -> cvt -> ds_write, T14 split).
__global__ __launch_bounds__(512, 1) void gemm_in_k(const float* __restrict__ X,
                                                    const unsigned short* __restrict__ Bw,
                                                    unsigned short* __restrict__ MvB,
                                                    const int* __restrict__ offs) {
  extern __shared__ char smem[];    // [2 buf][ A 32K | B 32K ], each op as 2 x 16K ksub
  int bid = blockIdx.x;             // 256 blocks
  int wg = (bid & 7) * 32 + (bid >> 3);      // XCD swizzle (256 % 8 == 0)
  int e = wg >> 4, rem = wg & 15, bm = rem >> 1, bn = rem & 1;
  int tid = threadIdx.x, wid = tid >> 6, lane = tid & 63;
  int wm = (wid >> 2) * 128, wn = (wid & 3) * 64;
  int ri = lane & 15, hi = lane >> 4;
  long rowbase = (long)offs[e] + bm * 256;   // A row base (x fp32 linear)
  long bw = (long)e * 64 + bn * 32;          // B window base (pinT tiled, K=1024)

  // phase p = t*2+s (t=K-tile 0..15, s=32-k sub 0..1)
  auto STGB = [&](int p) {
    int t = p >> 1, s = p & 1, b = t & 1;
    char* dst = smem + b * 65536 + 32768 + s * 16384;
#pragma unroll
    for (int i = 0; i < 2; ++i) {
      int d = i * 512 + tid;
      async16(Bw + (bw + (d >> 5)) * 8192 +
                  (long)((t * 8 + s * 4 + ((d >> 3) & 3)) * 64 + (d & 7) * 8),
              (unsigned short*)(dst + d * 16));
    }
  };
  auto A_LOAD = [&](int p, float4 ar[2][2]) {
    int t = p >> 1, s = p & 1;
#pragma unroll
    for (int i = 0; i < 2; ++i) {
      int d = i * 512 + tid;
      const float* src = X + (rowbase + ((d >> 5) * 8 + (d & 7))) * 1024 +
                         t * 64 + s * 32 + ((d >> 3) & 3) * 8;
      ar[i][0] = *(const float4*)src;
      ar[i][1] = *(const float4*)(src + 4);
    }
  };
  auto A_WRITE = [&](int p, float4 ar[2][2]) {
    int t = p >> 1, s = p & 1, b = t & 1;
    char* dst = smem + b * 65536 + s * 16384;
#pragma unroll
    for (int i = 0; i < 2; ++i) {
      int d = i * 512 + tid;
      uint4 o;
      o.x = pk2bf(ar[i][0].x, ar[i][0].y);
      o.y = pk2bf(ar[i][0].z, ar[i][0].w);
      o.z = pk2bf(ar[i][1].x, ar[i][1].y);
      o.w = pk2bf(ar[i][1].z, ar[i][1].w);
      *(uint4*)(dst + d * 16) = o;
    }
  };

  f32x4 acc[8][4];
#pragma unroll
  for (int i = 0; i < 8; ++i)
#pragma unroll
    for (int j = 0; j < 4; ++j) acc[i][j] = (f32x4){0.f, 0.f, 0.f, 0.f};

  // prologue: phases 0 and 1 staged (A via regs, B via async16)
  float4 ar[2][2];
  A_LOAD(0, ar); STGB(0); STGB(1);
  A_WRITE(0, ar);                 // compiler auto-waits the A regs
  A_LOAD(1, ar);
  A_WRITE(1, ar);
  wait_lgkm0();

#pragma unroll 2
  for (int p = 0; p < 32; ++p) {
    int t = p >> 1, s = p & 1, c = t & 1;
    if (p < 30) { A_LOAD(p + 2, ar); STGB(p + 2); }
    if (p < 30) asm volatile("s_waitcnt vmcnt(8)" ::: "memory");
    else if (p == 30) asm volatile("s_waitcnt vmcnt(2)" ::: "memory");
    else asm volatile("s_waitcnt vmcnt(0)" ::: "memory");
    sbar();
    const char* cA = smem + c * 65536 + s * 16384;
    const char* cB = smem + c * 65536 + 32768 + s * 16384;
    bf16x8 a[8], b[4];
#pragma unroll
    for (int i = 0; i < 8; ++i) a[i] = ld_frag(cA, wm + i * 16 + ri, hi);
#pragma unroll
    for (int j = 0; j < 4; ++j) b[j] = ld_frag(cB, wn + j * 16 + ri, hi);
    __builtin_amdgcn_s_setprio(1);
#pragma unroll
    for (int i = 0; i < 8; ++i)
#pragma unroll
      for (int j = 0; j < 4; ++j)
        acc[i][j] = __builtin_amdgcn_mfma_f32_16x16x32_bf16(a[i], b[j], acc[i][j], 0, 0, 0);
    __builtin_amdgcn_s_setprio(0);
    if (p < 30) A_WRITE(p + 2, ar);
    wait_lgkm0();
  }

  unsigned short* Cb = MvB + ((long)e * 2048 + (long)bm * 256) * 512 + bn * 256;
#pragma unroll
  for (int i = 0; i < 8; ++i)
#pragma unroll
    for (int j = 0; j < 4; ++j)
#pragma unroll
      for (int rr = 0; rr < 4; ++rr)
        Cb[(long)(wm + i * 16 + hi * 4 + rr) * 512 + wn + j * 16 + ri] =
            f2bf1(acc[i][j][rr]);
}

// ---------- merged 2-round fused kernel: 8 TOKENS PER WAVE ----------
// 32 tokens/block, 256 threads = 4 waves; each wave owns 8 tokens (64 trows,
// 4 trow-tiles) END-TO-END. Per F-eighth a wave runs 48 MFMAs (32 gate/up +
// 16 down) against the SAME per-phase fixed costs as 4-tok (8 W ds_reads,
// 4 Wd loads, stage, barrier) -> fixed-cost share halves again.
// Calibrated model (r3/r5 data): t = w + f/tok, w~46us f~300us -> 8tok ~84us.
// sFlat/sH/sMvh WAVE-PRIVATE (no barriers). W staging dbuf in eighths, one
// barrier per phase, full-phase prefetch distance (r4 structure).
// LDS 80K -> 2 blocks/CU (160K exact) at __launch_bounds__(256,2): VGPR cap
// 256 (~175 peak demand, no spill; r1/r2 lesson: starved caps -> scratch).
//   sFH  @0     32K: 4 waves x 8K  [64 trow][128B] xor (ri&7)<<4 (flat, then h)
//   sMv  @32K   32K: 4 waves x 8K  [8 tok][8 blade][128B] xor (blade)<<4
//   sW   @64K   16K: dbuf x (Wg 4K | Wu 4K) eighth (swizzle baked in global)
__global__ __launch_bounds__(256, 2) void rounds_k(
    const unsigned short* __restrict__ MvB, const unsigned short* __restrict__ WgT,
    const unsigned short* __restrict__ WuT, const unsigned short* __restrict__ WdT,
    const float* __restrict__ wcomb, const float* __restrict__ lnw,
    const float* __restrict__ lnb, unsigned short* __restrict__ Mvb) {
  extern __shared__ char smem[];
  int tid = threadIdx.x, wid = tid >> 6, lane = tid & 63;
  char* sFH = smem + wid * 8192;            // wave-private [64 trow][128B]
  char* sMv = smem + 32768 + wid * 8192;    // wave-private [8 tok][1K]
  char* sW  = smem + 65536;                 // dbuf 2 x 8K (Wg 4K | Wu 4K)

  int bid = blockIdx.x;
  int wg = (bid & 7) * 128 + (bid >> 3);    // XCD swizzle (1024 % 8 == 0)
  int e = wg >> 6, bx = wg & 63;

  int t8 = lane >> 3, q = lane & 7;         // P1 coords: token-in-wave, d-octet
  int ri = lane & 15, hi = lane >> 4;       // frag coords
  int sw = (ri & 7) << 4;

  // stage global eighth i8 (0..15; round = i8>>3, slice = i8&7)
  auto STAGE = [&](int i8) {
    long base = (long)(e * 2 + (i8 >> 3)) * 16384 + (i8 & 7) * 2048;
    char* dst = sW + (i8 & 1) * 8192;
    async16(WgT + base + tid * 8, (unsigned short*)(dst + tid * 16));
    async16(WuT + base + tid * 8, (unsigned short*)(dst + 4096 + tid * 16));
  };
  STAGE(0);   // prologue: lands under P1 of round 0

#pragma unroll 1
  for (int r = 0; r < 2; ++r) {
    int er = e * 2 + r;
    const unsigned short* wd = WdT + (long)er * 16384;  // [64 dout][256 F]

    // ---- P1a: mv (global bf16 on r0 -> stash to sMvh; sMvh on r1) ----
    // Each lane: token t8, d = 8q..8q+7 (two f32x4 halves).
    f32x4 mv[2][8];
    if (r == 0) {
      long base = ((long)e * 2048 + bx * 32 + wid * 8 + t8) * 512 + 8 * q;
      uint4 uv[8];
#pragma unroll
      for (int i = 0; i < 8; ++i)
        uv[i] = *(const uint4*)(MvB + base + i * 64);
#pragma unroll
      for (int i = 0; i < 8; ++i) {
        *(uint4*)(sMv + t8 * 1024 + i * 128 + ((16 * q) ^ (i << 4))) = uv[i];
        mv[0][i] = (f32x4){bf2f((unsigned short)(uv[i].x & 0xffff)),
                           bf2f((unsigned short)(uv[i].x >> 16)),
                           bf2f((unsigned short)(uv[i].y & 0xffff)),
                           bf2f((unsigned short)(uv[i].y >> 16))};
        mv[1][i] = (f32x4){bf2f((unsigned short)(uv[i].z & 0xffff)),
                           bf2f((unsigned short)(uv[i].z >> 16)),
                           bf2f((unsigned short)(uv[i].w & 0xffff)),
                           bf2f((unsigned short)(uv[i].w >> 16))};
      }
    } else {
#pragma unroll
      for (int i = 0; i < 8; ++i) {
        uint4 uv = *(const uint4*)(sMv + t8 * 1024 + i * 128 + ((16 * q) ^ (i << 4)));
        mv[0][i] = (f32x4){bf2f((unsigned short)(uv.x & 0xffff)),
                           bf2f((unsigned short)(uv.x >> 16)),
                           bf2f((unsigned short)(uv.y & 0xffff)),
                           bf2f((unsigned short)(uv.y >> 16))};
        mv[1][i] = (f32x4){bf2f((unsigned short)(uv.z & 0xffff)),
                           bf2f((unsigned short)(uv.z >> 16)),
                           bf2f((unsigned short)(uv.w & 0xffff)),
                           bf2f((unsigned short)(uv.w >> 16))};
      }
    }

    // ---- P1b: geo + mix + LN(64) -> sFH (packed math; wave-private) ----
    {
      const float* C = wcomb + er * 40;
      f32x4 g[2][8];
#pragma unroll
      for (int hf = 0; hf < 2; ++hf)
#pragma unroll
        for (int k = 0; k < 8; ++k) g[hf][k] = (f32x4){0.f, 0.f, 0.f, 0.f};
#pragma unroll
      for (int i = 0; i < 8; ++i)
#pragma unroll
        for (int j = i; j < 8; ++j) {
          float cc = C[PIDX(i, j)];
          const int k = KIDX(i, j);
          g[0][k] += cc * (mv[0][i] * mv[0][j]);
          g[1][k] += cc * (mv[1][i] * mv[1][j]);
        }
      float omg = C[36];
#pragma unroll
      for (int hf = 0; hf < 2; ++hf)
#pragma unroll
        for (int k = 0; k < 8; ++k) g[hf][k] = omg * mv[hf][k] + g[hf][k];
      float4 lwa = *(const float4*)(lnw + (long)er * 64 + 8 * q);
      float4 lwb = *(const float4*)(lnw + (long)er * 64 + 8 * q + 4);
      float4 lba = *(const float4*)(lnb + (long)er * 64 + 8 * q);
      float4 lbb = *(const float4*)(lnb + (long)er * 64 + 8 * q + 4);
      f32x4 lwvA = (f32x4){lwa.x, lwa.y, lwa.z, lwa.w};
      f32x4 lwvB = (f32x4){lwb.x, lwb.y, lwb.z, lwb.w};
      f32x4 lbvA = (f32x4){lba.x, lba.y, lba.z, lba.w};
      f32x4 lbvB = (f32x4){lbb.x, lbb.y, lbb.z, lbb.w};
#pragma unroll
      for (int bh = 0; bh < 2; ++bh) {
        f32x2 red[4];
#pragma unroll
        for (int k = 0; k < 4; ++k) {
          f32x4 a = g[0][bh * 4 + k], b = g[1][bh * 4 + k];
          red[k].x = ((a.x + a.y) + (a.z + a.w)) + ((b.x + b.y) + (b.z + b.w));
          red[k].y = (fmaf(a.x, a.x, a.y * a.y) + fmaf(a.z, a.z, a.w * a.w)) +
                     (fmaf(b.x, b.x, b.y * b.y) + fmaf(b.z, b.z, b.w * b.w));
        }
#pragma unroll
        for (int off = 4; off >= 1; off >>= 1)
#pragma unroll
          for (int t = 0; t < 4; ++t) {
            f32x2 o;
            o.x = __shfl_xor(red[t].x, off);
            o.y = __shfl_xor(red[t].y, off);
            red[t] += o;
          }
#pragma unroll
        for (int k = 0; k < 4; ++k) {
          int kk = bh * 4 + k;
          float mean = red[k].x * (1.f / 64.f);
          float var = red[k].y * (1.f / 64.f) - mean * mean;
          float rs = rsqrtf(var + 1e-5f);
          f32x4 ovA = ((g[0][kk] - mean) * rs) * lwvA + lbvA;
          f32x4 ovB = ((g[1][kk] - mean) * rs) * lwvB + lbvB;
          uint4 pv;
          pv.x = pk2bf(ovA.x, ovA.y);
          pv.y = pk2bf(ovA.z, ovA.w);
          pv.z = pk2bf(ovB.x, ovB.y);
          pv.w = pk2bf(ovB.z, ovB.w);
          int row = t8 * 8 + kk;                    // row&7 == kk
          *(uint4*)(sFH + row * 128 + ((16 * q) ^ (kk << 4))) = pv;
        }
      }
    }
    wait_lgkm0();   // own-wave flat writes done (cross-LANE reads next)

    // ---- hoist flat B-frags to regs (sFH gets reused for h afterwards) ----
    bf16x8 bfr[4][2];   // [trow-tile][k-half]
#pragma unroll
    for (int tt = 0; tt < 4; ++tt)
#pragma unroll
      for (int kt = 0; kt < 2; ++kt)
        bfr[tt][kt] = *(const bf16x8*)(sFH + (tt * 16 + ri) * 128 + ((kt * 64 + hi * 16) ^ sw));

    f32x4 acc2[4][4];   // [dout-tile][trow-tile]
#pragma unroll
    for (int j = 0; j < 4; ++j)
#pragma unroll
      for (int tt = 0; tt < 4; ++tt) acc2[j][tt] = (f32x4){0.f, 0.f, 0.f, 0.f};

#pragma unroll 1
    for (int q8 = 0; q8 < 8; ++q8) {
      int i8 = r * 8 + q8;
      wait_vm0();   // stage(i8) landed (issued a full eighth ago)
      sbar();       // all waves: stage(i8) in LDS; eighth i8-1 reads done
      if (i8 < 15) STAGE(i8 + 1);   // -> buf((i8+1)&1): free per the barrier

      // ---- Wd frags at PHASE TOP (global; full-phase latency cover) ----
      bf16x8 wdf[4];
#pragma unroll
      for (int j = 0; j < 4; ++j)
        wdf[j] = *(const bf16x8*)(wd + (j * 16 + ri) * 256 + q8 * 32 + hi * 8);

      const char* bufW = sW + (i8 & 1) * 8192;

      // ---- P2: 2 F-tiles x 4 trow-tiles; silu -> h ----
#pragma unroll
      for (int ftl = 0; ftl < 2; ++ftl) {
        const char* bg = bufW + (ftl * 16 + ri) * 128;
        const char* bu = bg + 4096;
        bf16x8 wg0 = *(const bf16x8*)(bg + ((hi * 16) ^ sw));
        bf16x8 wg1 = *(const bf16x8*)(bg + ((64 + hi * 16) ^ sw));
        bf16x8 wu0 = *(const bf16x8*)(bu + ((hi * 16) ^ sw));
        bf16x8 wu1 = *(const bf16x8*)(bu + ((64 + hi * 16) ^ sw));
        f32x4 ag[4], au[4];
#pragma unroll
        for (int tt = 0; tt < 4; ++tt) {
          ag[tt] = (f32x4){0.f, 0.f, 0.f, 0.f};
          au[tt] = (f32x4){0.f, 0.f, 0.f, 0.f};
        }
        __builtin_amdgcn_s_setprio(1);
#pragma unroll
        for (int tt = 0; tt < 4; ++tt) {
          ag[tt] = __builtin_amdgcn_mfma_f32_16x16x32_bf16(wg0, bfr[tt][0], ag[tt], 0, 0, 0);
          au[tt] = __builtin_amdgcn_mfma_f32_16x16x32_bf16(wu0, bfr[tt][0], au[tt], 0, 0, 0);
          ag[tt] = __builtin_amdgcn_mfma_f32_16x16x32_bf16(wg1, bfr[tt][1], ag[tt], 0, 0, 0);
          au[tt] = __builtin_amdgcn_mfma_f32_16x16x32_bf16(wu1, bfr[tt][1], au[tt], 0, 0, 0);
        }
        __builtin_amdgcn_s_setprio(0);
#pragma unroll
        for (int tt = 0; tt < 4; ++tt) {
          float hh[4];
#pragma unroll
          for (int rr = 0; rr < 4; ++rr) {
            float gv = ag[tt][rr], uu = au[tt][rr];
            hh[rr] = gv * uu * frcp(1.f + __expf(-gv));
          }
          uint2 hwv;
          hwv.x = pk2bf(hh[0], hh[1]);
          hwv.y = pk2bf(hh[2], hh[3]);
          // h (F_loc = ftl*16+hi*4+rr, trow = tt*16+ri) -> swizzled
          *(uint2*)(sFH + (tt * 16 + ri) * 128 + ((ftl * 32 + hi * 8) ^ sw)) = hwv;
        }
      }
      wait_lgkm0();  // own h writes complete before hk reads

      // ---- P4: acc2[dout][trow-tile] += Wd x h (one 32-k chunk) ----
      bf16x8 hk[4];
#pragma unroll
      for (int tt = 0; tt < 4; ++tt)
        hk[tt] = *(const bf16x8*)(sFH + (tt * 16 + ri) * 128 + ((hi * 16) ^ sw));
      __builtin_amdgcn_s_setprio(1);
#pragma unroll
      for (int j = 0; j < 4; ++j)
#pragma unroll
        for (int tt = 0; tt < 4; ++tt)
          acc2[j][tt] = __builtin_amdgcn_mfma_f32_16x16x32_bf16(wdf[j], hk[tt], acc2[j][tt], 0, 0, 0);
      __builtin_amdgcn_s_setprio(0);
    }

    // ---- P5: residual vs sMvh (wave-private, in place both rounds) ----
    {
#pragma unroll
      for (int tt = 0; tt < 4; ++tt) {
        int tl = tt * 2 + (ri >> 3);
        int kb = ri & 7;
#pragma unroll
        for (int j = 0; j < 4; ++j)
#pragma unroll
          for (int u = 0; u < 2; ++u) {
            int off = (j * 32 + hi * 8 + 4 * u) ^ sw;
            unsigned* p = (unsigned*)(sMv + tl * 1024 + kb * 128 + off);
            unsigned old = *p;
            float v0 = bf2f((unsigned short)(old & 0xffff)) + acc2[j][tt][2 * u];
            float v1 = bf2f((unsigned short)(old >> 16)) + acc2[j][tt][2 * u + 1];
            *p = pk2bf(v0, v1);
          }
      }
    }
    wait_lgkm0();   // sMvh updates done (next round's P1a / epilogue reads)

    // ---- r1: coalesced uint4 dump sMvh -> Mvb (8 rows = 8KB contiguous) ----
    if (r == 1) {
      int bl = lane >> 3, qq = lane & 7;
      long sbase = ((long)e * 2048 + bx * 32 + wid * 8) * 512;
#pragma unroll
      for (int h = 0; h < 8; ++h) {
        uint4 v = *(const uint4*)(sMv + h * 1024 + bl * 128 + ((16 * qq) ^ (bl << 4)));
        *(uint4*)(Mvb + sbase + h * 512 + lane * 8) = v;
      }
    }
  }
}

// ---------- fused out-projection + LayerNorm(D=1024), 512 threads/block ----------
// A (mvb) is LINEAR [token][512] bf16; tiled LDS layout derived via per-lane source addr.
__global__ __launch_bounds__(512, 2) void gemm_out_ln_k(
    const unsigned short* __restrict__ Mvb, const unsigned short* __restrict__ Pw,
    float* __restrict__ Out, const float* __restrict__ ow, const float* __restrict__ ob,
    const int* __restrict__ offs) {
  extern __shared__ char smem[];
  int bid = blockIdx.x;
  int wg = (bid & 7) * 64 + (bid >> 3);
  int e = wg >> 5, mb = wg & 31;
  int tid = threadIdx.x, wid = tid >> 6, lane = tid & 63;
  int ri = lane & 15, hi = lane >> 4;
  long bbase = (long)e * 524288;                 // poutT expert base (tiled)
  long arow0 = (long)e * 2048 + (long)mb * 64;   // mvb expert row base (linear)

  auto STAGE = [&](int buf, int kt) {
#pragma unroll
    for (int i = 0; i < 8; ++i) {
      int q = i * 512 + tid;
      int w = q >> 5, c = (q >> 3) & 3, rr = q & 7;
      async16(Pw + bbase + (long)w * 4096 + (kt * 4 + c) * 64 + rr * 8,
              (unsigned short*)(smem + buf * 65536 + q * 16));
    }
    if (tid < 256) {
      int q = tid;
      int w = q >> 5, c = (q >> 3) & 3, rr = q & 7;
      async16(Mvb + (arow0 + w * 8 + rr) * 512 + kt * 32 + c * 8,
              (unsigned short*)(smem + 131072 + buf * 4096 + q * 16));
    }
  };

  f32x4 acc[4][8];
#pragma unroll
  for (int i = 0; i < 4; ++i)
#pragma unroll
    for (int j = 0; j < 8; ++j) acc[i][j] = (f32x4){0.f, 0.f, 0.f, 0.f};

  STAGE(0, 0);
  for (int kt = 0; kt < 16; ++kt) {
    int cur = kt & 1;
    if (kt < 15) {
      STAGE(cur ^ 1, kt + 1);
      asm volatile("s_waitcnt vmcnt(8)" ::: "memory");
    } else {
      asm volatile("s_waitcnt vmcnt(0)" ::: "memory");
    }
    sbar();
    const char* cB = smem + cur * 65536;
    const char* cA = smem + 131072 + cur * 4096;
    bf16x8 a[4], b[8];
#pragma unroll
    for (int i = 0; i < 4; ++i) a[i] = ld_frag(cA, i * 16 + ri, hi);
#pragma unroll
    for (int j = 0; j < 8; ++j) b[j] = ld_frag(cB, wid * 128 + j * 16 + ri, hi);
    __builtin_amdgcn_s_setprio(1);
#pragma unroll
    for (int i = 0; i < 4; ++i)
#pragma unroll
      for (int j = 0; j < 8; ++j)
        acc[i][j] = __builtin_amdgcn_mfma_f32_16x16x32_bf16(a[i], b[j], acc[i][j], 0, 0, 0);
    __builtin_amdgcn_s_setprio(0);
    sbar();
  }

  float* rsum = (float*)(smem + 139264);
  float* rsq  = (float*)(smem + 141312);
  float* mexp = (float*)(smem + 143360);
  float* rstd = (float*)(smem + 143616);
  int hi4 = hi * 4;
#pragma unroll
  for (int i = 0; i < 4; ++i)
#pragma unroll
    for (int rr = 0; rr < 4; ++rr) {
      float s = 0.f, qv = 0.f;
#pragma unroll
      for (int j = 0; j < 8; ++j) { float v = acc[i][j][rr]; s += v; qv += v * v; }
#pragma unroll
      for (int off = 1; off < 16; off <<= 1) {
        s += __shfl_xor(s, off);
        qv += __shfl_xor(qv, off);
      }
      if (ri == 0) {
        int row = i * 16 + hi4 + rr;
        rsum[row * 8 + wid] = s;
        rsq[row * 8 + wid] = qv;
      }
    }
  __syncthreads();
  if (tid < 64) {
    float S = 0.f, Q = 0.f;
#pragma unroll
    for (int w = 0; w < 8; ++w) { S += rsum[tid * 8 + w]; Q += rsq[tid * 8 + w]; }
    float mean = S * (1.f / 1024.f);
    float var = Q * (1.f / 1024.f) - mean * mean;
    mexp[tid] = mean;
    rstd[tid] = rsqrtf(var + 1e-5f);
  }
  __syncthreads();
  long r0 = (long)offs[e] + (long)mb * 64;
  float owv[8], obv[8];
#pragma unroll
  for (int j = 0; j < 8; ++j) {
    int col = wid * 128 + j * 16 + ri;
    owv[j] = ow[col];
    obv[j] = ob[col];
  }
#pragma unroll
  for (int i = 0; i < 4; ++i)
#pragma unroll
    for (int rr = 0; rr < 4; ++rr) {
      int row = i * 16 + hi4 + rr;
      float mu = mexp[row], rs = rstd[row];
#pragma unroll
      for (int j = 0; j < 8; ++j) {
        int col = wid * 128 + j * 16 + ri;
        Out[(r0 + row) * 1024 + col] = (acc[i][j][rr] - mu) * rs * owv[j] + obv[j];
      }
    }
}

// ---------- host ----------
extern "C" void kernel_launch(void* const* d_in, const int* in_sizes, int n_in,
                              void* d_out, int out_size, void* d_ws, size_t ws_size,
                              hipStream_t stream) {
  const float* x    = (const float*)d_in[0];
  const float* pin  = (const float*)d_in[1];
  const float* pout = (const float*)d_in[2];
  const float* iw   = (const float*)d_in[3];
  const float* gg   = (const float*)d_in[4];
  const float* fg   = (const float*)d_in[5];
  const float* fu   = (const float*)d_in[6];
  const float* fd   = (const float*)d_in[7];
  const float* lnw  = (const float*)d_in[8];
  const float* lnb  = (const float*)d_in[9];
  const float* ow   = (const float*)d_in[10];
  const float* ob   = (const float*)d_in[11];
  const int* offs   = (const int*)d_in[12];

  char* ws = (char*)d_ws;
  unsigned short* mvB  = (unsigned short*)(ws + 0L);          //  33,554,432 B (linear bf16)
  unsigned short* mvb  = (unsigned short*)(ws + 33554432L);   //  33,554,432 B (linear bf16)
  unsigned short* pinT = (unsigned short*)(ws + 67108864L);   //  16,777,216 B (tiled)
  unsigned short* poutT= (unsigned short*)(ws + 83886080L);   //  16,777,216 B (tiled)
  unsigned short* wgT  = (unsigned short*)(ws + 100663296L);  //   2,097,152 B (swz-64)
  unsigned short* wuT  = (unsigned short*)(ws + 102760448L);  //   2,097,152 B (swz-64)
  unsigned short* wdT  = (unsigned short*)(ws + 104857600L);  //   2,097,152 B (plain)
  float* wcomb         = (float*)(ws + 106954752L);           //   5,120 B

  // prep (convert_k removed: A-conversion fused into gemm_in_k)
  trans_big_k<<<dim3(8, 16, 16), dim3(256), 0, stream>>>(pin, pinT, 1024, 512);
  trans_big_k<<<dim3(16, 8, 16), dim3(256), 0, stream>>>(pout, poutT, 512, 1024);
  transpose_k<1><<<dim3(8, 2, 32), dim3(256), 0, stream>>>(fg, wgT, 64, 256);
  transpose_k<1><<<dim3(8, 2, 32), dim3(256), 0, stream>>>(fu, wuT, 64, 256);
  transpose_k<0><<<dim3(2, 8, 32), dim3(256), 0, stream>>>(fd, wdT, 256, 64);
  geoprep_k<<<dim3(1), dim3(64), 0, stream>>>(iw, gg, wcomb);

  // mvB = x @ Pin (A fp32->bf16 reg-staged in-kernel; B from tiled pinT)
  gemm_in_k<<<dim3(256), dim3(512), 131072, stream>>>(x, pinT, mvB, offs);

  // both rounds in ONE kernel; 8 tokens/wave, W dbuf in eighths, 80K LDS
  rounds_k<<<dim3(1024), dim3(256), 81920, stream>>>(
      mvB, wgT, wuT, wdT, wcomb, lnw, lnb, mvb);

  // out = LN(mvb @ Pout)
  gemm_out_ln_k<<<dim3(512), dim3(512), 143872, stream>>>(
      mvb, poutT, (float*)d_out, ow, ob, offs);
}

// Round 8
// 253.069 us; speedup vs baseline: 2.1131x; 1.0446x over previous
//
#include <hip/hip_runtime.h>

#define DEV __device__ __forceinline__

typedef __attribute__((ext_vector_type(4))) float f32x4;
typedef __attribute__((ext_vector_type(2))) float f32x2;
typedef __attribute__((ext_vector_type(8))) short bf16x8;

// Shapes: E=16, D=1024, ED=512, NB=8, DB=64, R=2, F=256, N=32768, C=2048

// ---------- helpers ----------
DEV unsigned short f2bf(float f) {
  union { float f; unsigned u; } v; v.f = f;
  unsigned r = v.u + 0x7fffu + ((v.u >> 16) & 1u);
  return (unsigned short)(r >> 16);
}

DEV unsigned pk2bf(float lo, float hi) {  // v_cvt_pk_bf16_f32 (RNE)
  unsigned r;
  asm("v_cvt_pk_bf16_f32 %0, %1, %2" : "=v"(r) : "v"(lo), "v"(hi));
  return r;
}
DEV unsigned short f2bf1(float v) { return (unsigned short)pk2bf(v, v); }

DEV float bf2f(unsigned short b) {
  union { unsigned u; float f; } v; v.u = ((unsigned)b) << 16; return v.f;
}

DEV float frcp(float x) { return __builtin_amdgcn_rcpf(x); }

// raw barrier: NO implicit vmcnt drain. "memory" clobber = compiler fence.
DEV void sbar() { asm volatile("s_barrier" ::: "memory"); }
DEV void wait_lgkm0() { asm volatile("s_waitcnt lgkmcnt(0)" ::: "memory"); }
DEV void wait_vm0() { asm volatile("s_waitcnt vmcnt(0)" ::: "memory"); }

DEV void async16(const unsigned short* g, unsigned short* l) {
  __builtin_amdgcn_global_load_lds(
      (__attribute__((address_space(1))) const unsigned int*)g,
      (__attribute__((address_space(3))) unsigned int*)l, 16, 0, 0);
}

// Tiled global layout for GEMM operands: element (n,k) of an [N][K] panel at
//   (n>>3)*8K + (k>>3)*64 + (n&7)*8 + (k&7)
DEV long tiled_off(long n, int k, int K) {
  return (n >> 3) * (8L * K) + (long)(((k >> 3) * 64) + ((int)(n & 7)) * 8 + (k & 7));
}

// frag read from a tiled 32-k LDS subtile (bf16)
DEV bf16x8 ld_frag(const char* s, int row, int hi) {
  return *(const bf16x8*)(s + ((row >> 3) * 512 + hi * 128 + (row & 7) * 16));
}

// ---------- Cayley table at compile time ----------
__host__ __device__ constexpr int km_(int i) { return i==0?0:i==1?1:i==2?2:i==3?4:i==4?3:i==5?5:i==6?6:7; }
__host__ __device__ constexpr int pc_(int x) { int c = 0; while (x) { c += x & 1; x >>= 1; } return c; }
__host__ __device__ constexpr int KIDX(int i, int j) { return km_(km_(i) ^ km_(j)); }
__host__ __device__ constexpr int CSGN(int i, int j) {
  int a = km_(i), b = km_(j), aa = a >> 1, s = 0;
  while (aa) { s += pc_(aa & b); aa >>= 1; }
  return (s & 1) ? -1 : 1;
}
__host__ __device__ constexpr int PIDX(int i, int j) {  // i<=j
  return 8 * i - (i * (i - 1)) / 2 + (j - i);
}

// ---------- prep bodies (merged into ONE dispatch; r7 lesson: 7 serialized
// small launches cost ~5-10us each in gaps+ramp on the graph stream) ----------

DEV void geoprep_body(const float* __restrict__ iw, const float* __restrict__ gg,
                      float* __restrict__ wcomb, int er) {
  const float* w = iw + er * 64;
  float gate = frcp(1.f + __expf(-gg[er]));
  float* c = wcomb + er * 40;
  int p = 0;
  for (int i = 0; i < 8; ++i)
    for (int j = i; j < 8; ++j) {
      float v = (float)CSGN(i, j) * frcp(1.f + __expf(-w[i * 8 + j]));
      if (j > i) v += (float)CSGN(j, i) * frcp(1.f + __expf(-w[j * 8 + i]));
      c[p++] = gate * v;
    }
  c[36] = 1.f - gate;
}

// small transpose: in (Rr,Cc) fp32 (batch bz) -> (Cc,Rr) bf16.
// TI=0 linear; TI=1: k ^= (row&7)<<3 (needs Rr==64).
template<int TI>
DEV void transpose_body(const float* __restrict__ in, unsigned short* __restrict__ out,
                        int Rr, int Cc, int bx, int by, int bz, int tid, char* sbuf) {
  unsigned short (*tile)[33] = (unsigned short (*)[33])sbuf;
  const float* ib = in + (long)bz * Rr * Cc;
  unsigned short* ob = out + (long)bz * Rr * Cc;
  int r0 = by * 32, c0 = bx * 32;
  int tr = tid >> 5, tc = tid & 31;
#pragma unroll
  for (int i = 0; i < 4; ++i) {
    int r = tr + i * 8;
    tile[r][tc] = f2bf(ib[(long)(r0 + r) * Cc + c0 + tc]);
  }
  __syncthreads();
#pragma unroll
  for (int i = 0; i < 4; ++i) {
    int c = tr + i * 8;
    int row = c0 + c;
    int k = r0 + tc;
    if (TI == 0) ob[(long)row * Rr + k] = tile[tc][c];
    else ob[(long)row * Rr + (k ^ ((row & 7) << 3))] = tile[tc][c];
  }
}

// big convert+transpose for pin/pout: in [Rr k][Cc n] fp32 -> out tiled bf16 [n][k].
DEV void trans_big_body(const float* __restrict__ in, unsigned short* __restrict__ out,
                        int Rr, int Cc, int bx, int by, int bz, int tid, char* sbuf) {
  float (*t)[64] = (float (*)[64])sbuf;
  const float* ib = in + (long)bz * Rr * Cc;
  unsigned short* ob = out + (long)bz * (long)Rr * Cc;
  int k0 = by * 64, n0 = bx * 64;
#pragma unroll
  for (int p = 0; p < 4; ++p) {
    int idx = p * 256 + tid;
    int kr = idx >> 4, nc = (idx & 15) * 4;
    *(float4*)&t[kr][nc] = *(const float4*)(ib + (long)(k0 + kr) * Cc + n0 + nc);
  }
  __syncthreads();
#pragma unroll
  for (int p = 0; p < 2; ++p) {
    int idx = p * 256 + tid;
    int n = idx & 63, kc = idx >> 6;       // kc 0..7
    float v[8];
#pragma unroll
    for (int u = 0; u < 8; ++u) v[u] = t[kc * 8 + u][n];
    uint4 o;
    o.x = pk2bf(v[0], v[1]); o.y = pk2bf(v[2], v[3]);
    o.z = pk2bf(v[4], v[5]); o.w = pk2bf(v[6], v[7]);
    *(uint4*)(ob + tiled_off(n0 + n, k0 + kc * 8, Rr)) = o;
  }
}

// ONE dispatch for all prep: blocks 0..2047 pinT, 2048..4095 poutT,
// 4096..4607 wgT, 4608..5119 wuT, 5120..5631 wdT, 5632 geoprep.
__global__ __launch_bounds__(256) void prep_k(
    const float* __restrict__ pin, const float* __restrict__ pout,
    const float* __restrict__ fg, const float* __restrict__ fu,
    const float* __restrict__ fd, const float* __restrict__ iw,
    const float* __restrict__ gg,
    unsigned short* __restrict__ pinT, unsigned short* __restrict__ poutT,
    unsigned short* __restrict__ wgT, unsigned short* __restrict__ wuT,
    unsigned short* __restrict__ wdT, float* __restrict__ wcomb) {
  __shared__ char sbuf[16384];
  int b = blockIdx.x, tid = threadIdx.x;
  if (b < 2048) {
    trans_big_body(pin, pinT, 1024, 512, b & 7, (b >> 3) & 15, b >> 7, tid, sbuf);
  } else if (b < 4096) {
    int j = b - 2048;
    trans_big_body(pout, poutT, 512, 1024, j & 15, (j >> 4) & 7, j >> 7, tid, sbuf);
  } else if (b < 4608) {
    int j = b - 4096;
    transpose_body<1>(fg, wgT, 64, 256, j & 7, (j >> 3) & 1, j >> 4, tid, sbuf);
  } else if (b < 5120) {
    int j = b - 4608;
    transpose_body<1>(fu, wuT, 64, 256, j & 7, (j >> 3) & 1, j >> 4, tid, sbuf);
  } else if (b < 5632) {
    int j = b - 5120;
    transpose_body<0>(fd, wdT, 256, 64, j & 1, (j >> 1) & 7, j >> 4, tid, sbuf);
  } else {
    if (tid < 32) geoprep_body(iw, gg, wcomb, tid);
  }
}

// GEMM1 (convert FUSED): mvB(bf16, linear [token][512]) = x @ Pin^T per expert.
// 256x256 tile, BK=64 in two 32-sub-phases. B staged via async16 from tiled
// pinT; A staged from x fp32 directly (reg-load -> cvt -> ds_write, T14 split).
__global__ __launch_bounds__(512, 1) void gemm_in_k(const float* __restrict__ X,
                                                    const unsigned short* __restrict__ Bw,
                                                    unsigned short* __restrict__ MvB,
                                                    const int* __restrict__ offs) {
  extern __shared__ char smem[];    // [2 buf][ A 32K | B 32K ], each op as 2 x 16K ksub
  int bid = blockIdx.x;             // 256 blocks
  int wg = (bid & 7) * 32 + (bid >> 3);      // XCD swizzle (256 % 8 == 0)
  int e = wg >> 4, rem = wg & 15, bm = rem >> 1, bn = rem & 1;
  int tid = threadIdx.x, wid = tid >> 6, lane = tid & 63;
  int wm = (wid >> 2) * 128, wn = (wid & 3) * 64;
  int ri = lane & 15, hi = lane >> 4;
  long rowbase = (long)offs[e] + bm * 256;   // A row base (x fp32 linear)
  long bw = (long)e * 64 + bn * 32;          // B window base (pinT tiled, K=1024)

  // phase p = t*2+s (t=K-tile 0..15, s=32-k sub 0..1)
  auto STGB = [&](int p) {
    int t = p >> 1, s = p & 1, b = t & 1;
    char* dst = smem + b * 65536 + 32768 + s * 16384;
#pragma unroll
    for (int i = 0; i < 2; ++i) {
      int d = i * 512 + tid;
      async16(Bw + (bw + (d >> 5)) * 8192 +
                  (long)((t * 8 + s * 4 + ((d >> 3) & 3)) * 64 + (d & 7) * 8),
              (unsigned short*)(dst + d * 16));
    }
  };
  auto A_LOAD = [&](int p, float4 ar[2][2]) {
    int t = p >> 1, s = p & 1;
#pragma unroll
    for (int i = 0; i < 2; ++i) {
      int d = i * 512 + tid;
      const float* src = X + (rowbase + ((d >> 5) * 8 + (d & 7))) * 1024 +
                         t * 64 + s * 32 + ((d >> 3) & 3) * 8;
      ar[i][0] = *(const float4*)src;
      ar[i][1] = *(const float4*)(src + 4);
    }
  };
  auto A_WRITE = [&](int p, float4 ar[2][2]) {
    int t = p >> 1, s = p & 1, b = t & 1;
    char* dst = smem + b * 65536 + s * 16384;
#pragma unroll
    for (int i = 0; i < 2; ++i) {
      int d = i * 512 + tid;
      uint4 o;
      o.x = pk2bf(ar[i][0].x, ar[i][0].y);
      o.y = pk2bf(ar[i][0].z, ar[i][0].w);
      o.z = pk2bf(ar[i][1].x, ar[i][1].y);
      o.w = pk2bf(ar[i][1].z, ar[i][1].w);
      *(uint4*)(dst + d * 16) = o;
    }
  };

  f32x4 acc[8][4];
#pragma unroll
  for (int i = 0; i < 8; ++i)
#pragma unroll
    for (int j = 0; j < 4; ++j) acc[i][j] = (f32x4){0.f, 0.f, 0.f, 0.f};

  // prologue: phases 0 and 1 staged (A via regs, B via async16)
  float4 ar[2][2];
  A_LOAD(0, ar); STGB(0); STGB(1);
  A_WRITE(0, ar);                 // compiler auto-waits the A regs
  A_LOAD(1, ar);
  A_WRITE(1, ar);
  wait_lgkm0();

#pragma unroll 2
  for (int p = 0; p < 32; ++p) {
    int t = p >> 1, s = p & 1, c = t & 1;
    if (p < 30) { A_LOAD(p + 2, ar); STGB(p + 2); }
    if (p < 30) asm volatile("s_waitcnt vmcnt(8)" ::: "memory");
    else if (p == 30) asm volatile("s_waitcnt vmcnt(2)" ::: "memory");
    else asm volatile("s_waitcnt vmcnt(0)" ::: "memory");
    sbar();
    const char* cA = smem + c * 65536 + s * 16384;
    const char* cB = smem + c * 65536 + 32768 + s * 16384;
    bf16x8 a[8], b[4];
#pragma unroll
    for (int i = 0; i < 8; ++i) a[i] = ld_frag(cA, wm + i * 16 + ri, hi);
#pragma unroll
    for (int j = 0; j < 4; ++j) b[j] = ld_frag(cB, wn + j * 16 + ri, hi);
    __builtin_amdgcn_s_setprio(1);
#pragma unroll
    for (int i = 0; i < 8; ++i)
#pragma unroll
      for (int j = 0; j < 4; ++j)
        acc[i][j] = __builtin_amdgcn_mfma_f32_16x16x32_bf16(a[i], b[j], acc[i][j], 0, 0, 0);
    __builtin_amdgcn_s_setprio(0);
    if (p < 30) A_WRITE(p + 2, ar);
    wait_lgkm0();
  }

  unsigned short* Cb = MvB + ((long)e * 2048 + (long)bm * 256) * 512 + bn * 256;
#pragma unroll
  for (int i = 0; i < 8; ++i)
#pragma unroll
    for (int j = 0; j < 4; ++j)
#pragma unroll
      for (int rr = 0; rr < 4; ++rr)
        Cb[(long)(wm + i * 16 + hi * 4 + rr) * 512 + wn + j * 16 + ri] =
            f2bf1(acc[i][j][rr]);
}

// ---------- merged 2-round fused kernel: 8 TOKENS PER WAVE ----------
// (unchanged from round 7: 114.7us, MfmaUtil 18, VGPR 104, no spill)
__global__ __launch_bounds__(256, 2) void rounds_k(
    const unsigned short* __restrict__ MvB, const unsigned short* __restrict__ WgT,
    const unsigned short* __restrict__ WuT, const unsigned short* __restrict__ WdT,
    const float* __restrict__ wcomb, const float* __restrict__ lnw,
    const float* __restrict__ lnb, unsigned short* __restrict__ Mvb) {
  extern __shared__ char smem[];
  int tid = threadIdx.x, wid = tid >> 6, lane = tid & 63;
  char* sFH = smem + wid * 8192;            // wave-private [64 trow][128B]
  char* sMv = smem + 32768 + wid * 8192;    // wave-private [8 tok][1K]
  char* sW  = smem + 65536;                 // dbuf 2 x 8K (Wg 4K | Wu 4K)

  int bid = blockIdx.x;
  int wg = (bid & 7) * 128 + (bid >> 3);    // XCD swizzle (1024 % 8 == 0)
  int e = wg >> 6, bx = wg & 63;

  int t8 = lane >> 3, q = lane & 7;         // P1 coords: token-in-wave, d-octet
  int ri = lane & 15, hi = lane >> 4;       // frag coords
  int sw = (ri & 7) << 4;

  // stage global eighth i8 (0..15; round = i8>>3, slice = i8&7)
  auto STAGE = [&](int i8) {
    long base = (long)(e * 2 + (i8 >> 3)) * 16384 + (i8 & 7) * 2048;
    char* dst = sW + (i8 & 1) * 8192;
    async16(WgT + base + tid * 8, (unsigned short*)(dst + tid * 16));
    async16(WuT + base + tid * 8, (unsigned short*)(dst + 4096 + tid * 16));
  };
  STAGE(0);   // prologue: lands under P1 of round 0

#pragma unroll 1
  for (int r = 0; r < 2; ++r) {
    int er = e * 2 + r;
    const unsigned short* wd = WdT + (long)er * 16384;  // [64 dout][256 F]

    // ---- P1a: mv (global bf16 on r0 -> stash to sMvh; sMvh on r1) ----
    // Each lane: token t8, d = 8q..8q+7 (two f32x4 halves).
    f32x4 mv[2][8];
    if (r == 0) {
      long base = ((long)e * 2048 + bx * 32 + wid * 8 + t8) * 512 + 8 * q;
      uint4 uv[8];
#pragma unroll
      for (int i = 0; i < 8; ++i)
        uv[i] = *(const uint4*)(MvB + base + i * 64);
#pragma unroll
      for (int i = 0; i < 8; ++i) {
        *(uint4*)(sMv + t8 * 1024 + i * 128 + ((16 * q) ^ (i << 4))) = uv[i];
        mv[0][i] = (f32x4){bf2f((unsigned short)(uv[i].x & 0xffff)),
                           bf2f((unsigned short)(uv[i].x >> 16)),
                           bf2f((unsigned short)(uv[i].y & 0xffff)),
                           bf2f((unsigned short)(uv[i].y >> 16))};
        mv[1][i] = (f32x4){bf2f((unsigned short)(uv[i].z & 0xffff)),
                           bf2f((unsigned short)(uv[i].z >> 16)),
                           bf2f((unsigned short)(uv[i].w & 0xffff)),
                           bf2f((unsigned short)(uv[i].w >> 16))};
      }
    } else {
#pragma unroll
      for (int i = 0; i < 8; ++i) {
        uint4 uv = *(const uint4*)(sMv + t8 * 1024 + i * 128 + ((16 * q) ^ (i << 4)));
        mv[0][i] = (f32x4){bf2f((unsigned short)(uv.x & 0xffff)),
                           bf2f((unsigned short)(uv.x >> 16)),
                           bf2f((unsigned short)(uv.y & 0xffff)),
                           bf2f((unsigned short)(uv.y >> 16))};
        mv[1][i] = (f32x4){bf2f((unsigned short)(uv.z & 0xffff)),
                           bf2f((unsigned short)(uv.z >> 16)),
                           bf2f((unsigned short)(uv.w & 0xffff)),
                           bf2f((unsigned short)(uv.w >> 16))};
      }
    }

    // ---- P1b: geo + mix + LN(64) -> sFH (packed math; wave-private) ----
    {
      const float* C = wcomb + er * 40;
      f32x4 g[2][8];
#pragma unroll
      for (int hf = 0; hf < 2; ++hf)
#pragma unroll
        for (int k = 0; k < 8; ++k) g[hf][k] = (f32x4){0.f, 0.f, 0.f, 0.f};
#pragma unroll
      for (int i = 0; i < 8; ++i)
#pragma unroll
        for (int j = i; j < 8; ++j) {
          float cc = C[PIDX(i, j)];
          const int k = KIDX(i, j);
          g[0][k] += cc * (mv[0][i] * mv[0][j]);
          g[1][k] += cc * (mv[1][i] * mv[1][j]);
        }
      float omg = C[36];
#pragma unroll
      for (int hf = 0; hf < 2; ++hf)
#pragma unroll
        for (int k = 0; k < 8; ++k) g[hf][k] = omg * mv[hf][k] + g[hf][k];
      float4 lwa = *(const float4*)(lnw + (long)er * 64 + 8 * q);
      float4 lwb = *(const float4*)(lnw + (long)er * 64 + 8 * q + 4);
      float4 lba = *(const float4*)(lnb + (long)er * 64 + 8 * q);
      float4 lbb = *(const float4*)(lnb + (long)er * 64 + 8 * q + 4);
      f32x4 lwvA = (f32x4){lwa.x, lwa.y, lwa.z, lwa.w};
      f32x4 lwvB = (f32x4){lwb.x, lwb.y, lwb.z, lwb.w};
      f32x4 lbvA = (f32x4){lba.x, lba.y, lba.z, lba.w};
      f32x4 lbvB = (f32x4){lbb.x, lbb.y, lbb.z, lbb.w};
#pragma unroll
      for (int bh = 0; bh < 2; ++bh) {
        f32x2 red[4];
#pragma unroll
        for (int k = 0; k < 4; ++k) {
          f32x4 a = g[0][bh * 4 + k], b = g[1][bh * 4 + k];
          red[k].x = ((a.x + a.y) + (a.z + a.w)) + ((b.x + b.y) + (b.z + b.w));
          red[k].y = (fmaf(a.x, a.x, a.y * a.y) + fmaf(a.z, a.z, a.w * a.w)) +
                     (fmaf(b.x, b.x, b.y * b.y) + fmaf(b.z, b.z, b.w * b.w));
        }
#pragma unroll
        for (int off = 4; off >= 1; off >>= 1)
#pragma unroll
          for (int t = 0; t < 4; ++t) {
            f32x2 o;
            o.x = __shfl_xor(red[t].x, off);
            o.y = __shfl_xor(red[t].y, off);
            red[t] += o;
          }
#pragma unroll
        for (int k = 0; k < 4; ++k) {
          int kk = bh * 4 + k;
          float mean = red[k].x * (1.f / 64.f);
          float var = red[k].y * (1.f / 64.f) - mean * mean;
          float rs = rsqrtf(var + 1e-5f);
          f32x4 ovA = ((g[0][kk] - mean) * rs) * lwvA + lbvA;
          f32x4 ovB = ((g[1][kk] - mean) * rs) * lwvB + lbvB;
          uint4 pv;
          pv.x = pk2bf(ovA.x, ovA.y);
          pv.y = pk2bf(ovA.z, ovA.w);
          pv.z = pk2bf(ovB.x, ovB.y);
          pv.w = pk2bf(ovB.z, ovB.w);
          int row = t8 * 8 + kk;                    // row&7 == kk
          *(uint4*)(sFH + row * 128 + ((16 * q) ^ (kk << 4))) = pv;
        }
      }
    }
    wait_lgkm0();   // own-wave flat writes done (cross-LANE reads next)

    // ---- hoist flat B-frags to regs (sFH gets reused for h afterwards) ----
    bf16x8 bfr[4][2];   // [trow-tile][k-half]
#pragma unroll
    for (int tt = 0; tt < 4; ++tt)
#pragma unroll
      for (int kt = 0; kt < 2; ++kt)
        bfr[tt][kt] = *(const bf16x8*)(sFH + (tt * 16 + ri) * 128 + ((kt * 64 + hi * 16) ^ sw));

    f32x4 acc2[4][4];   // [dout-tile][trow-tile]
#pragma unroll
    for (int j = 0; j < 4; ++j)
#pragma unroll
      for (int tt = 0; tt < 4; ++tt) acc2[j][tt] = (f32x4){0.f, 0.f, 0.f, 0.f};

#pragma unroll 1
    for (int q8 = 0; q8 < 8; ++q8) {
      int i8 = r * 8 + q8;
      wait_vm0();   // stage(i8) landed (issued a full eighth ago)
      sbar();       // all waves: stage(i8) in LDS; eighth i8-1 reads done
      if (i8 < 15) STAGE(i8 + 1);   // -> buf((i8+1)&1): free per the barrier

      // ---- Wd frags at PHASE TOP (global; full-phase latency cover) ----
      bf16x8 wdf[4];
#pragma unroll
      for (int j = 0; j < 4; ++j)
        wdf[j] = *(const bf16x8*)(wd + (j * 16 + ri) * 256 + q8 * 32 + hi * 8);

      const char* bufW = sW + (i8 & 1) * 8192;

      // ---- P2: 2 F-tiles x 4 trow-tiles; silu -> h ----
#pragma unroll
      for (int ftl = 0; ftl < 2; ++ftl) {
        const char* bg = bufW + (ftl * 16 + ri) * 128;
        const char* bu = bg + 4096;
        bf16x8 wg0 = *(const bf16x8*)(bg + ((hi * 16) ^ sw));
        bf16x8 wg1 = *(const bf16x8*)(bg + ((64 + hi * 16) ^ sw));
        bf16x8 wu0 = *(const bf16x8*)(bu + ((hi * 16) ^ sw));
        bf16x8 wu1 = *(const bf16x8*)(bu + ((64 + hi * 16) ^ sw));
        f32x4 ag[4], au[4];
#pragma unroll
        for (int tt = 0; tt < 4; ++tt) {
          ag[tt] = (f32x4){0.f, 0.f, 0.f, 0.f};
          au[tt] = (f32x4){0.f, 0.f, 0.f, 0.f};
        }
        __builtin_amdgcn_s_setprio(1);
#pragma unroll
        for (int tt = 0; tt < 4; ++tt) {
          ag[tt] = __builtin_amdgcn_mfma_f32_16x16x32_bf16(wg0, bfr[tt][0], ag[tt], 0, 0, 0);
          au[tt] = __builtin_amdgcn_mfma_f32_16x16x32_bf16(wu0, bfr[tt][0], au[tt], 0, 0, 0);
          ag[tt] = __builtin_amdgcn_mfma_f32_16x16x32_bf16(wg1, bfr[tt][1], ag[tt], 0, 0, 0);
          au[tt] = __builtin_amdgcn_mfma_f32_16x16x32_bf16(wu1, bfr[tt][1], au[tt], 0, 0, 0);
        }
        __builtin_amdgcn_s_setprio(0);
#pragma unroll
        for (int tt = 0; tt < 4; ++tt) {
          float hh[4];
#pragma unroll
          for (int rr = 0; rr < 4; ++rr) {
            float gv = ag[tt][rr], uu = au[tt][rr];
            hh[rr] = gv * uu * frcp(1.f + __expf(-gv));
          }
          uint2 hwv;
          hwv.x = pk2bf(hh[0], hh[1]);
          hwv.y = pk2bf(hh[2], hh[3]);
          // h (F_loc = ftl*16+hi*4+rr, trow = tt*16+ri) -> swizzled
          *(uint2*)(sFH + (tt * 16 + ri) * 128 + ((ftl * 32 + hi * 8) ^ sw)) = hwv;
        }
      }
      wait_lgkm0();  // own h writes complete before hk reads

      // ---- P4: acc2[dout][trow-tile] += Wd x h (one 32-k chunk) ----
      bf16x8 hk[4];
#pragma unroll
      for (int tt = 0; tt < 4; ++tt)
        hk[tt] = *(const bf16x8*)(sFH + (tt * 16 + ri) * 128 + ((hi * 16) ^ sw));
      __builtin_amdgcn_s_setprio(1);
#pragma unroll
      for (int j = 0; j < 4; ++j)
#pragma unroll
        for (int tt = 0; tt < 4; ++tt)
          acc2[j][tt] = __builtin_amdgcn_mfma_f32_16x16x32_bf16(wdf[j], hk[tt], acc2[j][tt], 0, 0, 0);
      __builtin_amdgcn_s_setprio(0);
    }

    // ---- P5: residual vs sMvh (wave-private, in place both rounds) ----
    {
#pragma unroll
      for (int tt = 0; tt < 4; ++tt) {
        int tl = tt * 2 + (ri >> 3);
        int kb = ri & 7;
#pragma unroll
        for (int j = 0; j < 4; ++j)
#pragma unroll
          for (int u = 0; u < 2; ++u) {
            int off = (j * 32 + hi * 8 + 4 * u) ^ sw;
            unsigned* p = (unsigned*)(sMv + tl * 1024 + kb * 128 + off);
            unsigned old = *p;
            float v0 = bf2f((unsigned short)(old & 0xffff)) + acc2[j][tt][2 * u];
            float v1 = bf2f((unsigned short)(old >> 16)) + acc2[j][tt][2 * u + 1];
            *p = pk2bf(v0, v1);
          }
      }
    }
    wait_lgkm0();   // sMvh updates done (next round's P1a / epilogue reads)

    // ---- r1: coalesced uint4 dump sMvh -> Mvb (8 rows = 8KB contiguous) ----
    if (r == 1) {
      int bl = lane >> 3, qq = lane & 7;
      long sbase = ((long)e * 2048 + bx * 32 + wid * 8) * 512;
#pragma unroll
      for (int h = 0; h < 8; ++h) {
        uint4 v = *(const uint4*)(sMv + h * 1024 + bl * 128 + ((16 * qq) ^ (bl << 4)));
        *(uint4*)(Mvb + sbase + h * 512 + lane * 8) = v;
      }
    }
  }
}

// ---------- fused out-projection + LayerNorm(D=1024), 512 threads/block ----------
// A (mvb) is LINEAR [token][512] bf16; tiled LDS layout derived via per-lane source addr.
__global__ __launch_bounds__(512, 2) void gemm_out_ln_k(
    const unsigned short* __restrict__ Mvb, const unsigned short* __restrict__ Pw,
    float* __restrict__ Out, const float* __restrict__ ow, const float* __restrict__ ob,
    const int* __restrict__ offs) {
  extern __shared__ char smem[];
  int bid = blockIdx.x;
  int wg = (bid & 7) * 64 + (bid >> 3);
  int e = wg >> 5, mb = wg & 31;
  int tid = threadIdx.x, wid = tid >> 6, lane = tid & 63;
  int ri = lane & 15, hi = lane >> 4;
  long bbase = (long)e * 524288;                 // poutT expert base (tiled)
  long arow0 = (long)e * 2048 + (long)mb * 64;   // mvb expert row base (linear)

  auto STAGE = [&](int buf, int kt) {
#pragma unroll
    for (int i = 0; i < 8; ++i) {
      int q = i * 512 + tid;
      int w = q >> 5, c = (q >> 3) & 3, rr = q & 7;
      async16(Pw + bbase + (long)w * 4096 + (kt * 4 + c) * 64 + rr * 8,
              (unsigned short*)(smem + buf * 65536 + q * 16));
    }
    if (tid < 256) {
      int q = tid;
      int w = q >> 5, c = (q >> 3) & 3, rr = q & 7;
      async16(Mvb + (arow0 + w * 8 + rr) * 512 + kt * 32 + c * 8,
              (unsigned short*)(smem + 131072 + buf * 4096 + q * 16));
    }
  };

  f32x4 acc[4][8];
#pragma unroll
  for (int i = 0; i < 4; ++i)
#pragma unroll
    for (int j = 0; j < 8; ++j) acc[i][j] = (f32x4){0.f, 0.f, 0.f, 0.f};

  STAGE(0, 0);
  for (int kt = 0; kt < 16; ++kt) {
    int cur = kt & 1;
    if (kt < 15) {
      STAGE(cur ^ 1, kt + 1);
      asm volatile("s_waitcnt vmcnt(8)" ::: "memory");
    } else {
      asm volatile("s_waitcnt vmcnt(0)" ::: "memory");
    }
    sbar();
    const char* cB = smem + cur * 65536;
    const char* cA = smem + 131072 + cur * 4096;
    bf16x8 a[4], b[8];
#pragma unroll
    for (int i = 0; i < 4; ++i) a[i] = ld_frag(cA, i * 16 + ri, hi);
#pragma unroll
    for (int j = 0; j < 8; ++j) b[j] = ld_frag(cB, wid * 128 + j * 16 + ri, hi);
    __builtin_amdgcn_s_setprio(1);
#pragma unroll
    for (int i = 0; i < 4; ++i)
#pragma unroll
      for (int j = 0; j < 8; ++j)
        acc[i][j] = __builtin_amdgcn_mfma_f32_16x16x32_bf16(a[i], b[j], acc[i][j], 0, 0, 0);
    __builtin_amdgcn_s_setprio(0);
    sbar();
  }

  float* rsum = (float*)(smem + 139264);
  float* rsq  = (float*)(smem + 141312);
  float* mexp = (float*)(smem + 143360);
  float* rstd = (float*)(smem + 143616);
  int hi4 = hi * 4;
#pragma unroll
  for (int i = 0; i < 4; ++i)
#pragma unroll
    for (int rr = 0; rr < 4; ++rr) {
      float s = 0.f, qv = 0.f;
#pragma unroll
      for (int j = 0; j < 8; ++j) { float v = acc[i][j][rr]; s += v; qv += v * v; }
#pragma unroll
      for (int off = 1; off < 16; off <<= 1) {
        s += __shfl_xor(s, off);
        qv += __shfl_xor(qv, off);
      }
      if (ri == 0) {
        int row = i * 16 + hi4 + rr;
        rsum[row * 8 + wid] = s;
        rsq[row * 8 + wid] = qv;
      }
    }
  __syncthreads();
  if (tid < 64) {
    float S = 0.f, Q = 0.f;
#pragma unroll
    for (int w = 0; w < 8; ++w) { S += rsum[tid * 8 + w]; Q += rsq[tid * 8 + w]; }
    float mean = S * (1.f / 1024.f);
    float var = Q * (1.f / 1024.f) - mean * mean;
    mexp[tid] = mean;
    rstd[tid] = rsqrtf(var + 1e-5f);
  }
  __syncthreads();
  long r0 = (long)offs[e] + (long)mb * 64;
  float owv[8], obv[8];
#pragma unroll
  for (int j = 0; j < 8; ++j) {
    int col = wid * 128 + j * 16 + ri;
    owv[j] = ow[col];
    obv[j] = ob[col];
  }
#pragma unroll
  for (int i = 0; i < 4; ++i)
#pragma unroll
    for (int rr = 0; rr < 4; ++rr) {
      int row = i * 16 + hi4 + rr;
      float mu = mexp[row], rs = rstd[row];
#pragma unroll
      for (int j = 0; j < 8; ++j) {
        int col = wid * 128 + j * 16 + ri;
        Out[(r0 + row) * 1024 + col] = (acc[i][j][rr] - mu) * rs * owv[j] + obv[j];
      }
    }
}

// ---------- host ----------
extern "C" void kernel_launch(void* const* d_in, const int* in_sizes, int n_in,
                              void* d_out, int out_size, void* d_ws, size_t ws_size,
                              hipStream_t stream) {
  const float* x    = (const float*)d_in[0];
  const float* pin  = (const float*)d_in[1];
  const float* pout = (const float*)d_in[2];
  const float* iw   = (const float*)d_in[3];
  const float* gg   = (const float*)d_in[4];
  const float* fg   = (const float*)d_in[5];
  const float* fu   = (const float*)d_in[6];
  const float* fd   = (const float*)d_in[7];
  const float* lnw  = (const float*)d_in[8];
  const float* lnb  = (const float*)d_in[9];
  const float* ow   = (const float*)d_in[10];
  const float* ob   = (const float*)d_in[11];
  const int* offs   = (const int*)d_in[12];

  char* ws = (char*)d_ws;
  unsigned short* mvB  = (unsigned short*)(ws + 0L);          //  33,554,432 B (linear bf16)
  unsigned short* mvb  = (unsigned short*)(ws + 33554432L);   //  33,554,432 B (linear bf16)
  unsigned short* pinT = (unsigned short*)(ws + 67108864L);   //  16,777,216 B (tiled)
  unsigned short* poutT= (unsigned short*)(ws + 83886080L);   //  16,777,216 B (tiled)
  unsigned short* wgT  = (unsigned short*)(ws + 100663296L);  //   2,097,152 B (swz-64)
  unsigned short* wuT  = (unsigned short*)(ws + 102760448L);  //   2,097,152 B (swz-64)
  unsigned short* wdT  = (unsigned short*)(ws + 104857600L);  //   2,097,152 B (plain)
  float* wcomb         = (float*)(ws + 106954752L);           //   5,120 B

  // ALL prep in ONE dispatch (r7 lesson: 7 serialized launches ~= 30-50us of
  // gaps+ramp; sub-grids are independent -> pack them into one grid)
  prep_k<<<dim3(5633), dim3(256), 0, stream>>>(
      pin, pout, fg, fu, fd, iw, gg, pinT, poutT, wgT, wuT, wdT, wcomb);

  // mvB = x @ Pin (A fp32->bf16 reg-staged in-kernel; B from tiled pinT)
  gemm_in_k<<<dim3(256), dim3(512), 131072, stream>>>(x, pinT, mvB, offs);

  // both rounds in ONE kernel; 8 tokens/wave, W dbuf in eighths, 80K LDS
  rounds_k<<<dim3(1024), dim3(256), 81920, stream>>>(
      mvB, wgT, wuT, wdT, wcomb, lnw, lnb, mvb);

  // out = LN(mvb @ Pout)
  gemm_out_ln_k<<<dim3(512), dim3(512), 143872, stream>>>(
      mvb, poutT, (float*)d_out, ow, ob, offs);
}